// Round 9
// baseline (249.967 us; speedup 1.0000x reference)
//
#include <hip/hip_runtime.h>
#include <hip/hip_bf16.h>
#include <math.h>

#define Bc 32
#define Rc 200
#define Nc 200
#define Dc 128
#define Hc 8
#define QKc 16
#define Kc 10
#define BRc (Bc*Rc)

typedef __attribute__((ext_vector_type(8))) short short8;
typedef __attribute__((ext_vector_type(4))) float f32x4;
typedef unsigned long long u64;

#define GLOAD_LDS16(g, l) __builtin_amdgcn_global_load_lds( \
    (const __attribute__((address_space(1))) void*)(g), \
    (__attribute__((address_space(3))) void*)(l), 16, 0, 0)

// ---------------------------------------------------------------------------
// 32x32 transpose+convert tile helper (block-uniform call sites only)
// ---------------------------------------------------------------------------
__device__ inline void transpose_tile(const float* __restrict__ src, int lds_,
                                      __hip_bfloat16* __restrict__ dst, int ldd,
                                      int k0, int n0, float scale)
{
    __shared__ float tile[32][33];
    int tx = threadIdx.x & 31, ty = threadIdx.x >> 5;  // 32 x 8
    #pragma unroll
    for (int i = ty; i < 32; i += 8)
        tile[i][tx] = src[(size_t)(k0 + i) * lds_ + n0 + tx];
    __syncthreads();
    #pragma unroll
    for (int i = ty; i < 32; i += 8)
        dst[(size_t)(n0 + i) * ldd + k0 + tx] = __float2bfloat16(tile[tx][i] * scale);
}

// ---------------------------------------------------------------------------
// Kernel P: all weight preprocessing in ONE launch (role = blockIdx.x range).
// Wcat/bq carry the attention scale 0.25 folded in (q comes out pre-scaled).
// ---------------------------------------------------------------------------
__global__ __launch_bounds__(256) void prep_kernel(
    const float* __restrict__ W1, const float* __restrict__ W2,
    const float* __restrict__ Wq, const float* __restrict__ Wmhc,
    const float* __restrict__ Wk, const float* __restrict__ Wv,
    const float* __restrict__ b2, const float* __restrict__ enc,
    __hip_bfloat16* __restrict__ W1t, __hip_bfloat16* __restrict__ Wkvt,
    __hip_bfloat16* __restrict__ Wmt, __hip_bfloat16* __restrict__ Wcat,
    float* __restrict__ bq, __hip_bfloat16* __restrict__ encb)
{
    int bid = blockIdx.x;
    int t = threadIdx.x;
    if (bid < 800) {
        transpose_tile(W1, 640, W1t, 1280, (bid % 40) * 32, (bid / 40) * 32, 1.f);
    } else if (bid < 816) {
        int id = bid - 800;
        transpose_tile(Wk, 128, Wkvt, 128, (id & 3) * 32, (id >> 2) * 32, 1.f);
    } else if (bid < 832) {
        int id = bid - 816;
        transpose_tile(Wv, 128, Wkvt + 128 * 128, 128, (id & 3) * 32, (id >> 2) * 32, 1.f);
    } else if (bid < 848) {
        int id = bid - 832;
        transpose_tile(Wmhc, 128, Wmt, 128, (id & 3) * 32, (id >> 2) * 32, 1.f);
    } else if (bid < 864) {
        int id = bid - 848;
        transpose_tile(Wq, 128, Wcat, 768, (id & 3) * 32, (id >> 2) * 32, 0.25f);
    } else if (bid < 904) {
        int j0 = (bid - 864) * 16;
        int n = t & 127, half = t >> 7;
        #pragma unroll
        for (int jj = 0; jj < 8; ++jj) {
            int j = j0 + half * 8 + jj;
            float acc = 0.f;
            for (int k = 0; k < 128; ++k)
                acc = fmaf(W2[(size_t)j * 128 + k], Wq[(size_t)(128 + k) * 128 + n], acc);
            Wcat[(size_t)n * 768 + 128 + j] = __float2bfloat16(acc * 0.25f);
        }
    } else if (bid < 929) {
        size_t base = (size_t)(bid - 904) * 32768 + (size_t)t * 4;
        #pragma unroll 4
        for (int it = 0; it < 32; ++it) {
            size_t i = base + (size_t)it * 1024;
            float4 v = *(const float4*)(enc + i);
            encb[i + 0] = __float2bfloat16(v.x);
            encb[i + 1] = __float2bfloat16(v.y);
            encb[i + 2] = __float2bfloat16(v.z);
            encb[i + 3] = __float2bfloat16(v.w);
        }
    } else {
        if (t < 128) {
            float acc = 0.f;
            for (int k = 0; k < 128; ++k)
                acc = fmaf(b2[k], Wq[(size_t)(128 + k) * 128 + t], acc);
            bq[t] = acc * 0.25f;
        }
    }
}

// ---------------------------------------------------------------------------
// Kernel 1: kNN top-10 (JAX tie-break) on one wave. Writes aoff (row-offset
// table for gemm1's gather), maskbits, cur_emb->hq[:,0:128]. The enc gather
// is only needed to build the pad-mean row, and pads can only occur when
// fewer than K nodes are unvisited — detected via s_idx[K-1]==Nc (pads
// trail), so the gather runs under a block-uniform branch (cold path).
// ---------------------------------------------------------------------------
__global__ __launch_bounds__(64) void knn_kernel(
    const float* __restrict__ dist, const float* __restrict__ mask,
    const int* __restrict__ cur, __hip_bfloat16* __restrict__ encb,
    unsigned* __restrict__ aoff, __hip_bfloat16* __restrict__ hq,
    u64* __restrict__ maskbits)
{
    int br = blockIdx.x;
    int b = br / Rc;
    int t = threadIdx.x;           // 0..63, one wave
    __shared__ int s_idx[Kc];

    int c = cur[br];
    const float* drow = dist + ((size_t)b * Nc + c) * Nc;
    const float* mrow = mask + (size_t)br * Nc;

    float v[4];
    #pragma unroll
    for (int j = 0; j < 4; ++j) {
        int n = t + 64 * j;
        bool allowed = false;
        float val = INFINITY;
        if (n < Nc) {
            float mv = mrow[n];
            if (!isinf(mv)) { val = drow[n]; allowed = true; }
        }
        v[j] = val;
        u64 w = __ballot(allowed);
        if (t == 0) maskbits[(size_t)br * 4 + j] = w;
    }
    unsigned myrow = 0;
    for (int k = 0; k < Kc; ++k) {
        float bv = v[0]; int bn = t;
        #pragma unroll
        for (int j = 1; j < 4; ++j) {
            if (v[j] < bv) { bv = v[j]; bn = t + 64 * j; }
        }
        #pragma unroll
        for (int off = 32; off > 0; off >>= 1) {
            float ov = __shfl_xor(bv, off);
            int   on = __shfl_xor(bn, off);
            if (ov < bv || (ov == bv && on < bn)) { bv = ov; bn = on; }
        }
        bool pad = isinf(bv);
        if (t == 0) s_idx[k] = pad ? Nc : bn;
        if (t == k) myrow = pad ? (unsigned)(Bc * Nc + br) : (unsigned)(b * Nc + bn);
        int oj = bn >> 6, ol = bn & 63;
        if (!pad && t == ol) v[oj] = INFINITY;
    }
    if (t < Kc) aoff[(size_t)br * 16 + t] = myrow << 7;

    // cur_emb -> hq[:,0:128] (bf16 copy, bit-identical to bf16(enc))
    const short* erow = (const short*)encb + ((size_t)b * Nc + c) * Dc;
    short* hrow = (short*)hq + (size_t)br * 768;
    hrow[t] = erow[t];
    hrow[t + 64] = erow[t + 64];

    __syncthreads();
    if (s_idx[Kc - 1] == Nc) {     // block-uniform cold path: pads exist
        float cnt = 0.f;
        #pragma unroll
        for (int k = 0; k < Kc; ++k) cnt += (s_idx[k] < Nc) ? 1.f : 0.f;
        float icnt = 1.f / fmaxf(cnt, 1e-9f);
        #pragma unroll
        for (int half = 0; half < 2; ++half) {
            int d = t + 64 * half;
            float sum = 0.f;
            for (int k = 0; k < Kc; ++k) {
                int idx = s_idx[k];
                if (idx < Nc)
                    sum += __bfloat162float(encb[((size_t)b * Nc + idx) * Dc + d]);
            }
            encb[((size_t)(Bc * Nc) + br) * Dc + d] = __float2bfloat16(sum * icnt);
        }
    }
}

// ---------------------------------------------------------------------------
// Kernel 3: BM=64 x BN=128 bf16 MFMA GEMM. C = A @ Bt^T (+bias). BK=64.
// Doubled grid vs the 128-tile => ~2x blocks/CU, overlapping barrier drains.
// ---------------------------------------------------------------------------
template<bool HASBIAS, bool OUTBF16>
__global__ __launch_bounds__(256) void mfma_gemm64_kernel(
    const __hip_bfloat16* __restrict__ A, int lda,
    const __hip_bfloat16* __restrict__ Bt, int ldbt, int Kloop,
    const float* __restrict__ bias,
    void* __restrict__ Cout, int ldc, int coff)
{
    __shared__ short Asl[2][64 * 32];
    __shared__ short Bsl[2][128 * 32];
    int tid = threadIdx.x;
    int wave = tid >> 6, lane = tid & 63;
    int m0 = blockIdx.y * 64, n0 = blockIdx.x * 128;

    int lrow = lane >> 2;
    int cg   = lane & 3;
    int ss   = (lane >> 3) & 3;
    int gq   = (cg - ss) & 3;
    const short* Ab = (const short*)A;
    const short* Bb = (const short*)Bt;
    const short* gA0 = Ab + (size_t)(m0 + (wave & 1) * 32 + lrow) * lda + gq * 8;
    const short* gA1 = gA0 + (size_t)16 * lda;
    const short* gB0 = Bb + (size_t)(n0 + wave * 32 + lrow) * ldbt + gq * 8;
    const short* gB1 = gB0 + (size_t)16 * ldbt;

    int wm = wave >> 1, wn = wave & 1;
    int rrow = lane & 15, quad = lane >> 4;
    int srd  = (rrow >> 1) & 3;

    f32x4 acc[2][4];
    #pragma unroll
    for (int i = 0; i < 2; ++i)
        #pragma unroll
        for (int j = 0; j < 4; ++j)
            acc[i][j] = (f32x4){0.f, 0.f, 0.f, 0.f};

    for (int k0 = 0; k0 < Kloop; k0 += 64) {
        __syncthreads();
        #pragma unroll
        for (int s = 0; s < 2; ++s) {
            if (wave < 2) {
                GLOAD_LDS16(gA0 + k0 + s * 32, &Asl[s][(wave * 32) * 32]);
                GLOAD_LDS16(gA1 + k0 + s * 32, &Asl[s][(wave * 32 + 16) * 32]);
            }
            GLOAD_LDS16(gB0 + k0 + s * 32, &Bsl[s][(wave * 32) * 32]);
            GLOAD_LDS16(gB1 + k0 + s * 32, &Bsl[s][(wave * 32 + 16) * 32]);
        }
        __syncthreads();
        #pragma unroll
        for (int s = 0; s < 2; ++s) {
            short8 afr[2], bfr[4];
            #pragma unroll
            for (int mt = 0; mt < 2; ++mt) {
                int rowa = wm * 32 + mt * 16 + rrow;
                afr[mt] = *(const short8*)&Asl[s][rowa * 32 + ((quad + srd) & 3) * 8];
            }
            #pragma unroll
            for (int nt = 0; nt < 4; ++nt) {
                int rowb = wn * 64 + nt * 16 + rrow;
                bfr[nt] = *(const short8*)&Bsl[s][rowb * 32 + ((quad + srd) & 3) * 8];
            }
            #pragma unroll
            for (int mt = 0; mt < 2; ++mt)
                #pragma unroll
                for (int nt = 0; nt < 4; ++nt)
                    acc[mt][nt] = __builtin_amdgcn_mfma_f32_16x16x32_bf16(
                        afr[mt], bfr[nt], acc[mt][nt], 0, 0, 0);
        }
    }

    #pragma unroll
    for (int mt = 0; mt < 2; ++mt) {
        #pragma unroll
        for (int nt = 0; nt < 4; ++nt) {
            int n = wn * 64 + nt * 16 + rrow;
            float bv = HASBIAS ? bias[n0 + n] : 0.f;
            #pragma unroll
            for (int i = 0; i < 4; ++i) {
                int m = m0 + wm * 32 + mt * 16 + quad * 4 + i;
                float vv = acc[mt][nt][i] + bv;
                size_t off = (size_t)m * ldc + coff + n0 + n;
                if (OUTBF16) ((__hip_bfloat16*)Cout)[off] = __float2bfloat16(vv);
                else         ((float*)Cout)[off] = vv;
            }
        }
    }
}

// ---------------------------------------------------------------------------
// Kernel 2: GEMM1 hq[:,128:768] = relu(gather(encb) @ W1t^T + b1).
// BM=64 variant of the gather GEMM; K=1280 fully unrolled; BK=64.
// ---------------------------------------------------------------------------
__global__ __launch_bounds__(256) void gemm1_kernel(
    const __hip_bfloat16* __restrict__ encb, const unsigned* __restrict__ aoff,
    const __hip_bfloat16* __restrict__ W1t, const float* __restrict__ b1,
    __hip_bfloat16* __restrict__ hq)
{
    __shared__ short Asl[2][64 * 32];
    __shared__ short Bsl[2][128 * 32];
    int tid = threadIdx.x;
    int wave = tid >> 6, lane = tid & 63;
    int m0 = blockIdx.y * 64, n0 = blockIdx.x * 128;

    int lrow = lane >> 2;
    int cg   = lane & 3;
    int ss   = (lane >> 3) & 3;
    int gq   = (cg - ss) & 3;

    unsigned o0[Kc], o1[Kc];
    {
        const unsigned* ap0 = aoff + (size_t)(m0 + (wave & 1) * 32 + lrow) * 16;
        const unsigned* ap1 = ap0 + 16 * 16;
        #pragma unroll
        for (int j = 0; j < Kc; ++j) { o0[j] = ap0[j]; o1[j] = ap1[j]; }
    }
    const short* Eb = (const short*)encb;
    const short* Bb = (const short*)W1t;
    const short* gB0 = Bb + (size_t)(n0 + wave * 32 + lrow) * 1280 + gq * 8;
    const short* gB1 = gB0 + (size_t)16 * 1280;

    int wm = wave >> 1, wn = wave & 1;
    int rrow = lane & 15, quad = lane >> 4;
    int srd  = (rrow >> 1) & 3;

    f32x4 acc[2][4];
    #pragma unroll
    for (int i = 0; i < 2; ++i)
        #pragma unroll
        for (int j = 0; j < 4; ++j)
            acc[i][j] = (f32x4){0.f, 0.f, 0.f, 0.f};

    #pragma unroll
    for (int kt = 0; kt < 20; ++kt) {
        int k0 = kt * 64;
        int slot = kt >> 1;
        int dbase = (kt & 1) * 64 + gq * 8;
        __syncthreads();
        #pragma unroll
        for (int s = 0; s < 2; ++s) {
            if (wave < 2) {
                GLOAD_LDS16(Eb + o0[slot] + dbase + s * 32, &Asl[s][(wave * 32) * 32]);
                GLOAD_LDS16(Eb + o1[slot] + dbase + s * 32, &Asl[s][(wave * 32 + 16) * 32]);
            }
            GLOAD_LDS16(gB0 + k0 + s * 32, &Bsl[s][(wave * 32) * 32]);
            GLOAD_LDS16(gB1 + k0 + s * 32, &Bsl[s][(wave * 32 + 16) * 32]);
        }
        __syncthreads();
        #pragma unroll
        for (int s = 0; s < 2; ++s) {
            short8 afr[2], bfr[4];
            #pragma unroll
            for (int mt = 0; mt < 2; ++mt) {
                int rowa = wm * 32 + mt * 16 + rrow;
                afr[mt] = *(const short8*)&Asl[s][rowa * 32 + ((quad + srd) & 3) * 8];
            }
            #pragma unroll
            for (int nt = 0; nt < 4; ++nt) {
                int rowb = wn * 64 + nt * 16 + rrow;
                bfr[nt] = *(const short8*)&Bsl[s][rowb * 32 + ((quad + srd) & 3) * 8];
            }
            #pragma unroll
            for (int mt = 0; mt < 2; ++mt)
                #pragma unroll
                for (int nt = 0; nt < 4; ++nt)
                    acc[mt][nt] = __builtin_amdgcn_mfma_f32_16x16x32_bf16(
                        afr[mt], bfr[nt], acc[mt][nt], 0, 0, 0);
        }
    }

    #pragma unroll
    for (int mt = 0; mt < 2; ++mt) {
        #pragma unroll
        for (int nt = 0; nt < 4; ++nt) {
            int n = wn * 64 + nt * 16 + rrow;
            float bv = b1[n0 + n];
            #pragma unroll
            for (int i = 0; i < 4; ++i) {
                int m = m0 + wm * 32 + mt * 16 + quad * 4 + i;
                float vv = fmaxf(acc[mt][nt][i] + bv, 0.f);
                hq[(size_t)m * 768 + 128 + n0 + n] = __float2bfloat16(vv);
            }
        }
    }
}

// ---------------------------------------------------------------------------
// Kernel 4: MFMA flash attention, one block per (b,h), 4 waves. (unchanged)
// ---------------------------------------------------------------------------
__global__ __launch_bounds__(256) void attn_mfma_kernel(
    const __hip_bfloat16* __restrict__ q, const __hip_bfloat16* __restrict__ kvf,
    const u64* __restrict__ maskbits, __hip_bfloat16* __restrict__ att)
{
    constexpr int RP = 208;
    constexpr int QS = 40;
    constexpr int VS = 232;
    __shared__ short Qs[RP * QS];
    __shared__ short Ks[RP * QS];
    __shared__ short Vt[16 * VS];
    __shared__ short Ps[4][16 * VS];
    __shared__ u64 smask[RP][4];

    int b = blockIdx.x >> 3, h = blockIdx.x & 7;
    int t = threadIdx.x;
    int wave = t >> 6, lane = t & 63;
    int rrow = lane & 15, quad = lane >> 4;

    const short8 z8 = {0, 0, 0, 0, 0, 0, 0, 0};
    for (int idx = t; idx < RP * 2; idx += 256) {
        int r = idx >> 1, g = idx & 1;
        short8 qa = z8, ka = z8;
        if (r < Rc) {
            qa = *(const short8*)((const short*)q + ((size_t)(b * Rc + r)) * 128 + h * 16 + g * 8);
            ka = *(const short8*)((const short*)kvf + ((size_t)(b * Nc + r)) * 256 + h * 16 + g * 8);
        }
        *(short8*)&Qs[r * QS + g * 8] = qa;
        *(short8*)&Ks[r * QS + g * 8] = ka;
        *(short8*)&Qs[r * QS + 16 + g * 8] = z8;
        *(short8*)&Ks[r * QS + 16 + g * 8] = z8;
    }
    if (t < Rc) {
        const short* vp = (const short*)kvf + ((size_t)(b * Nc + t)) * 256 + 128 + h * 16;
        short8 v0 = *(const short8*)vp;
        short8 v1 = *(const short8*)(vp + 8);
        #pragma unroll
        for (int d = 0; d < 8; ++d) Vt[d * VS + t] = v0[d];
        #pragma unroll
        for (int d = 0; d < 8; ++d) Vt[(d + 8) * VS + t] = v1[d];
    }
    for (int idx = t; idx < 16 * 32; idx += 256) {
        int d = idx >> 5, cN = 200 + (idx & 31);
        if (cN < VS) Vt[d * VS + cN] = 0;
    }
    for (int idx = lane; idx < 16 * 16; idx += 64) {
        int rr = idx >> 4, cc = 208 + (idx & 15);
        Ps[wave][rr * VS + cc] = 0;
    }
    for (int idx = t; idx < RP * 4; idx += 256) {
        int r = idx >> 2, w = idx & 3;
        smask[r][w] = (r < Rc) ? maskbits[((size_t)b * Rc + r) * 4 + w] : ~0ull;
    }
    __syncthreads();

    for (int rt = wave; rt < 13; rt += 4) {
        short8 qf = *(const short8*)&Qs[(rt * 16 + rrow) * QS + quad * 8];
        f32x4 sacc[13];
        #pragma unroll
        for (int nt = 0; nt < 13; ++nt) {
            short8 kf = *(const short8*)&Ks[(nt * 16 + rrow) * QS + quad * 8];
            sacc[nt] = __builtin_amdgcn_mfma_f32_16x16x32_bf16(
                qf, kf, (f32x4){0.f, 0.f, 0.f, 0.f}, 0, 0, 0);
        }
        float inv[4];
        #pragma unroll
        for (int i = 0; i < 4; ++i) {
            int r = rt * 16 + quad * 4 + i;
            u64 wv0 = smask[r][0], wv1 = smask[r][1], wv2 = smask[r][2], wv3 = smask[r][3];
            float mx = -INFINITY;
            #pragma unroll
            for (int nt = 0; nt < 13; ++nt) {
                u64 w = (nt < 4) ? wv0 : (nt < 8) ? wv1 : (nt < 12) ? wv2 : wv3;
                int sh = ((nt & 3) << 4) + rrow;
                float s = ((w >> sh) & 1ull) ? sacc[nt][i] : -INFINITY;
                sacc[nt][i] = s;
                mx = fmaxf(mx, s);
            }
            mx = fmaxf(mx, __shfl_xor(mx, 1));
            mx = fmaxf(mx, __shfl_xor(mx, 2));
            mx = fmaxf(mx, __shfl_xor(mx, 4));
            mx = fmaxf(mx, __shfl_xor(mx, 8));
            float l = 0.f;
            #pragma unroll
            for (int nt = 0; nt < 13; ++nt) {
                float p = __expf(sacc[nt][i] - mx);
                sacc[nt][i] = p;
                l += p;
            }
            l += __shfl_xor(l, 1);
            l += __shfl_xor(l, 2);
            l += __shfl_xor(l, 4);
            l += __shfl_xor(l, 8);
            inv[i] = (l > 0.f) ? 1.f / l : 0.f;
        }
        #pragma unroll
        for (int nt = 0; nt < 13; ++nt)
            #pragma unroll
            for (int i = 0; i < 4; ++i)
                *(__hip_bfloat16*)&Ps[wave][(quad * 4 + i) * VS + nt * 16 + rrow] =
                    __float2bfloat16(sacc[nt][i]);
        f32x4 oacc = (f32x4){0.f, 0.f, 0.f, 0.f};
        #pragma unroll
        for (int kt = 0; kt < 7; ++kt) {
            short8 pf = *(const short8*)&Ps[wave][rrow * VS + kt * 32 + quad * 8];
            short8 vf = *(const short8*)&Vt[rrow * VS + kt * 32 + quad * 8];
            oacc = __builtin_amdgcn_mfma_f32_16x16x32_bf16(pf, vf, oacc, 0, 0, 0);
        }
        #pragma unroll
        for (int i = 0; i < 4; ++i) {
            int r = rt * 16 + quad * 4 + i;
            if (r < Rc)
                att[((size_t)(b * Rc + r)) * 128 + h * 16 + rrow] =
                    __float2bfloat16(oacc[i] * inv[i]);
        }
    }
}

// ---------------------------------------------------------------------------
// Kernel 5: fused logits+softmax. Block = (b, 128-row tile), all 208 cols
// in-block (13 n-tiles). K=128 staged once; attn-style register softmax;
// writes final probabilities to d_out.
// ---------------------------------------------------------------------------
__global__ __launch_bounds__(256) void logits_softmax_kernel(
    const __hip_bfloat16* __restrict__ mh, const __hip_bfloat16* __restrict__ encb,
    const u64* __restrict__ maskbits, float* __restrict__ out)
{
    __shared__ short Asl[4][128 * 32];   // 32 KB
    __shared__ short Bsl[4][208 * 32];   // 53 KB
    __shared__ u64 sm[128][4];
    int b = blockIdx.x, m0 = blockIdx.y * 128;
    int t = threadIdx.x, wave = t >> 6, lane = t & 63;
    int lrow = lane >> 2, cg = lane & 3, ss = (lane >> 3) & 3, gq = (cg - ss) & 3;
    int rrow = lane & 15, quad = lane >> 4, srd = (rrow >> 1) & 3;

    const short* Amh = (const short*)mh + ((size_t)b * Rc + m0) * 128;
    const short* Ben = (const short*)encb + (size_t)b * Nc * 128;

    #pragma unroll
    for (int rc = 0; rc < 2; ++rc)
        #pragma unroll
        for (int kc = 0; kc < 4; ++kc)
            GLOAD_LDS16(Amh + (size_t)(wave * 32 + rc * 16 + lrow) * 128 + kc * 32 + gq * 8,
                        &Asl[kc][(wave * 32 + rc * 16) * 32]);
    for (int cch = wave; cch < 13; cch += 4)
        #pragma unroll
        for (int kc = 0; kc < 4; ++kc)
            GLOAD_LDS16(Ben + (size_t)(cch * 16 + lrow) * 128 + kc * 32 + gq * 8,
                        &Bsl[kc][(cch * 16) * 32]);
    for (int idx = t; idx < 512; idx += 256) {
        int r = idx >> 2, w = idx & 3;
        sm[r][w] = (m0 + r < Rc) ? maskbits[((size_t)b * Rc + m0 + r) * 4 + w] : 0ull;
    }
    __syncthreads();

    short8 afr[2][4];
    #pragma unroll
    for (int mt = 0; mt < 2; ++mt)
        #pragma unroll
        for (int kc = 0; kc < 4; ++kc)
            afr[mt][kc] = *(const short8*)
                &Asl[kc][(wave * 32 + mt * 16 + rrow) * 32 + ((quad + srd) & 3) * 8];

    f32x4 acc[2][13];
    #pragma unroll
    for (int mt = 0; mt < 2; ++mt)
        #pragma unroll
        for (int nt = 0; nt < 13; ++nt)
            acc[mt][nt] = (f32x4){0.f, 0.f, 0.f, 0.f};
    #pragma unroll
    for (int nt = 0; nt < 13; ++nt)
        #pragma unroll
        for (int kc = 0; kc < 4; ++kc) {
            short8 bfr = *(const short8*)
                &Bsl[kc][(nt * 16 + rrow) * 32 + ((quad + srd) & 3) * 8];
            acc[0][nt] = __builtin_amdgcn_mfma_f32_16x16x32_bf16(afr[0][kc], bfr, acc[0][nt], 0, 0, 0);
            acc[1][nt] = __builtin_amdgcn_mfma_f32_16x16x32_bf16(afr[1][kc], bfr, acc[1][nt], 0, 0, 0);
        }

    const float scale = 0.08838834764831843f;  // 1/sqrt(128)
    #pragma unroll
    for (int mt = 0; mt < 2; ++mt) {
        #pragma unroll
        for (int i = 0; i < 4; ++i) {
            int rloc = wave * 32 + mt * 16 + quad * 4 + i;
            int r = m0 + rloc;
            u64 w0 = sm[rloc][0], w1 = sm[rloc][1], w2 = sm[rloc][2], w3 = sm[rloc][3];
            float vals[13];
            float mx = -INFINITY;
            #pragma unroll
            for (int nt = 0; nt < 13; ++nt) {
                u64 w = (nt < 4) ? w0 : (nt < 8) ? w1 : (nt < 12) ? w2 : w3;
                int sh = ((nt & 3) << 4) + rrow;
                float lg = ((w >> sh) & 1ull)
                         ? 10.f * tanhf(acc[mt][nt][i] * scale) : -INFINITY;
                vals[nt] = lg;
                mx = fmaxf(mx, lg);
            }
            mx = fmaxf(mx, __shfl_xor(mx, 1));
            mx = fmaxf(mx, __shfl_xor(mx, 2));
            mx = fmaxf(mx, __shfl_xor(mx, 4));
            mx = fmaxf(mx, __shfl_xor(mx, 8));
            float l = 0.f;
            #pragma unroll
            for (int nt = 0; nt < 13; ++nt) {
                float p = (vals[nt] == -INFINITY) ? 0.f : __expf(vals[nt] - mx);
                vals[nt] = p;
                l += p;
            }
            l += __shfl_xor(l, 1);
            l += __shfl_xor(l, 2);
            l += __shfl_xor(l, 4);
            l += __shfl_xor(l, 8);
            float inv = (l > 0.f) ? 1.f / l : 0.f;
            if (r < Rc) {
                #pragma unroll
                for (int nt = 0; nt < 13; ++nt) {
                    int n = nt * 16 + rrow;
                    if (n < Nc)
                        out[((size_t)b * Rc + r) * Nc + n] = vals[nt] * inv;
                }
            }
        }
    }
}

// ---------------------------------------------------------------------------
extern "C" void kernel_launch(void* const* d_in, const int* in_sizes, int n_in,
                              void* d_out, int out_size, void* d_ws, size_t ws_size,
                              hipStream_t stream)
{
    const float* enc  = (const float*)d_in[0];
    const float* dist = (const float*)d_in[1];
    const float* mask = (const float*)d_in[2];
    const int*   cur  = (const int*)d_in[3];
    const float* Wq   = (const float*)d_in[4];
    const float* Wk   = (const float*)d_in[5];
    const float* Wv   = (const float*)d_in[6];
    const float* Wmhc = (const float*)d_in[7];
    const float* bmhc = (const float*)d_in[8];
    const float* W1   = (const float*)d_in[9];
    const float* b1   = (const float*)d_in[10];
    const float* W2   = (const float*)d_in[11];
    const float* b2   = (const float*)d_in[12];
    float* out = (float*)d_out;

    char* ws = (char*)d_ws;
    size_t off = 0;
    auto alloc = [&](size_t bytes) { char* p = ws + off; off += (bytes + 255) & ~(size_t)255; return p; };
    __hip_bfloat16* W1t  = (__hip_bfloat16*)alloc((size_t)640 * 1280 * 2);
    __hip_bfloat16* Wkvt = (__hip_bfloat16*)alloc((size_t)256 * 128 * 2);
    __hip_bfloat16* Wmt  = (__hip_bfloat16*)alloc((size_t)128 * 128 * 2);
    __hip_bfloat16* Wcat = (__hip_bfloat16*)alloc((size_t)128 * 768 * 2);
    float* bq = (float*)alloc((size_t)128 * 4);
    // encb: rows [0, Bc*Nc) = enc bf16; rows [Bc*Nc, Bc*Nc+BRc) = mean rows
    __hip_bfloat16* encb = (__hip_bfloat16*)alloc((size_t)(Bc * Nc + BRc + 64) * Dc * 2);
    unsigned* aoff = (unsigned*)alloc((size_t)BRc * 16 * 4);
    __hip_bfloat16* hq   = (__hip_bfloat16*)alloc((size_t)BRc * 768 * 2);
    __hip_bfloat16* q    = (__hip_bfloat16*)alloc((size_t)BRc * 128 * 2);
    __hip_bfloat16* kvf  = (__hip_bfloat16*)alloc((size_t)Bc * Nc * 256 * 2);
    __hip_bfloat16* att  = (__hip_bfloat16*)alloc((size_t)BRc * 128 * 2);
    __hip_bfloat16* mh   = (__hip_bfloat16*)alloc((size_t)(BRc + 64) * 128 * 2);
    u64* maskbits = (u64*)alloc((size_t)BRc * 4 * 8);

    // 1) weight preprocessing
    prep_kernel<<<930, 256, 0, stream>>>(W1, W2, Wq, Wmhc, Wk, Wv, b2, enc,
                                         W1t, Wkvt, Wmt, Wcat, bq, encb);
    // 2) kNN select -> aoff/maskbits/cur_emb (+mean rows only if pads exist)
    knn_kernel<<<BRc, 64, 0, stream>>>(dist, mask, cur, encb, aoff, hq, maskbits);
    // 3) kvf = enc @ [Wk|Wv]      grid (2,100)
    mfma_gemm64_kernel<false, true><<<dim3(2, (Bc * Nc) / 64), 256, 0, stream>>>(
        encb, 128, Wkvt, 128, 128, nullptr, kvf, 256, 0);
    // 4) hq[:,128:768] = relu(gather(encb) @ W1t^T + b1)   grid (5,100)
    gemm1_kernel<<<dim3(5, BRc / 64), 256, 0, stream>>>(encb, aoff, W1t, b1, hq);
    // 5) q = hq @ Wcat^T + bq  (pre-scaled, bf16)   grid (1,100)
    mfma_gemm64_kernel<true, true><<<dim3(1, BRc / 64), 256, 0, stream>>>(
        hq, 768, Wcat, 768, 768, bq, q, 128, 0);
    // 6) MFMA flash attention
    attn_mfma_kernel<<<Bc * Hc, 256, 0, stream>>>(q, kvf, maskbits, att);
    // 7) mh = att @ Wmhc + b_mhc (bf16 out)   grid (1,100)
    mfma_gemm64_kernel<true, true><<<dim3(1, BRc / 64), 256, 0, stream>>>(
        att, 128, Wmt, 128, 128, bmhc, mh, 128, 0);
    // 8) fused logits + softmax -> d_out
    logits_softmax_kernel<<<dim3(Bc, 2), 256, 0, stream>>>(mh, encb, maskbits, out);
}

// Round 10
// 203.426 us; speedup vs baseline: 1.2288x; 1.2288x over previous
//
#include <hip/hip_runtime.h>
#include <hip/hip_bf16.h>
#include <math.h>

#define Bc 32
#define Rc 200
#define Nc 200
#define Dc 128
#define Hc 8
#define QKc 16
#define Kc 10
#define BRc (Bc*Rc)

typedef __attribute__((ext_vector_type(8))) short short8;
typedef __attribute__((ext_vector_type(4))) float f32x4;
typedef unsigned long long u64;

#define GLOAD_LDS16(g, l) __builtin_amdgcn_global_load_lds( \
    (const __attribute__((address_space(1))) void*)(g), \
    (__attribute__((address_space(3))) void*)(l), 16, 0, 0)

// ---------------------------------------------------------------------------
// 32x32 transpose+convert tile helper (block-uniform call sites only)
// ---------------------------------------------------------------------------
__device__ inline void transpose_tile(const float* __restrict__ src, int lds_,
                                      __hip_bfloat16* __restrict__ dst, int ldd,
                                      int k0, int n0, float scale)
{
    __shared__ float tile[32][33];
    int tx = threadIdx.x & 31, ty = threadIdx.x >> 5;  // 32 x 8
    #pragma unroll
    for (int i = ty; i < 32; i += 8)
        tile[i][tx] = src[(size_t)(k0 + i) * lds_ + n0 + tx];
    __syncthreads();
    #pragma unroll
    for (int i = ty; i < 32; i += 8)
        dst[(size_t)(n0 + i) * ldd + k0 + tx] = __float2bfloat16(tile[tx][i] * scale);
}

// ---------------------------------------------------------------------------
// Kernel P: all weight preprocessing in ONE launch (role = blockIdx.x range).
// Wcat/bq carry the attention scale 0.25 folded in (q comes out pre-scaled).
// ---------------------------------------------------------------------------
__global__ __launch_bounds__(256) void prep_kernel(
    const float* __restrict__ W1, const float* __restrict__ W2,
    const float* __restrict__ Wq, const float* __restrict__ Wmhc,
    const float* __restrict__ Wk, const float* __restrict__ Wv,
    const float* __restrict__ b2, const float* __restrict__ enc,
    __hip_bfloat16* __restrict__ W1t, __hip_bfloat16* __restrict__ Wkvt,
    __hip_bfloat16* __restrict__ Wmt, __hip_bfloat16* __restrict__ Wcat,
    float* __restrict__ bq, __hip_bfloat16* __restrict__ encb)
{
    int bid = blockIdx.x;
    int t = threadIdx.x;
    if (bid < 800) {
        transpose_tile(W1, 640, W1t, 1280, (bid % 40) * 32, (bid / 40) * 32, 1.f);
    } else if (bid < 816) {
        int id = bid - 800;
        transpose_tile(Wk, 128, Wkvt, 128, (id & 3) * 32, (id >> 2) * 32, 1.f);
    } else if (bid < 832) {
        int id = bid - 816;
        transpose_tile(Wv, 128, Wkvt + 128 * 128, 128, (id & 3) * 32, (id >> 2) * 32, 1.f);
    } else if (bid < 848) {
        int id = bid - 832;
        transpose_tile(Wmhc, 128, Wmt, 128, (id & 3) * 32, (id >> 2) * 32, 1.f);
    } else if (bid < 864) {
        int id = bid - 848;
        transpose_tile(Wq, 128, Wcat, 768, (id & 3) * 32, (id >> 2) * 32, 0.25f);
    } else if (bid < 904) {
        int j0 = (bid - 864) * 16;
        int n = t & 127, half = t >> 7;
        #pragma unroll
        for (int jj = 0; jj < 8; ++jj) {
            int j = j0 + half * 8 + jj;
            float acc = 0.f;
            for (int k = 0; k < 128; ++k)
                acc = fmaf(W2[(size_t)j * 128 + k], Wq[(size_t)(128 + k) * 128 + n], acc);
            Wcat[(size_t)n * 768 + 128 + j] = __float2bfloat16(acc * 0.25f);
        }
    } else if (bid < 929) {
        size_t base = (size_t)(bid - 904) * 32768 + (size_t)t * 4;
        #pragma unroll 4
        for (int it = 0; it < 32; ++it) {
            size_t i = base + (size_t)it * 1024;
            float4 v = *(const float4*)(enc + i);
            encb[i + 0] = __float2bfloat16(v.x);
            encb[i + 1] = __float2bfloat16(v.y);
            encb[i + 2] = __float2bfloat16(v.z);
            encb[i + 3] = __float2bfloat16(v.w);
        }
    } else {
        if (t < 128) {
            float acc = 0.f;
            for (int k = 0; k < 128; ++k)
                acc = fmaf(b2[k], Wq[(size_t)(128 + k) * 128 + t], acc);
            bq[t] = acc * 0.25f;
        }
    }
}

// ---------------------------------------------------------------------------
// Kernel 1: kNN top-10 (JAX tie-break) on one wave. Writes aoff, maskbits,
// cur_emb->hq[:,0:128]; mean row only on the block-uniform cold path.
// ---------------------------------------------------------------------------
__global__ __launch_bounds__(64) void knn_kernel(
    const float* __restrict__ dist, const float* __restrict__ mask,
    const int* __restrict__ cur, __hip_bfloat16* __restrict__ encb,
    unsigned* __restrict__ aoff, __hip_bfloat16* __restrict__ hq,
    u64* __restrict__ maskbits)
{
    int br = blockIdx.x;
    int b = br / Rc;
    int t = threadIdx.x;           // 0..63, one wave
    __shared__ int s_idx[Kc];

    int c = cur[br];
    const float* drow = dist + ((size_t)b * Nc + c) * Nc;
    const float* mrow = mask + (size_t)br * Nc;

    float v[4];
    #pragma unroll
    for (int j = 0; j < 4; ++j) {
        int n = t + 64 * j;
        bool allowed = false;
        float val = INFINITY;
        if (n < Nc) {
            float mv = mrow[n];
            if (!isinf(mv)) { val = drow[n]; allowed = true; }
        }
        v[j] = val;
        u64 w = __ballot(allowed);
        if (t == 0) maskbits[(size_t)br * 4 + j] = w;
    }
    unsigned myrow = 0;
    for (int k = 0; k < Kc; ++k) {
        float bv = v[0]; int bn = t;
        #pragma unroll
        for (int j = 1; j < 4; ++j) {
            if (v[j] < bv) { bv = v[j]; bn = t + 64 * j; }
        }
        #pragma unroll
        for (int off = 32; off > 0; off >>= 1) {
            float ov = __shfl_xor(bv, off);
            int   on = __shfl_xor(bn, off);
            if (ov < bv || (ov == bv && on < bn)) { bv = ov; bn = on; }
        }
        bool pad = isinf(bv);
        if (t == 0) s_idx[k] = pad ? Nc : bn;
        if (t == k) myrow = pad ? (unsigned)(Bc * Nc + br) : (unsigned)(b * Nc + bn);
        int oj = bn >> 6, ol = bn & 63;
        if (!pad && t == ol) v[oj] = INFINITY;
    }
    if (t < Kc) aoff[(size_t)br * 16 + t] = myrow << 7;

    // cur_emb -> hq[:,0:128] (bf16 copy, bit-identical to bf16(enc))
    const short* erow = (const short*)encb + ((size_t)b * Nc + c) * Dc;
    short* hrow = (short*)hq + (size_t)br * 768;
    hrow[t] = erow[t];
    hrow[t + 64] = erow[t + 64];

    __syncthreads();
    if (s_idx[Kc - 1] == Nc) {     // block-uniform cold path: pads exist
        float cnt = 0.f;
        #pragma unroll
        for (int k = 0; k < Kc; ++k) cnt += (s_idx[k] < Nc) ? 1.f : 0.f;
        float icnt = 1.f / fmaxf(cnt, 1e-9f);
        #pragma unroll
        for (int half = 0; half < 2; ++half) {
            int d = t + 64 * half;
            float sum = 0.f;
            for (int k = 0; k < Kc; ++k) {
                int idx = s_idx[k];
                if (idx < Nc)
                    sum += __bfloat162float(encb[((size_t)b * Nc + idx) * Dc + d]);
            }
            encb[((size_t)(Bc * Nc) + br) * Dc + d] = __float2bfloat16(sum * icnt);
        }
    }
}

// ---------------------------------------------------------------------------
// Kernel 3: BM=64 x BN=128 bf16 MFMA GEMM. C = A @ Bt^T (+bias). BK=64.
// ---------------------------------------------------------------------------
template<bool HASBIAS, bool OUTBF16>
__global__ __launch_bounds__(256) void mfma_gemm64_kernel(
    const __hip_bfloat16* __restrict__ A, int lda,
    const __hip_bfloat16* __restrict__ Bt, int ldbt, int Kloop,
    const float* __restrict__ bias,
    void* __restrict__ Cout, int ldc, int coff)
{
    __shared__ short Asl[2][64 * 32];
    __shared__ short Bsl[2][128 * 32];
    int tid = threadIdx.x;
    int wave = tid >> 6, lane = tid & 63;
    int m0 = blockIdx.y * 64, n0 = blockIdx.x * 128;

    int lrow = lane >> 2;
    int cg   = lane & 3;
    int ss   = (lane >> 3) & 3;
    int gq   = (cg - ss) & 3;
    const short* Ab = (const short*)A;
    const short* Bb = (const short*)Bt;
    const short* gA0 = Ab + (size_t)(m0 + (wave & 1) * 32 + lrow) * lda + gq * 8;
    const short* gA1 = gA0 + (size_t)16 * lda;
    const short* gB0 = Bb + (size_t)(n0 + wave * 32 + lrow) * ldbt + gq * 8;
    const short* gB1 = gB0 + (size_t)16 * ldbt;

    int wm = wave >> 1, wn = wave & 1;
    int rrow = lane & 15, quad = lane >> 4;
    int srd  = (rrow >> 1) & 3;

    f32x4 acc[2][4];
    #pragma unroll
    for (int i = 0; i < 2; ++i)
        #pragma unroll
        for (int j = 0; j < 4; ++j)
            acc[i][j] = (f32x4){0.f, 0.f, 0.f, 0.f};

    for (int k0 = 0; k0 < Kloop; k0 += 64) {
        __syncthreads();
        #pragma unroll
        for (int s = 0; s < 2; ++s) {
            if (wave < 2) {
                GLOAD_LDS16(gA0 + k0 + s * 32, &Asl[s][(wave * 32) * 32]);
                GLOAD_LDS16(gA1 + k0 + s * 32, &Asl[s][(wave * 32 + 16) * 32]);
            }
            GLOAD_LDS16(gB0 + k0 + s * 32, &Bsl[s][(wave * 32) * 32]);
            GLOAD_LDS16(gB1 + k0 + s * 32, &Bsl[s][(wave * 32 + 16) * 32]);
        }
        __syncthreads();
        #pragma unroll
        for (int s = 0; s < 2; ++s) {
            short8 afr[2], bfr[4];
            #pragma unroll
            for (int mt = 0; mt < 2; ++mt) {
                int rowa = wm * 32 + mt * 16 + rrow;
                afr[mt] = *(const short8*)&Asl[s][rowa * 32 + ((quad + srd) & 3) * 8];
            }
            #pragma unroll
            for (int nt = 0; nt < 4; ++nt) {
                int rowb = wn * 64 + nt * 16 + rrow;
                bfr[nt] = *(const short8*)&Bsl[s][rowb * 32 + ((quad + srd) & 3) * 8];
            }
            #pragma unroll
            for (int mt = 0; mt < 2; ++mt)
                #pragma unroll
                for (int nt = 0; nt < 4; ++nt)
                    acc[mt][nt] = __builtin_amdgcn_mfma_f32_16x16x32_bf16(
                        afr[mt], bfr[nt], acc[mt][nt], 0, 0, 0);
        }
    }

    #pragma unroll
    for (int mt = 0; mt < 2; ++mt) {
        #pragma unroll
        for (int nt = 0; nt < 4; ++nt) {
            int n = wn * 64 + nt * 16 + rrow;
            float bv = HASBIAS ? bias[n0 + n] : 0.f;
            #pragma unroll
            for (int i = 0; i < 4; ++i) {
                int m = m0 + wm * 32 + mt * 16 + quad * 4 + i;
                float vv = acc[mt][nt][i] + bv;
                size_t off = (size_t)m * ldc + coff + n0 + n;
                if (OUTBF16) ((__hip_bfloat16*)Cout)[off] = __float2bfloat16(vv);
                else         ((float*)Cout)[off] = vv;
            }
        }
    }
}

// ---------------------------------------------------------------------------
// Kernel 2: GEMM1 hq[:,128:768] = relu(gather(encb) @ W1t^T + b1).
// BM=64 gather GEMM; K=1280 fully unrolled; BK=64.
// ---------------------------------------------------------------------------
__global__ __launch_bounds__(256) void gemm1_kernel(
    const __hip_bfloat16* __restrict__ encb, const unsigned* __restrict__ aoff,
    const __hip_bfloat16* __restrict__ W1t, const float* __restrict__ b1,
    __hip_bfloat16* __restrict__ hq)
{
    __shared__ short Asl[2][64 * 32];
    __shared__ short Bsl[2][128 * 32];
    int tid = threadIdx.x;
    int wave = tid >> 6, lane = tid & 63;
    int m0 = blockIdx.y * 64, n0 = blockIdx.x * 128;

    int lrow = lane >> 2;
    int cg   = lane & 3;
    int ss   = (lane >> 3) & 3;
    int gq   = (cg - ss) & 3;

    unsigned o0[Kc], o1[Kc];
    {
        const unsigned* ap0 = aoff + (size_t)(m0 + (wave & 1) * 32 + lrow) * 16;
        const unsigned* ap1 = ap0 + 16 * 16;
        #pragma unroll
        for (int j = 0; j < Kc; ++j) { o0[j] = ap0[j]; o1[j] = ap1[j]; }
    }
    const short* Eb = (const short*)encb;
    const short* Bb = (const short*)W1t;
    const short* gB0 = Bb + (size_t)(n0 + wave * 32 + lrow) * 1280 + gq * 8;
    const short* gB1 = gB0 + (size_t)16 * 1280;

    int wm = wave >> 1, wn = wave & 1;
    int rrow = lane & 15, quad = lane >> 4;
    int srd  = (rrow >> 1) & 3;

    f32x4 acc[2][4];
    #pragma unroll
    for (int i = 0; i < 2; ++i)
        #pragma unroll
        for (int j = 0; j < 4; ++j)
            acc[i][j] = (f32x4){0.f, 0.f, 0.f, 0.f};

    #pragma unroll
    for (int kt = 0; kt < 20; ++kt) {
        int k0 = kt * 64;
        int slot = kt >> 1;
        int dbase = (kt & 1) * 64 + gq * 8;
        __syncthreads();
        #pragma unroll
        for (int s = 0; s < 2; ++s) {
            if (wave < 2) {
                GLOAD_LDS16(Eb + o0[slot] + dbase + s * 32, &Asl[s][(wave * 32) * 32]);
                GLOAD_LDS16(Eb + o1[slot] + dbase + s * 32, &Asl[s][(wave * 32 + 16) * 32]);
            }
            GLOAD_LDS16(gB0 + k0 + s * 32, &Bsl[s][(wave * 32) * 32]);
            GLOAD_LDS16(gB1 + k0 + s * 32, &Bsl[s][(wave * 32 + 16) * 32]);
        }
        __syncthreads();
        #pragma unroll
        for (int s = 0; s < 2; ++s) {
            short8 afr[2], bfr[4];
            #pragma unroll
            for (int mt = 0; mt < 2; ++mt) {
                int rowa = wm * 32 + mt * 16 + rrow;
                afr[mt] = *(const short8*)&Asl[s][rowa * 32 + ((quad + srd) & 3) * 8];
            }
            #pragma unroll
            for (int nt = 0; nt < 4; ++nt) {
                int rowb = wn * 64 + nt * 16 + rrow;
                bfr[nt] = *(const short8*)&Bsl[s][rowb * 32 + ((quad + srd) & 3) * 8];
            }
            #pragma unroll
            for (int mt = 0; mt < 2; ++mt)
                #pragma unroll
                for (int nt = 0; nt < 4; ++nt)
                    acc[mt][nt] = __builtin_amdgcn_mfma_f32_16x16x32_bf16(
                        afr[mt], bfr[nt], acc[mt][nt], 0, 0, 0);
        }
    }

    #pragma unroll
    for (int mt = 0; mt < 2; ++mt) {
        #pragma unroll
        for (int nt = 0; nt < 4; ++nt) {
            int n = wn * 64 + nt * 16 + rrow;
            float bv = b1[n0 + n];
            #pragma unroll
            for (int i = 0; i < 4; ++i) {
                int m = m0 + wm * 32 + mt * 16 + quad * 4 + i;
                float vv = fmaxf(acc[mt][nt][i] + bv, 0.f);
                hq[(size_t)m * 768 + 128 + n0 + n] = __float2bfloat16(vv);
            }
        }
    }
}

// ---------------------------------------------------------------------------
// Kernel 4: MFMA flash attention, one block per (b,h), 4 waves.
// ---------------------------------------------------------------------------
__global__ __launch_bounds__(256) void attn_mfma_kernel(
    const __hip_bfloat16* __restrict__ q, const __hip_bfloat16* __restrict__ kvf,
    const u64* __restrict__ maskbits, __hip_bfloat16* __restrict__ att)
{
    constexpr int RP = 208;
    constexpr int QS = 40;
    constexpr int VS = 232;
    __shared__ short Qs[RP * QS];
    __shared__ short Ks[RP * QS];
    __shared__ short Vt[16 * VS];
    __shared__ short Ps[4][16 * VS];
    __shared__ u64 smask[RP][4];

    int b = blockIdx.x >> 3, h = blockIdx.x & 7;
    int t = threadIdx.x;
    int wave = t >> 6, lane = t & 63;
    int rrow = lane & 15, quad = lane >> 4;

    const short8 z8 = {0, 0, 0, 0, 0, 0, 0, 0};
    for (int idx = t; idx < RP * 2; idx += 256) {
        int r = idx >> 1, g = idx & 1;
        short8 qa = z8, ka = z8;
        if (r < Rc) {
            qa = *(const short8*)((const short*)q + ((size_t)(b * Rc + r)) * 128 + h * 16 + g * 8);
            ka = *(const short8*)((const short*)kvf + ((size_t)(b * Nc + r)) * 256 + h * 16 + g * 8);
        }
        *(short8*)&Qs[r * QS + g * 8] = qa;
        *(short8*)&Ks[r * QS + g * 8] = ka;
        *(short8*)&Qs[r * QS + 16 + g * 8] = z8;
        *(short8*)&Ks[r * QS + 16 + g * 8] = z8;
    }
    if (t < Rc) {
        const short* vp = (const short*)kvf + ((size_t)(b * Nc + t)) * 256 + 128 + h * 16;
        short8 v0 = *(const short8*)vp;
        short8 v1 = *(const short8*)(vp + 8);
        #pragma unroll
        for (int d = 0; d < 8; ++d) Vt[d * VS + t] = v0[d];
        #pragma unroll
        for (int d = 0; d < 8; ++d) Vt[(d + 8) * VS + t] = v1[d];
    }
    for (int idx = t; idx < 16 * 32; idx += 256) {
        int d = idx >> 5, cN = 200 + (idx & 31);
        if (cN < VS) Vt[d * VS + cN] = 0;
    }
    for (int idx = lane; idx < 16 * 16; idx += 64) {
        int rr = idx >> 4, cc = 208 + (idx & 15);
        Ps[wave][rr * VS + cc] = 0;
    }
    for (int idx = t; idx < RP * 4; idx += 256) {
        int r = idx >> 2, w = idx & 3;
        smask[r][w] = (r < Rc) ? maskbits[((size_t)b * Rc + r) * 4 + w] : ~0ull;
    }
    __syncthreads();

    for (int rt = wave; rt < 13; rt += 4) {
        short8 qf = *(const short8*)&Qs[(rt * 16 + rrow) * QS + quad * 8];
        f32x4 sacc[13];
        #pragma unroll
        for (int nt = 0; nt < 13; ++nt) {
            short8 kf = *(const short8*)&Ks[(nt * 16 + rrow) * QS + quad * 8];
            sacc[nt] = __builtin_amdgcn_mfma_f32_16x16x32_bf16(
                qf, kf, (f32x4){0.f, 0.f, 0.f, 0.f}, 0, 0, 0);
        }
        float inv[4];
        #pragma unroll
        for (int i = 0; i < 4; ++i) {
            int r = rt * 16 + quad * 4 + i;
            u64 wv0 = smask[r][0], wv1 = smask[r][1], wv2 = smask[r][2], wv3 = smask[r][3];
            float mx = -INFINITY;
            #pragma unroll
            for (int nt = 0; nt < 13; ++nt) {
                u64 w = (nt < 4) ? wv0 : (nt < 8) ? wv1 : (nt < 12) ? wv2 : wv3;
                int sh = ((nt & 3) << 4) + rrow;
                float s = ((w >> sh) & 1ull) ? sacc[nt][i] : -INFINITY;
                sacc[nt][i] = s;
                mx = fmaxf(mx, s);
            }
            mx = fmaxf(mx, __shfl_xor(mx, 1));
            mx = fmaxf(mx, __shfl_xor(mx, 2));
            mx = fmaxf(mx, __shfl_xor(mx, 4));
            mx = fmaxf(mx, __shfl_xor(mx, 8));
            float l = 0.f;
            #pragma unroll
            for (int nt = 0; nt < 13; ++nt) {
                float p = __expf(sacc[nt][i] - mx);
                sacc[nt][i] = p;
                l += p;
            }
            l += __shfl_xor(l, 1);
            l += __shfl_xor(l, 2);
            l += __shfl_xor(l, 4);
            l += __shfl_xor(l, 8);
            inv[i] = (l > 0.f) ? 1.f / l : 0.f;
        }
        #pragma unroll
        for (int nt = 0; nt < 13; ++nt)
            #pragma unroll
            for (int i = 0; i < 4; ++i)
                *(__hip_bfloat16*)&Ps[wave][(quad * 4 + i) * VS + nt * 16 + rrow] =
                    __float2bfloat16(sacc[nt][i]);
        f32x4 oacc = (f32x4){0.f, 0.f, 0.f, 0.f};
        #pragma unroll
        for (int kt = 0; kt < 7; ++kt) {
            short8 pf = *(const short8*)&Ps[wave][rrow * VS + kt * 32 + quad * 8];
            short8 vf = *(const short8*)&Vt[rrow * VS + kt * 32 + quad * 8];
            oacc = __builtin_amdgcn_mfma_f32_16x16x32_bf16(pf, vf, oacc, 0, 0, 0);
        }
        #pragma unroll
        for (int i = 0; i < 4; ++i) {
            int r = rt * 16 + quad * 4 + i;
            if (r < Rc)
                att[((size_t)(b * Rc + r)) * 128 + h * 16 + rrow] =
                    __float2bfloat16(oacc[i] * inv[i]);
        }
    }
}

// ---------------------------------------------------------------------------
// Kernel 5: logits = 10*tanh((mh @ enc^T)/sqrt(128)) masked via maskbits.
// ---------------------------------------------------------------------------
__global__ __launch_bounds__(256) void logits_mfma_kernel(
    const __hip_bfloat16* __restrict__ mh, const __hip_bfloat16* __restrict__ encb,
    const u64* __restrict__ maskbits, float* __restrict__ out)
{
    __shared__ short Asl[128 * 32];
    __shared__ short Bsl[128 * 32];
    __shared__ u64 sm[128][4];
    int b = blockIdx.x;
    int m0 = blockIdx.y * 128;
    int n0 = blockIdx.z * 128;
    int tid = threadIdx.x;
    int wave = tid >> 6, lane = tid & 63;

    for (int idx = tid; idx < 512; idx += 256) {
        int r = idx >> 2, w = idx & 3;
        int gr = m0 + r;
        sm[r][w] = (gr < Rc) ? maskbits[((size_t)b * Rc + gr) * 4 + w] : 0ull;
    }

    int lrow = lane >> 2;
    int cg   = lane & 3;
    int ss   = (lane >> 3) & 3;
    int gq   = (cg - ss) & 3;
    const short* Ab = (const short*)(mh + (size_t)b * Rc * 128);
    const short* Bb = (const short*)(encb + (size_t)b * Nc * 128);
    const short* gA0 = Ab + (size_t)(m0 + wave * 32 + lrow) * 128 + gq * 8;
    const short* gA1 = gA0 + (size_t)16 * 128;
    const short* gB0 = Bb + (size_t)(n0 + wave * 32 + lrow) * 128 + gq * 8;
    const short* gB1 = gB0 + (size_t)16 * 128;
    short* lA0 = &Asl[(wave * 32) * 32];
    short* lA1 = &Asl[(wave * 32 + 16) * 32];
    short* lB0 = &Bsl[(wave * 32) * 32];
    short* lB1 = &Bsl[(wave * 32 + 16) * 32];

    int wm = wave >> 1, wn = wave & 1;
    int rrow = lane & 15, quad = lane >> 4;
    int srd  = (rrow >> 1) & 3;

    f32x4 acc[4][4];
    #pragma unroll
    for (int i = 0; i < 4; ++i)
        #pragma unroll
        for (int j = 0; j < 4; ++j)
            acc[i][j] = (f32x4){0.f, 0.f, 0.f, 0.f};

    for (int k0 = 0; k0 < 128; k0 += 32) {
        __syncthreads();
        GLOAD_LDS16(gA0 + k0, lA0);
        GLOAD_LDS16(gA1 + k0, lA1);
        GLOAD_LDS16(gB0 + k0, lB0);
        GLOAD_LDS16(gB1 + k0, lB1);
        __syncthreads();
        short8 afr[4], bfr[4];
        #pragma unroll
        for (int mt = 0; mt < 4; ++mt) {
            int rowa = wm * 64 + mt * 16 + rrow;
            afr[mt] = *(const short8*)&Asl[rowa * 32 + ((quad + srd) & 3) * 8];
            int rowb = wn * 64 + mt * 16 + rrow;
            bfr[mt] = *(const short8*)&Bsl[rowb * 32 + ((quad + srd) & 3) * 8];
        }
        #pragma unroll
        for (int mt = 0; mt < 4; ++mt)
            #pragma unroll
            for (int nt = 0; nt < 4; ++nt)
                acc[mt][nt] = __builtin_amdgcn_mfma_f32_16x16x32_bf16(
                    afr[mt], bfr[nt], acc[mt][nt], 0, 0, 0);
    }

    const float scale = 0.08838834764831843f;
    #pragma unroll
    for (int mt = 0; mt < 4; ++mt) {
        #pragma unroll
        for (int nt = 0; nt < 4; ++nt) {
            int n = n0 + wn * 64 + nt * 16 + rrow;
            #pragma unroll
            for (int i = 0; i < 4; ++i) {
                int r = m0 + wm * 64 + mt * 16 + quad * 4 + i;
                if (r < Rc && n < Nc) {
                    u64 w = sm[r - m0][n >> 6];
                    float lg = ((w >> (n & 63)) & 1ull)
                             ? 10.f * tanhf(acc[mt][nt][i] * scale) : -INFINITY;
                    out[((size_t)b * Rc + r) * Nc + n] = lg;
                }
            }
        }
    }
}

// ---------------------------------------------------------------------------
// Kernel 6: row softmax over N=200, in place.
// ---------------------------------------------------------------------------
__global__ __launch_bounds__(64) void softmax_kernel(float* __restrict__ out)
{
    int br = blockIdx.x;
    float* row = out + (size_t)br * Nc;
    int t = threadIdx.x;
    float v[4]; float m = -INFINITY;
    #pragma unroll
    for (int j = 0; j < 4; ++j) {
        int n = t + 64 * j;
        v[j] = (n < Nc) ? row[n] : -INFINITY;
        m = fmaxf(m, v[j]);
    }
    #pragma unroll
    for (int off = 32; off > 0; off >>= 1) m = fmaxf(m, __shfl_xor(m, off));
    float e[4]; float s = 0.f;
    #pragma unroll
    for (int j = 0; j < 4; ++j) {
        e[j] = (v[j] == -INFINITY) ? 0.f : expf(v[j] - m);
        s += e[j];
    }
    #pragma unroll
    for (int off = 32; off > 0; off >>= 1) s += __shfl_xor(s, off);
    float inv = 1.f / s;
    #pragma unroll
    for (int j = 0; j < 4; ++j) {
        int n = t + 64 * j;
        if (n < Nc) row[n] = e[j] * inv;
    }
}

// ---------------------------------------------------------------------------
extern "C" void kernel_launch(void* const* d_in, const int* in_sizes, int n_in,
                              void* d_out, int out_size, void* d_ws, size_t ws_size,
                              hipStream_t stream)
{
    const float* enc  = (const float*)d_in[0];
    const float* dist = (const float*)d_in[1];
    const float* mask = (const float*)d_in[2];
    const int*   cur  = (const int*)d_in[3];
    const float* Wq   = (const float*)d_in[4];
    const float* Wk   = (const float*)d_in[5];
    const float* Wv   = (const float*)d_in[6];
    const float* Wmhc = (const float*)d_in[7];
    const float* bmhc = (const float*)d_in[8];
    const float* W1   = (const float*)d_in[9];
    const float* b1   = (const float*)d_in[10];
    const float* W2   = (const float*)d_in[11];
    const float* b2   = (const float*)d_in[12];
    float* out = (float*)d_out;

    char* ws = (char*)d_ws;
    size_t off = 0;
    auto alloc = [&](size_t bytes) { char* p = ws + off; off += (bytes + 255) & ~(size_t)255; return p; };
    __hip_bfloat16* W1t  = (__hip_bfloat16*)alloc((size_t)640 * 1280 * 2);
    __hip_bfloat16* Wkvt = (__hip_bfloat16*)alloc((size_t)256 * 128 * 2);
    __hip_bfloat16* Wmt  = (__hip_bfloat16*)alloc((size_t)128 * 128 * 2);
    __hip_bfloat16* Wcat = (__hip_bfloat16*)alloc((size_t)128 * 768 * 2);
    float* bq = (float*)alloc((size_t)128 * 4);
    // encb: rows [0, Bc*Nc) = enc bf16; rows [Bc*Nc, Bc*Nc+BRc) = mean rows
    __hip_bfloat16* encb = (__hip_bfloat16*)alloc((size_t)(Bc * Nc + BRc + 64) * Dc * 2);
    unsigned* aoff = (unsigned*)alloc((size_t)BRc * 16 * 4);
    __hip_bfloat16* hq   = (__hip_bfloat16*)alloc((size_t)BRc * 768 * 2);
    __hip_bfloat16* q    = (__hip_bfloat16*)alloc((size_t)BRc * 128 * 2);
    __hip_bfloat16* kvf  = (__hip_bfloat16*)alloc((size_t)Bc * Nc * 256 * 2);
    __hip_bfloat16* att  = (__hip_bfloat16*)alloc((size_t)BRc * 128 * 2);
    __hip_bfloat16* mh   = (__hip_bfloat16*)alloc((size_t)(BRc + 64) * 128 * 2);
    u64* maskbits = (u64*)alloc((size_t)BRc * 4 * 8);

    // 1) weight preprocessing
    prep_kernel<<<930, 256, 0, stream>>>(W1, W2, Wq, Wmhc, Wk, Wv, b2, enc,
                                         W1t, Wkvt, Wmt, Wcat, bq, encb);
    // 2) kNN select -> aoff/maskbits/cur_emb (+mean rows only if pads exist)
    knn_kernel<<<BRc, 64, 0, stream>>>(dist, mask, cur, encb, aoff, hq, maskbits);
    // 3) kvf = enc @ [Wk|Wv]      grid (2,100)
    mfma_gemm64_kernel<false, true><<<dim3(2, (Bc * Nc) / 64), 256, 0, stream>>>(
        encb, 128, Wkvt, 128, 128, nullptr, kvf, 256, 0);
    // 4) hq[:,128:768] = relu(gather(encb) @ W1t^T + b1)   grid (5,100)
    gemm1_kernel<<<dim3(5, BRc / 64), 256, 0, stream>>>(encb, aoff, W1t, b1, hq);
    // 5) q = hq @ Wcat^T + bq  (pre-scaled, bf16)   grid (1,100)
    mfma_gemm64_kernel<true, true><<<dim3(1, BRc / 64), 256, 0, stream>>>(
        hq, 768, Wcat, 768, 768, bq, q, 128, 0);
    // 6) MFMA flash attention
    attn_mfma_kernel<<<Bc * Hc, 256, 0, stream>>>(q, kvf, maskbits, att);
    // 7) mh = att @ Wmhc + b_mhc (bf16 out)   grid (1,100)
    mfma_gemm64_kernel<true, true><<<dim3(1, BRc / 64), 256, 0, stream>>>(
        att, 128, Wmt, 128, 128, bmhc, mh, 128, 0);
    // 8) logits (MFMA, 128 blocks) + maskbits epilogue
    logits_mfma_kernel<<<dim3(Bc, 2, 2), 256, 0, stream>>>(mh, encb, maskbits, out);
    // 9) softmax (6400 blocks)
    softmax_kernel<<<BRc, 64, 0, stream>>>(out);
}

// Round 12
// 187.545 us; speedup vs baseline: 1.3328x; 1.0847x over previous
//
#include <hip/hip_runtime.h>
#include <hip/hip_bf16.h>
#include <math.h>

#define Bc 32
#define Rc 200
#define Nc 200
#define Dc 128
#define Hc 8
#define QKc 16
#define Kc 10
#define BRc (Bc*Rc)

typedef __attribute__((ext_vector_type(8))) short short8;
typedef __attribute__((ext_vector_type(4))) float f32x4;
typedef unsigned long long u64;

#define GLOAD_LDS16(g, l) __builtin_amdgcn_global_load_lds( \
    (const __attribute__((address_space(1))) void*)(g), \
    (__attribute__((address_space(3))) void*)(l), 16, 0, 0)

// ---------------------------------------------------------------------------
// 32x32 transpose+convert tile helper (block-uniform call sites only)
// ---------------------------------------------------------------------------
__device__ inline void transpose_tile(const float* __restrict__ src, int lds_,
                                      __hip_bfloat16* __restrict__ dst, int ldd,
                                      int k0, int n0, float scale)
{
    __shared__ float tile[32][33];
    int tx = threadIdx.x & 31, ty = threadIdx.x >> 5;  // 32 x 8
    #pragma unroll
    for (int i = ty; i < 32; i += 8)
        tile[i][tx] = src[(size_t)(k0 + i) * lds_ + n0 + tx];
    __syncthreads();
    #pragma unroll
    for (int i = ty; i < 32; i += 8)
        dst[(size_t)(n0 + i) * ldd + k0 + tx] = __float2bfloat16(tile[tx][i] * scale);
}

// ---------------------------------------------------------------------------
// Kernel 1: prep + kNN fused (independent roles, one launch).
//  [0,800)    W1 -> W1t (transpose, bf16)
//  [800,816)  Wk -> Wkvt[0:128]
//  [816,832)  Wv -> Wkvt[128:256]
//  [832,848)  Wmhc -> Wmb (straight bf16 convert, NO transpose)
//  [848,864)  Wq top -> Wcat[:,0:128] (x0.25)
//  [864,904)  Wfused = W2 @ Wq_bot (fp32) -> Wcat[:,128:768] (x0.25)
//  [904,929)  enc fp32 -> encb bf16
//  [929]      bq
//  [930,2530) kNN: wave-per-row, register-only butterfly top-10.
// ---------------------------------------------------------------------------
__global__ __launch_bounds__(256) void prep_knn_kernel(
    const float* __restrict__ W1, const float* __restrict__ W2,
    const float* __restrict__ Wq, const float* __restrict__ Wmhc,
    const float* __restrict__ Wk, const float* __restrict__ Wv,
    const float* __restrict__ b2, const float* __restrict__ enc,
    const float* __restrict__ dist, const float* __restrict__ mask,
    const int* __restrict__ cur,
    __hip_bfloat16* __restrict__ W1t, __hip_bfloat16* __restrict__ Wkvt,
    __hip_bfloat16* __restrict__ Wmb, __hip_bfloat16* __restrict__ Wcat,
    float* __restrict__ bq, __hip_bfloat16* __restrict__ encb,
    unsigned* __restrict__ aoff, __hip_bfloat16* __restrict__ hq,
    u64* __restrict__ maskbits)
{
    int bid = blockIdx.x;
    int t = threadIdx.x;
    if (bid < 800) {
        transpose_tile(W1, 640, W1t, 1280, (bid % 40) * 32, (bid / 40) * 32, 1.f);
    } else if (bid < 816) {
        int id = bid - 800;
        transpose_tile(Wk, 128, Wkvt, 128, (id & 3) * 32, (id >> 2) * 32, 1.f);
    } else if (bid < 832) {
        int id = bid - 816;
        transpose_tile(Wv, 128, Wkvt + 128 * 128, 128, (id & 3) * 32, (id >> 2) * 32, 1.f);
    } else if (bid < 848) {
        int e = (bid - 832) * 1024 + t * 4;
        #pragma unroll
        for (int j = 0; j < 4; ++j) Wmb[e + j] = __float2bfloat16(Wmhc[e + j]);
    } else if (bid < 864) {
        int id = bid - 848;
        transpose_tile(Wq, 128, Wcat, 768, (id & 3) * 32, (id >> 2) * 32, 0.25f);
    } else if (bid < 904) {
        int j0 = (bid - 864) * 16;
        int n = t & 127, half = t >> 7;
        #pragma unroll
        for (int jj = 0; jj < 8; ++jj) {
            int j = j0 + half * 8 + jj;
            float acc = 0.f;
            for (int k = 0; k < 128; ++k)
                acc = fmaf(W2[(size_t)j * 128 + k], Wq[(size_t)(128 + k) * 128 + n], acc);
            Wcat[(size_t)n * 768 + 128 + j] = __float2bfloat16(acc * 0.25f);
        }
    } else if (bid < 929) {
        size_t base = (size_t)(bid - 904) * 32768 + (size_t)t * 4;
        #pragma unroll 4
        for (int it = 0; it < 32; ++it) {
            size_t i = base + (size_t)it * 1024;
            float4 v = *(const float4*)(enc + i);
            encb[i + 0] = __float2bfloat16(v.x);
            encb[i + 1] = __float2bfloat16(v.y);
            encb[i + 2] = __float2bfloat16(v.z);
            encb[i + 3] = __float2bfloat16(v.w);
        }
    } else if (bid == 929) {
        if (t < 128) {
            float acc = 0.f;
            for (int k = 0; k < 128; ++k)
                acc = fmaf(b2[k], Wq[(size_t)(128 + k) * 128 + t], acc);
            bq[t] = acc * 0.25f;
        }
    } else {
        // kNN role: wave-per-row, register-only
        int lane = t & 63, w = t >> 6;
        int br = (bid - 930) * 4 + w;
        int b = br / Rc;
        int c = cur[br];
        const float* drow = dist + ((size_t)b * Nc + c) * Nc;
        const float* mrow = mask + (size_t)br * Nc;

        float v[4];
        #pragma unroll
        for (int j = 0; j < 4; ++j) {
            int n = lane + 64 * j;
            bool allowed = false;
            float val = INFINITY;
            if (n < Nc) {
                float mv = mrow[n];
                if (!isinf(mv)) { val = drow[n]; allowed = true; }
            }
            v[j] = val;
            u64 wb = __ballot(allowed);
            if (lane == 0) maskbits[(size_t)br * 4 + j] = wb;
        }
        int idxs[Kc];
        unsigned myrow = 0;
        #pragma unroll
        for (int k = 0; k < Kc; ++k) {
            float bv = v[0]; int bn = lane;
            #pragma unroll
            for (int j = 1; j < 4; ++j) {
                if (v[j] < bv) { bv = v[j]; bn = lane + 64 * j; }
            }
            #pragma unroll
            for (int off = 32; off > 0; off >>= 1) {
                float ov = __shfl_xor(bv, off);
                int   on = __shfl_xor(bn, off);
                if (ov < bv || (ov == bv && on < bn)) { bv = ov; bn = on; }
            }
            bool pad = isinf(bv);
            idxs[k] = pad ? Nc : bn;
            if (lane == k) myrow = pad ? (unsigned)(Bc * Nc + br) : (unsigned)(b * Nc + bn);
            int oj = bn >> 6, ol = bn & 63;
            if (!pad && lane == ol) v[oj] = INFINITY;
        }
        if (lane < Kc) aoff[(size_t)br * 16 + lane] = myrow << 7;

        // cur_emb -> hq[:,0:128] (same bits as bf16(enc))
        const float* erow = enc + ((size_t)b * Nc + c) * Dc;
        __hip_bfloat16* hrow = hq + (size_t)br * 768;
        hrow[lane]      = __float2bfloat16(erow[lane]);
        hrow[lane + 64] = __float2bfloat16(erow[lane + 64]);

        if (idxs[Kc - 1] == Nc) {   // wave-uniform cold path: pads exist
            float cnt = 0.f;
            #pragma unroll
            for (int k = 0; k < Kc; ++k) cnt += (idxs[k] < Nc) ? 1.f : 0.f;
            float icnt = 1.f / fmaxf(cnt, 1e-9f);
            #pragma unroll
            for (int half = 0; half < 2; ++half) {
                int d = lane + 64 * half;
                float sum = 0.f;
                #pragma unroll
                for (int k = 0; k < Kc; ++k) {
                    if (idxs[k] < Nc)
                        sum += enc[((size_t)b * Nc + idxs[k]) * Dc + d];
                }
                encb[((size_t)(Bc * Nc) + br) * Dc + d] = __float2bfloat16(sum * icnt);
            }
        }
    }
}

// ---------------------------------------------------------------------------
// Kernel 2: all independent mid-pipeline GEMMs in ONE launch (825 blocks):
//  [0,500)   gemm1: hq[:,128:768] = relu(gather(encb) @ W1t^T + b1), K=1280
//  [500,700) kvf = encb @ [Wk|Wv]^T          (K=128)
//  [700,800) em  = encb @ Wmb^T  (= enc@Wmhc^T, replaces the mh GEMM)
//  [800,825) be[i] = bmhc . enc[i]  (fp32 dot per thread, 6400 rows)
// ---------------------------------------------------------------------------
__global__ __launch_bounds__(256) void fused_gemms_kernel(
    const __hip_bfloat16* __restrict__ encb, const unsigned* __restrict__ aoff,
    const __hip_bfloat16* __restrict__ W1t, const float* __restrict__ b1,
    const __hip_bfloat16* __restrict__ Wkvt, const __hip_bfloat16* __restrict__ Wmb,
    const float* __restrict__ bmhc, const float* __restrict__ enc,
    __hip_bfloat16* __restrict__ hq, __hip_bfloat16* __restrict__ kvf,
    __hip_bfloat16* __restrict__ em, float* __restrict__ be)
{
    __shared__ short Asl[2][64 * 32];
    __shared__ short Bsl[2][128 * 32];
    int bid = blockIdx.x;
    int tid = threadIdx.x;
    int wave = tid >> 6, lane = tid & 63;
    int lrow = lane >> 2;
    int cg   = lane & 3;
    int ss   = (lane >> 3) & 3;
    int gq   = (cg - ss) & 3;
    int wm = wave >> 1, wn = wave & 1;
    int rrow = lane & 15, quad = lane >> 4;
    int srd  = (rrow >> 1) & 3;

    if (bid < 500) {
        // ---- gemm1 (gather A, K=1280 fully unrolled)
        int m0 = (bid / 5) * 64, n0 = (bid % 5) * 128;
        unsigned o0[Kc], o1[Kc];
        {
            const unsigned* ap0 = aoff + (size_t)(m0 + (wave & 1) * 32 + lrow) * 16;
            const unsigned* ap1 = ap0 + 16 * 16;
            #pragma unroll
            for (int j = 0; j < Kc; ++j) { o0[j] = ap0[j]; o1[j] = ap1[j]; }
        }
        const short* Eb = (const short*)encb;
        const short* Bb = (const short*)W1t;
        const short* gB0 = Bb + (size_t)(n0 + wave * 32 + lrow) * 1280 + gq * 8;
        const short* gB1 = gB0 + (size_t)16 * 1280;

        f32x4 acc[2][4];
        #pragma unroll
        for (int i = 0; i < 2; ++i)
            #pragma unroll
            for (int j = 0; j < 4; ++j)
                acc[i][j] = (f32x4){0.f, 0.f, 0.f, 0.f};

        #pragma unroll
        for (int kt = 0; kt < 20; ++kt) {
            int k0 = kt * 64;
            int slot = kt >> 1;
            int dbase = (kt & 1) * 64 + gq * 8;
            __syncthreads();
            #pragma unroll
            for (int s = 0; s < 2; ++s) {
                if (wave < 2) {
                    GLOAD_LDS16(Eb + o0[slot] + dbase + s * 32, &Asl[s][(wave * 32) * 32]);
                    GLOAD_LDS16(Eb + o1[slot] + dbase + s * 32, &Asl[s][(wave * 32 + 16) * 32]);
                }
                GLOAD_LDS16(gB0 + k0 + s * 32, &Bsl[s][(wave * 32) * 32]);
                GLOAD_LDS16(gB1 + k0 + s * 32, &Bsl[s][(wave * 32 + 16) * 32]);
            }
            __syncthreads();
            #pragma unroll
            for (int s = 0; s < 2; ++s) {
                short8 afr[2], bfr[4];
                #pragma unroll
                for (int mt = 0; mt < 2; ++mt)
                    afr[mt] = *(const short8*)&Asl[s][(wm * 32 + mt * 16 + rrow) * 32 + ((quad + srd) & 3) * 8];
                #pragma unroll
                for (int nt = 0; nt < 4; ++nt)
                    bfr[nt] = *(const short8*)&Bsl[s][(wn * 64 + nt * 16 + rrow) * 32 + ((quad + srd) & 3) * 8];
                #pragma unroll
                for (int mt = 0; mt < 2; ++mt)
                    #pragma unroll
                    for (int nt = 0; nt < 4; ++nt)
                        acc[mt][nt] = __builtin_amdgcn_mfma_f32_16x16x32_bf16(
                            afr[mt], bfr[nt], acc[mt][nt], 0, 0, 0);
            }
        }
        #pragma unroll
        for (int mt = 0; mt < 2; ++mt)
            #pragma unroll
            for (int nt = 0; nt < 4; ++nt) {
                int n = wn * 64 + nt * 16 + rrow;
                float bv = b1[n0 + n];
                #pragma unroll
                for (int i = 0; i < 4; ++i) {
                    int m = m0 + wm * 32 + mt * 16 + quad * 4 + i;
                    float vv = fmaxf(acc[mt][nt][i] + bv, 0.f);
                    hq[(size_t)m * 768 + 128 + n0 + n] = __float2bfloat16(vv);
                }
            }
    } else if (bid < 800) {
        // ---- kvf or em (K=128, 2 barrier iters)
        const __hip_bfloat16* Bt; __hip_bfloat16* Cout; int ldc, m0, n0;
        if (bid < 700) {
            int id = bid - 500;
            Bt = Wkvt; Cout = kvf; ldc = 256;
            m0 = (id >> 1) * 64; n0 = (id & 1) * 128;
        } else {
            int id = bid - 700;
            Bt = Wmb; Cout = em; ldc = 128;
            m0 = id * 64; n0 = 0;
        }
        const short* Ab = (const short*)encb;
        const short* Bb = (const short*)Bt;
        const short* gA0 = Ab + (size_t)(m0 + (wave & 1) * 32 + lrow) * 128 + gq * 8;
        const short* gA1 = gA0 + (size_t)16 * 128;
        const short* gB0 = Bb + (size_t)(n0 + wave * 32 + lrow) * 128 + gq * 8;
        const short* gB1 = gB0 + (size_t)16 * 128;

        f32x4 acc[2][4];
        #pragma unroll
        for (int i = 0; i < 2; ++i)
            #pragma unroll
            for (int j = 0; j < 4; ++j)
                acc[i][j] = (f32x4){0.f, 0.f, 0.f, 0.f};

        #pragma unroll
        for (int kt = 0; kt < 2; ++kt) {
            int k0 = kt * 64;
            __syncthreads();
            #pragma unroll
            for (int s = 0; s < 2; ++s) {
                if (wave < 2) {
                    GLOAD_LDS16(gA0 + k0 + s * 32, &Asl[s][(wave * 32) * 32]);
                    GLOAD_LDS16(gA1 + k0 + s * 32, &Asl[s][(wave * 32 + 16) * 32]);
                }
                GLOAD_LDS16(gB0 + k0 + s * 32, &Bsl[s][(wave * 32) * 32]);
                GLOAD_LDS16(gB1 + k0 + s * 32, &Bsl[s][(wave * 32 + 16) * 32]);
            }
            __syncthreads();
            #pragma unroll
            for (int s = 0; s < 2; ++s) {
                short8 afr[2], bfr[4];
                #pragma unroll
                for (int mt = 0; mt < 2; ++mt)
                    afr[mt] = *(const short8*)&Asl[s][(wm * 32 + mt * 16 + rrow) * 32 + ((quad + srd) & 3) * 8];
                #pragma unroll
                for (int nt = 0; nt < 4; ++nt)
                    bfr[nt] = *(const short8*)&Bsl[s][(wn * 64 + nt * 16 + rrow) * 32 + ((quad + srd) & 3) * 8];
                #pragma unroll
                for (int mt = 0; mt < 2; ++mt)
                    #pragma unroll
                    for (int nt = 0; nt < 4; ++nt)
                        acc[mt][nt] = __builtin_amdgcn_mfma_f32_16x16x32_bf16(
                            afr[mt], bfr[nt], acc[mt][nt], 0, 0, 0);
            }
        }
        #pragma unroll
        for (int mt = 0; mt < 2; ++mt)
            #pragma unroll
            for (int nt = 0; nt < 4; ++nt) {
                int n = wn * 64 + nt * 16 + rrow;
                #pragma unroll
                for (int i = 0; i < 4; ++i) {
                    int m = m0 + wm * 32 + mt * 16 + quad * 4 + i;
                    Cout[(size_t)m * ldc + n0 + n] = __float2bfloat16(acc[mt][nt][i]);
                }
            }
    } else {
        // ---- be[i] = bmhc . enc[i,:]   (i < Bc*Nc = 6400; 25 blocks)
        int i = (bid - 800) * 256 + tid;
        if (i < Bc * Nc) {
            const float* row = enc + (size_t)i * 128;
            float acc = 0.f;
            #pragma unroll
            for (int dq = 0; dq < 32; ++dq) {
                float4 e4 = *(const float4*)(row + dq * 4);
                acc = fmaf(bmhc[dq * 4 + 0], e4.x, acc);
                acc = fmaf(bmhc[dq * 4 + 1], e4.y, acc);
                acc = fmaf(bmhc[dq * 4 + 2], e4.z, acc);
                acc = fmaf(bmhc[dq * 4 + 3], e4.w, acc);
            }
            be[i] = acc;
        }
    }
}

// ---------------------------------------------------------------------------
// Kernel 3: BM=64 x BN=128 bf16 MFMA GEMM (used for q). C = A @ Bt^T + bias.
// ---------------------------------------------------------------------------
template<bool HASBIAS, bool OUTBF16>
__global__ __launch_bounds__(256) void mfma_gemm64_kernel(
    const __hip_bfloat16* __restrict__ A, int lda,
    const __hip_bfloat16* __restrict__ Bt, int ldbt, int Kloop,
    const float* __restrict__ bias,
    void* __restrict__ Cout, int ldc, int coff)
{
    __shared__ short Asl[2][64 * 32];
    __shared__ short Bsl[2][128 * 32];
    int tid = threadIdx.x;
    int wave = tid >> 6, lane = tid & 63;
    int m0 = blockIdx.y * 64, n0 = blockIdx.x * 128;

    int lrow = lane >> 2;
    int cg   = lane & 3;
    int ss   = (lane >> 3) & 3;
    int gq   = (cg - ss) & 3;
    const short* Ab = (const short*)A;
    const short* Bb = (const short*)Bt;
    const short* gA0 = Ab + (size_t)(m0 + (wave & 1) * 32 + lrow) * lda + gq * 8;
    const short* gA1 = gA0 + (size_t)16 * lda;
    const short* gB0 = Bb + (size_t)(n0 + wave * 32 + lrow) * ldbt + gq * 8;
    const short* gB1 = gB0 + (size_t)16 * ldbt;

    int wm = wave >> 1, wn = wave & 1;
    int rrow = lane & 15, quad = lane >> 4;
    int srd  = (rrow >> 1) & 3;

    f32x4 acc[2][4];
    #pragma unroll
    for (int i = 0; i < 2; ++i)
        #pragma unroll
        for (int j = 0; j < 4; ++j)
            acc[i][j] = (f32x4){0.f, 0.f, 0.f, 0.f};

    for (int k0 = 0; k0 < Kloop; k0 += 64) {
        __syncthreads();
        #pragma unroll
        for (int s = 0; s < 2; ++s) {
            if (wave < 2) {
                GLOAD_LDS16(gA0 + k0 + s * 32, &Asl[s][(wave * 32) * 32]);
                GLOAD_LDS16(gA1 + k0 + s * 32, &Asl[s][(wave * 32 + 16) * 32]);
            }
            GLOAD_LDS16(gB0 + k0 + s * 32, &Bsl[s][(wave * 32) * 32]);
            GLOAD_LDS16(gB1 + k0 + s * 32, &Bsl[s][(wave * 32 + 16) * 32]);
        }
        __syncthreads();
        #pragma unroll
        for (int s = 0; s < 2; ++s) {
            short8 afr[2], bfr[4];
            #pragma unroll
            for (int mt = 0; mt < 2; ++mt)
                afr[mt] = *(const short8*)&Asl[s][(wm * 32 + mt * 16 + rrow) * 32 + ((quad + srd) & 3) * 8];
            #pragma unroll
            for (int nt = 0; nt < 4; ++nt)
                bfr[nt] = *(const short8*)&Bsl[s][(wn * 64 + nt * 16 + rrow) * 32 + ((quad + srd) & 3) * 8];
            #pragma unroll
            for (int mt = 0; mt < 2; ++mt)
                #pragma unroll
                for (int nt = 0; nt < 4; ++nt)
                    acc[mt][nt] = __builtin_amdgcn_mfma_f32_16x16x32_bf16(
                        afr[mt], bfr[nt], acc[mt][nt], 0, 0, 0);
        }
    }

    #pragma unroll
    for (int mt = 0; mt < 2; ++mt) {
        #pragma unroll
        for (int nt = 0; nt < 4; ++nt) {
            int n = wn * 64 + nt * 16 + rrow;
            float bv = HASBIAS ? bias[n0 + n] : 0.f;
            #pragma unroll
            for (int i = 0; i < 4; ++i) {
                int m = m0 + wm * 32 + mt * 16 + quad * 4 + i;
                float vv = acc[mt][nt][i] + bv;
                size_t off = (size_t)m * ldc + coff + n0 + n;
                if (OUTBF16) ((__hip_bfloat16*)Cout)[off] = __float2bfloat16(vv);
                else         ((float*)Cout)[off] = vv;
            }
        }
    }
}

// ---------------------------------------------------------------------------
// Kernel 4: MFMA flash attention, one block per (b,h), 4 waves.
// ---------------------------------------------------------------------------
__global__ __launch_bounds__(256) void attn_mfma_kernel(
    const __hip_bfloat16* __restrict__ q, const __hip_bfloat16* __restrict__ kvf,
    const u64* __restrict__ maskbits, __hip_bfloat16* __restrict__ att)
{
    constexpr int RP = 208;
    constexpr int QS = 40;
    constexpr int VS = 232;
    __shared__ short Qs[RP * QS];
    __shared__ short Ks[RP * QS];
    __shared__ short Vt[16 * VS];
    __shared__ short Ps[4][16 * VS];
    __shared__ u64 smask[RP][4];

    int b = blockIdx.x >> 3, h = blockIdx.x & 7;
    int t = threadIdx.x;
    int wave = t >> 6, lane = t & 63;
    int rrow = lane & 15, quad = lane >> 4;

    const short8 z8 = {0, 0, 0, 0, 0, 0, 0, 0};
    for (int idx = t; idx < RP * 2; idx += 256) {
        int r = idx >> 1, g = idx & 1;
        short8 qa = z8, ka = z8;
        if (r < Rc) {
            qa = *(const short8*)((const short*)q + ((size_t)(b * Rc + r)) * 128 + h * 16 + g * 8);
            ka = *(const short8*)((const short*)kvf + ((size_t)(b * Nc + r)) * 256 + h * 16 + g * 8);
        }
        *(short8*)&Qs[r * QS + g * 8] = qa;
        *(short8*)&Ks[r * QS + g * 8] = ka;
        *(short8*)&Qs[r * QS + 16 + g * 8] = z8;
        *(short8*)&Ks[r * QS + 16 + g * 8] = z8;
    }
    if (t < Rc) {
        const short* vp = (const short*)kvf + ((size_t)(b * Nc + t)) * 256 + 128 + h * 16;
        short8 v0 = *(const short8*)vp;
        short8 v1 = *(const short8*)(vp + 8);
        #pragma unroll
        for (int d = 0; d < 8; ++d) Vt[d * VS + t] = v0[d];
        #pragma unroll
        for (int d = 0; d < 8; ++d) Vt[(d + 8) * VS + t] = v1[d];
    }
    for (int idx = t; idx < 16 * 32; idx += 256) {
        int d = idx >> 5, cN = 200 + (idx & 31);
        if (cN < VS) Vt[d * VS + cN] = 0;
    }
    for (int idx = lane; idx < 16 * 16; idx += 64) {
        int rr = idx >> 4, cc = 208 + (idx & 15);
        Ps[wave][rr * VS + cc] = 0;
    }
    for (int idx = t; idx < RP * 4; idx += 256) {
        int r = idx >> 2, w = idx & 3;
        smask[r][w] = (r < Rc) ? maskbits[((size_t)b * Rc + r) * 4 + w] : ~0ull;
    }
    __syncthreads();

    for (int rt = wave; rt < 13; rt += 4) {
        short8 qf = *(const short8*)&Qs[(rt * 16 + rrow) * QS + quad * 8];
        f32x4 sacc[13];
        #pragma unroll
        for (int nt = 0; nt < 13; ++nt) {
            short8 kf = *(const short8*)&Ks[(nt * 16 + rrow) * QS + quad * 8];
            sacc[nt] = __builtin_amdgcn_mfma_f32_16x16x32_bf16(
                qf, kf, (f32x4){0.f, 0.f, 0.f, 0.f}, 0, 0, 0);
        }
        float inv[4];
        #pragma unroll
        for (int i = 0; i < 4; ++i) {
            int r = rt * 16 + quad * 4 + i;
            u64 wv0 = smask[r][0], wv1 = smask[r][1], wv2 = smask[r][2], wv3 = smask[r][3];
            float mx = -INFINITY;
            #pragma unroll
            for (int nt = 0; nt < 13; ++nt) {
                u64 w = (nt < 4) ? wv0 : (nt < 8) ? wv1 : (nt < 12) ? wv2 : wv3;
                int sh = ((nt & 3) << 4) + rrow;
                float s = ((w >> sh) & 1ull) ? sacc[nt][i] : -INFINITY;
                sacc[nt][i] = s;
                mx = fmaxf(mx, s);
            }
            mx = fmaxf(mx, __shfl_xor(mx, 1));
            mx = fmaxf(mx, __shfl_xor(mx, 2));
            mx = fmaxf(mx, __shfl_xor(mx, 4));
            mx = fmaxf(mx, __shfl_xor(mx, 8));
            float l = 0.f;
            #pragma unroll
            for (int nt = 0; nt < 13; ++nt) {
                float p = __expf(sacc[nt][i] - mx);
                sacc[nt][i] = p;
                l += p;
            }
            l += __shfl_xor(l, 1);
            l += __shfl_xor(l, 2);
            l += __shfl_xor(l, 4);
            l += __shfl_xor(l, 8);
            inv[i] = (l > 0.f) ? 1.f / l : 0.f;
        }
        #pragma unroll
        for (int nt = 0; nt < 13; ++nt)
            #pragma unroll
            for (int i = 0; i < 4; ++i)
                *(__hip_bfloat16*)&Ps[wave][(quad * 4 + i) * VS + nt * 16 + rrow] =
                    __float2bfloat16(sacc[nt][i]);
        f32x4 oacc = (f32x4){0.f, 0.f, 0.f, 0.f};
        #pragma unroll
        for (int kt = 0; kt < 7; ++kt) {
            short8 pf = *(const short8*)&Ps[wave][rrow * VS + kt * 32 + quad * 8];
            short8 vf = *(const short8*)&Vt[rrow * VS + kt * 32 + quad * 8];
            oacc = __builtin_amdgcn_mfma_f32_16x16x32_bf16(pf, vf, oacc, 0, 0, 0);
        }
        #pragma unroll
        for (int i = 0; i < 4; ++i) {
            int r = rt * 16 + quad * 4 + i;
            if (r < Rc)
                att[((size_t)(b * Rc + r)) * 128 + h * 16 + rrow] =
                    __float2bfloat16(oacc[i] * inv[i]);
        }
    }
}

// ---------------------------------------------------------------------------
// Kernel 5: logits = 10*tanh((att @ em^T + be)/sqrt(128)) masked via
// maskbits (mh GEMM folded away: em = enc@Wmhc^T, be = bmhc.enc).
// ---------------------------------------------------------------------------
__global__ __launch_bounds__(256) void logits_mfma_kernel(
    const __hip_bfloat16* __restrict__ att, const __hip_bfloat16* __restrict__ em,
    const float* __restrict__ be, const u64* __restrict__ maskbits,
    float* __restrict__ out)
{
    __shared__ short Asl[128 * 32];
    __shared__ short Bsl[128 * 32];
    __shared__ u64 sm[128][4];
    __shared__ float sbe[128];
    int b = blockIdx.x;
    int m0 = blockIdx.y * 128;
    int n0 = blockIdx.z * 128;
    int tid = threadIdx.x;
    int wave = tid >> 6, lane = tid & 63;

    for (int idx = tid; idx < 512; idx += 256) {
        int r = idx >> 2, w = idx & 3;
        int gr = m0 + r;
        sm[r][w] = (gr < Rc) ? maskbits[((size_t)b * Rc + gr) * 4 + w] : 0ull;
    }
    if (tid < 128) {
        int gn = n0 + tid;
        sbe[tid] = (gn < Nc) ? be[(size_t)b * Nc + gn] : 0.f;
    }

    int lrow = lane >> 2;
    int cg   = lane & 3;
    int ss   = (lane >> 3) & 3;
    int gq   = (cg - ss) & 3;
    const short* Ab = (const short*)(att + (size_t)b * Rc * 128);
    const short* Bb = (const short*)(em + (size_t)b * Nc * 128);
    const short* gA0 = Ab + (size_t)(m0 + wave * 32 + lrow) * 128 + gq * 8;
    const short* gA1 = gA0 + (size_t)16 * 128;
    const short* gB0 = Bb + (size_t)(n0 + wave * 32 + lrow) * 128 + gq * 8;
    const short* gB1 = gB0 + (size_t)16 * 128;
    short* lA0 = &Asl[(wave * 32) * 32];
    short* lA1 = &Asl[(wave * 32 + 16) * 32];
    short* lB0 = &Bsl[(wave * 32) * 32];
    short* lB1 = &Bsl[(wave * 32 + 16) * 32];

    int wm = wave >> 1, wn = wave & 1;
    int rrow = lane & 15, quad = lane >> 4;
    int srd  = (rrow >> 1) & 3;

    f32x4 acc[4][4];
    #pragma unroll
    for (int i = 0; i < 4; ++i)
        #pragma unroll
        for (int j = 0; j < 4; ++j)
            acc[i][j] = (f32x4){0.f, 0.f, 0.f, 0.f};

    for (int k0 = 0; k0 < 128; k0 += 32) {
        __syncthreads();
        GLOAD_LDS16(gA0 + k0, lA0);
        GLOAD_LDS16(gA1 + k0, lA1);
        GLOAD_LDS16(gB0 + k0, lB0);
        GLOAD_LDS16(gB1 + k0, lB1);
        __syncthreads();
        short8 afr[4], bfr[4];
        #pragma unroll
        for (int mt = 0; mt < 4; ++mt) {
            int rowa = wm * 64 + mt * 16 + rrow;
            afr[mt] = *(const short8*)&Asl[rowa * 32 + ((quad + srd) & 3) * 8];
            int rowb = wn * 64 + mt * 16 + rrow;
            bfr[mt] = *(const short8*)&Bsl[rowb * 32 + ((quad + srd) & 3) * 8];
        }
        #pragma unroll
        for (int mt = 0; mt < 4; ++mt)
            #pragma unroll
            for (int nt = 0; nt < 4; ++nt)
                acc[mt][nt] = __builtin_amdgcn_mfma_f32_16x16x32_bf16(
                    afr[mt], bfr[nt], acc[mt][nt], 0, 0, 0);
    }

    const float scale = 0.08838834764831843f;
    #pragma unroll
    for (int mt = 0; mt < 4; ++mt) {
        #pragma unroll
        for (int nt = 0; nt < 4; ++nt) {
            int nl = wn * 64 + nt * 16 + rrow;
            int n = n0 + nl;
            #pragma unroll
            for (int i = 0; i < 4; ++i) {
                int r = m0 + wm * 64 + mt * 16 + quad * 4 + i;
                if (r < Rc && n < Nc) {
                    u64 w = sm[r - m0][n >> 6];
                    float sh = (acc[mt][nt][i] + sbe[nl]) * scale;
                    float lg = ((w >> (n & 63)) & 1ull)
                             ? 10.f * tanhf(sh) : -INFINITY;
                    out[((size_t)b * Rc + r) * Nc + n] = lg;
                }
            }
        }
    }
}

// ---------------------------------------------------------------------------
// Kernel 6: row softmax over N=200, in place.
// ---------------------------------------------------------------------------
__global__ __launch_bounds__(64) void softmax_kernel(float* __restrict__ out)
{
    int br = blockIdx.x;
    float* row = out + (size_t)br * Nc;
    int t = threadIdx.x;
    float v[4]; float m = -INFINITY;
    #pragma unroll
    for (int j = 0; j < 4; ++j) {
        int n = t + 64 * j;
        v[j] = (n < Nc) ? row[n] : -INFINITY;
        m = fmaxf(m, v[j]);
    }
    #pragma unroll
    for (int off = 32; off > 0; off >>= 1) m = fmaxf(m, __shfl_xor(m, off));
    float e[4]; float s = 0.f;
    #pragma unroll
    for (int j = 0; j < 4; ++j) {
        e[j] = (v[j] == -INFINITY) ? 0.f : expf(v[j] - m);
        s += e[j];
    }
    #pragma unroll
    for (int off = 32; off > 0; off >>= 1) s += __shfl_xor(s, off);
    float inv = 1.f / s;
    #pragma unroll
    for (int j = 0; j < 4; ++j) {
        int n = t + 64 * j;
        if (n < Nc) row[n] = e[j] * inv;
    }
}

// ---------------------------------------------------------------------------
extern "C" void kernel_launch(void* const* d_in, const int* in_sizes, int n_in,
                              void* d_out, int out_size, void* d_ws, size_t ws_size,
                              hipStream_t stream)
{
    const float* enc  = (const float*)d_in[0];
    const float* dist = (const float*)d_in[1];
    const float* mask = (const float*)d_in[2];
    const int*   cur  = (const int*)d_in[3];
    const float* Wq   = (const float*)d_in[4];
    const float* Wk   = (const float*)d_in[5];
    const float* Wv   = (const float*)d_in[6];
    const float* Wmhc = (const float*)d_in[7];
    const float* bmhc = (const float*)d_in[8];
    const float* W1   = (const float*)d_in[9];
    const float* b1   = (const float*)d_in[10];
    const float* W2   = (const float*)d_in[11];
    const float* b2   = (const float*)d_in[12];
    float* out = (float*)d_out;

    char* ws = (char*)d_ws;
    size_t off = 0;
    auto alloc = [&](size_t bytes) { char* p = ws + off; off += (bytes + 255) & ~(size_t)255; return p; };
    __hip_bfloat16* W1t  = (__hip_bfloat16*)alloc((size_t)640 * 1280 * 2);
    __hip_bfloat16* Wkvt = (__hip_bfloat16*)alloc((size_t)256 * 128 * 2);
    __hip_bfloat16* Wmb  = (__hip_bfloat16*)alloc((size_t)128 * 128 * 2);
    __hip_bfloat16* Wcat = (__hip_bfloat16*)alloc((size_t)128 * 768 * 2);
    float* bq = (float*)alloc((size_t)128 * 4);
    // encb: rows [0, Bc*Nc) = enc bf16; rows [Bc*Nc, Bc*Nc+BRc) = mean rows
    __hip_bfloat16* encb = (__hip_bfloat16*)alloc((size_t)(Bc * Nc + BRc + 64) * Dc * 2);
    unsigned* aoff = (unsigned*)alloc((size_t)BRc * 16 * 4);
    __hip_bfloat16* hq   = (__hip_bfloat16*)alloc((size_t)BRc * 768 * 2);
    __hip_bfloat16* q    = (__hip_bfloat16*)alloc((size_t)BRc * 128 * 2);
    __hip_bfloat16* kvf  = (__hip_bfloat16*)alloc((size_t)Bc * Nc * 256 * 2);
    __hip_bfloat16* att  = (__hip_bfloat16*)alloc((size_t)(BRc + 64) * 128 * 2);
    __hip_bfloat16* em   = (__hip_bfloat16*)alloc((size_t)(Bc * Nc + 64) * 128 * 2);
    float* be = (float*)alloc((size_t)Bc * Nc * 4);
    u64* maskbits = (u64*)alloc((size_t)BRc * 4 * 8);

    // 1) prep + kNN (independent roles, one launch, 2530 blocks)
    prep_knn_kernel<<<2530, 256, 0, stream>>>(
        W1, W2, Wq, Wmhc, Wk, Wv, b2, enc, dist, mask, cur,
        W1t, Wkvt, Wmb, Wcat, bq, encb, aoff, hq, maskbits);
    // 2) gemm1 + kvf + em + be (independent, one launch, 825 blocks)
    fused_gemms_kernel<<<825, 256, 0, stream>>>(
        encb, aoff, W1t, b1, Wkvt, Wmb, bmhc, enc, hq, kvf, em, be);
    // 3) q = hq @ Wcat^T + bq  (pre-scaled, bf16)
    mfma_gemm64_kernel<true, true><<<dim3(1, BRc / 64), 256, 0, stream>>>(
        hq, 768, Wcat, 768, 768, bq, q, 128, 0);
    // 4) MFMA flash attention
    attn_mfma_kernel<<<Bc * Hc, 256, 0, stream>>>(q, kvf, maskbits, att);
    // 5) logits = tanh((att@em^T + be)*scale) masked (mh GEMM folded away)
    logits_mfma_kernel<<<dim3(Bc, 2, 2), 256, 0, stream>>>(att, em, be, maskbits, out);
    // 6) softmax
    softmax_kernel<<<BRc, 64, 0, stream>>>(out);
}

// Round 13
// 185.768 us; speedup vs baseline: 1.3456x; 1.0096x over previous
//
#include <hip/hip_runtime.h>
#include <hip/hip_bf16.h>
#include <math.h>

#define Bc 32
#define Rc 200
#define Nc 200
#define Dc 128
#define Hc 8
#define QKc 16
#define Kc 10
#define BRc (Bc*Rc)

typedef __attribute__((ext_vector_type(8))) short short8;
typedef __attribute__((ext_vector_type(4))) float f32x4;
typedef unsigned long long u64;

#define GLOAD_LDS16(g, l) __builtin_amdgcn_global_load_lds( \
    (const __attribute__((address_space(1))) void*)(g), \
    (__attribute__((address_space(3))) void*)(l), 16, 0, 0)

// ---------------------------------------------------------------------------
// 32x32 transpose+convert tile helper (block-uniform call sites only)
// ---------------------------------------------------------------------------
__device__ inline void transpose_tile(const float* __restrict__ src, int lds_,
                                      __hip_bfloat16* __restrict__ dst, int ldd,
                                      int k0, int n0, float scale)
{
    __shared__ float tile[32][33];
    int tx = threadIdx.x & 31, ty = threadIdx.x >> 5;  // 32 x 8
    #pragma unroll
    for (int i = ty; i < 32; i += 8)
        tile[i][tx] = src[(size_t)(k0 + i) * lds_ + n0 + tx];
    __syncthreads();
    #pragma unroll
    for (int i = ty; i < 32; i += 8)
        dst[(size_t)(n0 + i) * ldd + k0 + tx] = __float2bfloat16(tile[tx][i] * scale);
}

// ---------------------------------------------------------------------------
// Kernel 1: prep + kNN fused (independent roles, one launch).
//  [0,800)    W1 -> W1t   [800,816) Wk   [816,832) Wv   [832,848) Wmhc->Wmb
//  [848,864)  Wq top -> Wcat[:,0:128] (x0.25)
//  [864,904)  Wfused = W2 @ Wq_bot (fp32) -> Wcat[:,128:768] (x0.25)
//  [904,929)  enc -> encb bf16    [929] bq
//  [930,2530) kNN: wave-per-row, register-only butterfly top-10.
// ---------------------------------------------------------------------------
__global__ __launch_bounds__(256) void prep_knn_kernel(
    const float* __restrict__ W1, const float* __restrict__ W2,
    const float* __restrict__ Wq, const float* __restrict__ Wmhc,
    const float* __restrict__ Wk, const float* __restrict__ Wv,
    const float* __restrict__ b2, const float* __restrict__ enc,
    const float* __restrict__ dist, const float* __restrict__ mask,
    const int* __restrict__ cur,
    __hip_bfloat16* __restrict__ W1t, __hip_bfloat16* __restrict__ Wkvt,
    __hip_bfloat16* __restrict__ Wmb, __hip_bfloat16* __restrict__ Wcat,
    float* __restrict__ bq, __hip_bfloat16* __restrict__ encb,
    unsigned* __restrict__ aoff, __hip_bfloat16* __restrict__ hq,
    u64* __restrict__ maskbits)
{
    int bid = blockIdx.x;
    int t = threadIdx.x;
    if (bid < 800) {
        transpose_tile(W1, 640, W1t, 1280, (bid % 40) * 32, (bid / 40) * 32, 1.f);
    } else if (bid < 816) {
        int id = bid - 800;
        transpose_tile(Wk, 128, Wkvt, 128, (id & 3) * 32, (id >> 2) * 32, 1.f);
    } else if (bid < 832) {
        int id = bid - 816;
        transpose_tile(Wv, 128, Wkvt + 128 * 128, 128, (id & 3) * 32, (id >> 2) * 32, 1.f);
    } else if (bid < 848) {
        int e = (bid - 832) * 1024 + t * 4;
        #pragma unroll
        for (int j = 0; j < 4; ++j) Wmb[e + j] = __float2bfloat16(Wmhc[e + j]);
    } else if (bid < 864) {
        int id = bid - 848;
        transpose_tile(Wq, 128, Wcat, 768, (id & 3) * 32, (id >> 2) * 32, 0.25f);
    } else if (bid < 904) {
        int j0 = (bid - 864) * 16;
        int n = t & 127, half = t >> 7;
        #pragma unroll
        for (int jj = 0; jj < 8; ++jj) {
            int j = j0 + half * 8 + jj;
            float acc = 0.f;
            for (int k = 0; k < 128; ++k)
                acc = fmaf(W2[(size_t)j * 128 + k], Wq[(size_t)(128 + k) * 128 + n], acc);
            Wcat[(size_t)n * 768 + 128 + j] = __float2bfloat16(acc * 0.25f);
        }
    } else if (bid < 929) {
        size_t base = (size_t)(bid - 904) * 32768 + (size_t)t * 4;
        #pragma unroll 4
        for (int it = 0; it < 32; ++it) {
            size_t i = base + (size_t)it * 1024;
            float4 v = *(const float4*)(enc + i);
            encb[i + 0] = __float2bfloat16(v.x);
            encb[i + 1] = __float2bfloat16(v.y);
            encb[i + 2] = __float2bfloat16(v.z);
            encb[i + 3] = __float2bfloat16(v.w);
        }
    } else if (bid == 929) {
        if (t < 128) {
            float acc = 0.f;
            for (int k = 0; k < 128; ++k)
                acc = fmaf(b2[k], Wq[(size_t)(128 + k) * 128 + t], acc);
            bq[t] = acc * 0.25f;
        }
    } else {
        // kNN role: wave-per-row, register-only
        int lane = t & 63, w = t >> 6;
        int br = (bid - 930) * 4 + w;
        int b = br / Rc;
        int c = cur[br];
        const float* drow = dist + ((size_t)b * Nc + c) * Nc;
        const float* mrow = mask + (size_t)br * Nc;

        float v[4];
        #pragma unroll
        for (int j = 0; j < 4; ++j) {
            int n = lane + 64 * j;
            bool allowed = false;
            float val = INFINITY;
            if (n < Nc) {
                float mv = mrow[n];
                if (!isinf(mv)) { val = drow[n]; allowed = true; }
            }
            v[j] = val;
            u64 wb = __ballot(allowed);
            if (lane == 0) maskbits[(size_t)br * 4 + j] = wb;
        }
        int idxs[Kc];
        unsigned myrow = 0;
        #pragma unroll
        for (int k = 0; k < Kc; ++k) {
            float bv = v[0]; int bn = lane;
            #pragma unroll
            for (int j = 1; j < 4; ++j) {
                if (v[j] < bv) { bv = v[j]; bn = lane + 64 * j; }
            }
            #pragma unroll
            for (int off = 32; off > 0; off >>= 1) {
                float ov = __shfl_xor(bv, off);
                int   on = __shfl_xor(bn, off);
                if (ov < bv || (ov == bv && on < bn)) { bv = ov; bn = on; }
            }
            bool pad = isinf(bv);
            idxs[k] = pad ? Nc : bn;
            if (lane == k) myrow = pad ? (unsigned)(Bc * Nc + br) : (unsigned)(b * Nc + bn);
            int oj = bn >> 6, ol = bn & 63;
            if (!pad && lane == ol) v[oj] = INFINITY;
        }
        if (lane < Kc) aoff[(size_t)br * 16 + lane] = myrow << 7;

        const float* erow = enc + ((size_t)b * Nc + c) * Dc;
        __hip_bfloat16* hrow = hq + (size_t)br * 768;
        hrow[lane]      = __float2bfloat16(erow[lane]);
        hrow[lane + 64] = __float2bfloat16(erow[lane + 64]);

        if (idxs[Kc - 1] == Nc) {   // wave-uniform cold path: pads exist
            float cnt = 0.f;
            #pragma unroll
            for (int k = 0; k < Kc; ++k) cnt += (idxs[k] < Nc) ? 1.f : 0.f;
            float icnt = 1.f / fmaxf(cnt, 1e-9f);
            #pragma unroll
            for (int half = 0; half < 2; ++half) {
                int d = lane + 64 * half;
                float sum = 0.f;
                #pragma unroll
                for (int k = 0; k < Kc; ++k) {
                    if (idxs[k] < Nc)
                        sum += enc[((size_t)b * Nc + idxs[k]) * Dc + d];
                }
                encb[((size_t)(Bc * Nc) + br) * Dc + d] = __float2bfloat16(sum * icnt);
            }
        }
    }
}

// ---------------------------------------------------------------------------
// Kernel 2: mid-pipeline GEMMs, 64x64 tiles (waves 0-1 stage A, 2-3 stage B;
// 2x2 wave layout, acc[2][2]) for 4 blocks/CU co-residency:
//  [0,1000)    gemm1: hq[:,128:768] = relu(gather(encb) @ W1t^T + b1), K=1280
//  [1000,1400) kvf = encb @ [Wk|Wv]^T  (K=128)
//  [1400,1600) em  = encb @ Wmb^T      (K=128)
//  [1600,1625) be[i] = bmhc . enc[i]
// ---------------------------------------------------------------------------
__global__ __launch_bounds__(256) void fused_gemms_kernel(
    const __hip_bfloat16* __restrict__ encb, const unsigned* __restrict__ aoff,
    const __hip_bfloat16* __restrict__ W1t, const float* __restrict__ b1,
    const __hip_bfloat16* __restrict__ Wkvt, const __hip_bfloat16* __restrict__ Wmb,
    const float* __restrict__ bmhc, const float* __restrict__ enc,
    __hip_bfloat16* __restrict__ hq, __hip_bfloat16* __restrict__ kvf,
    __hip_bfloat16* __restrict__ em, float* __restrict__ be)
{
    __shared__ short Asl[2][64 * 32];
    __shared__ short Bsl[2][64 * 32];
    int bid = blockIdx.x;
    int tid = threadIdx.x;
    int wave = tid >> 6, lane = tid & 63;
    int lrow = lane >> 2;
    int cg   = lane & 3;
    int ss   = (lane >> 3) & 3;
    int gq   = (cg - ss) & 3;
    int wm = wave >> 1, wn = wave & 1;
    int rrow = lane & 15, quad = lane >> 4;
    int srd  = (rrow >> 1) & 3;
    int strip = (wave & 1) * 32;   // staging strip for this wave's operand

    if (bid < 1000) {
        // ---- gemm1 (gather A, K=1280 fully unrolled), 64x64
        int m0 = (bid / 10) * 64, n0 = (bid % 10) * 64;
        unsigned o0[Kc], o1[Kc];
        if (wave < 2) {
            const unsigned* ap0 = aoff + (size_t)(m0 + strip + lrow) * 16;
            const unsigned* ap1 = ap0 + 16 * 16;
            #pragma unroll
            for (int j = 0; j < Kc; ++j) { o0[j] = ap0[j]; o1[j] = ap1[j]; }
        }
        const short* Eb = (const short*)encb;
        const short* gB0 = (const short*)W1t + (size_t)(n0 + strip + lrow) * 1280 + gq * 8;
        const short* gB1 = gB0 + (size_t)16 * 1280;

        f32x4 acc[2][2];
        #pragma unroll
        for (int i = 0; i < 2; ++i)
            #pragma unroll
            for (int j = 0; j < 2; ++j)
                acc[i][j] = (f32x4){0.f, 0.f, 0.f, 0.f};

        #pragma unroll
        for (int kt = 0; kt < 20; ++kt) {
            int k0 = kt * 64;
            int slot = kt >> 1;
            int dbase = (kt & 1) * 64 + gq * 8;
            __syncthreads();
            #pragma unroll
            for (int s = 0; s < 2; ++s) {
                if (wave < 2) {
                    GLOAD_LDS16(Eb + o0[slot] + dbase + s * 32, &Asl[s][strip * 32]);
                    GLOAD_LDS16(Eb + o1[slot] + dbase + s * 32, &Asl[s][(strip + 16) * 32]);
                } else {
                    GLOAD_LDS16(gB0 + k0 + s * 32, &Bsl[s][strip * 32]);
                    GLOAD_LDS16(gB1 + k0 + s * 32, &Bsl[s][(strip + 16) * 32]);
                }
            }
            __syncthreads();
            #pragma unroll
            for (int s = 0; s < 2; ++s) {
                short8 afr[2], bfr[2];
                #pragma unroll
                for (int mt = 0; mt < 2; ++mt)
                    afr[mt] = *(const short8*)&Asl[s][(wm * 32 + mt * 16 + rrow) * 32 + ((quad + srd) & 3) * 8];
                #pragma unroll
                for (int nt = 0; nt < 2; ++nt)
                    bfr[nt] = *(const short8*)&Bsl[s][(wn * 32 + nt * 16 + rrow) * 32 + ((quad + srd) & 3) * 8];
                #pragma unroll
                for (int mt = 0; mt < 2; ++mt)
                    #pragma unroll
                    for (int nt = 0; nt < 2; ++nt)
                        acc[mt][nt] = __builtin_amdgcn_mfma_f32_16x16x32_bf16(
                            afr[mt], bfr[nt], acc[mt][nt], 0, 0, 0);
            }
        }
        #pragma unroll
        for (int mt = 0; mt < 2; ++mt)
            #pragma unroll
            for (int nt = 0; nt < 2; ++nt) {
                int n = wn * 32 + nt * 16 + rrow;
                float bv = b1[n0 + n];
                #pragma unroll
                for (int i = 0; i < 4; ++i) {
                    int m = m0 + wm * 32 + mt * 16 + quad * 4 + i;
                    float vv = fmaxf(acc[mt][nt][i] + bv, 0.f);
                    hq[(size_t)m * 768 + 128 + n0 + n] = __float2bfloat16(vv);
                }
            }
    } else if (bid < 1600) {
        // ---- kvf or em (K=128, 2 barrier iters), 64x64
        const short* Bbase; __hip_bfloat16* Cout; int ldc, m0, n0;
        if (bid < 1400) {
            int id = bid - 1000;
            Bbase = (const short*)Wkvt; Cout = kvf; ldc = 256;
            m0 = (id >> 2) * 64; n0 = (id & 3) * 64;
        } else {
            int id = bid - 1400;
            Bbase = (const short*)Wmb; Cout = em; ldc = 128;
            m0 = (id >> 1) * 64; n0 = (id & 1) * 64;
        }
        const short* g0 = (wave < 2)
            ? (const short*)encb + (size_t)(m0 + strip + lrow) * 128 + gq * 8
            : Bbase + (size_t)(n0 + strip + lrow) * 128 + gq * 8;
        const short* g1 = g0 + (size_t)16 * 128;

        f32x4 acc[2][2];
        #pragma unroll
        for (int i = 0; i < 2; ++i)
            #pragma unroll
            for (int j = 0; j < 2; ++j)
                acc[i][j] = (f32x4){0.f, 0.f, 0.f, 0.f};

        #pragma unroll
        for (int kt = 0; kt < 2; ++kt) {
            int k0 = kt * 64;
            __syncthreads();
            #pragma unroll
            for (int s = 0; s < 2; ++s) {
                short* l0 = (wave < 2) ? &Asl[s][strip * 32] : &Bsl[s][strip * 32];
                short* l1 = (wave < 2) ? &Asl[s][(strip + 16) * 32] : &Bsl[s][(strip + 16) * 32];
                GLOAD_LDS16(g0 + k0 + s * 32, l0);
                GLOAD_LDS16(g1 + k0 + s * 32, l1);
            }
            __syncthreads();
            #pragma unroll
            for (int s = 0; s < 2; ++s) {
                short8 afr[2], bfr[2];
                #pragma unroll
                for (int mt = 0; mt < 2; ++mt)
                    afr[mt] = *(const short8*)&Asl[s][(wm * 32 + mt * 16 + rrow) * 32 + ((quad + srd) & 3) * 8];
                #pragma unroll
                for (int nt = 0; nt < 2; ++nt)
                    bfr[nt] = *(const short8*)&Bsl[s][(wn * 32 + nt * 16 + rrow) * 32 + ((quad + srd) & 3) * 8];
                #pragma unroll
                for (int mt = 0; mt < 2; ++mt)
                    #pragma unroll
                    for (int nt = 0; nt < 2; ++nt)
                        acc[mt][nt] = __builtin_amdgcn_mfma_f32_16x16x32_bf16(
                            afr[mt], bfr[nt], acc[mt][nt], 0, 0, 0);
            }
        }
        #pragma unroll
        for (int mt = 0; mt < 2; ++mt)
            #pragma unroll
            for (int nt = 0; nt < 2; ++nt) {
                int n = wn * 32 + nt * 16 + rrow;
                #pragma unroll
                for (int i = 0; i < 4; ++i) {
                    int m = m0 + wm * 32 + mt * 16 + quad * 4 + i;
                    Cout[(size_t)m * ldc + n0 + n] = __float2bfloat16(acc[mt][nt][i]);
                }
            }
    } else {
        // ---- be[i] = bmhc . enc[i,:]   (i < Bc*Nc = 6400; 25 blocks)
        int i = (bid - 1600) * 256 + tid;
        if (i < Bc * Nc) {
            const float* row = enc + (size_t)i * 128;
            float acc = 0.f;
            #pragma unroll
            for (int dq = 0; dq < 32; ++dq) {
                float4 e4 = *(const float4*)(row + dq * 4);
                acc = fmaf(bmhc[dq * 4 + 0], e4.x, acc);
                acc = fmaf(bmhc[dq * 4 + 1], e4.y, acc);
                acc = fmaf(bmhc[dq * 4 + 2], e4.z, acc);
                acc = fmaf(bmhc[dq * 4 + 3], e4.w, acc);
            }
            be[i] = acc;
        }
    }
}

// ---------------------------------------------------------------------------
// Kernel 3: q = hq @ Wcat^T + bq  (64x64 tiles, grid (2,100) = 200 blocks)
// ---------------------------------------------------------------------------
__global__ __launch_bounds__(256) void qgemm_kernel(
    const __hip_bfloat16* __restrict__ hq, const __hip_bfloat16* __restrict__ Wcat,
    const float* __restrict__ bq, __hip_bfloat16* __restrict__ q)
{
    __shared__ short Asl[2][64 * 32];
    __shared__ short Bsl[2][64 * 32];
    int tid = threadIdx.x;
    int wave = tid >> 6, lane = tid & 63;
    int m0 = blockIdx.y * 64, n0 = blockIdx.x * 64;
    int lrow = lane >> 2;
    int cg   = lane & 3;
    int ss   = (lane >> 3) & 3;
    int gq   = (cg - ss) & 3;
    int wm = wave >> 1, wn = wave & 1;
    int rrow = lane & 15, quad = lane >> 4;
    int srd  = (rrow >> 1) & 3;
    int strip = (wave & 1) * 32;

    const short* g0 = (wave < 2)
        ? (const short*)hq + (size_t)(m0 + strip + lrow) * 768 + gq * 8
        : (const short*)Wcat + (size_t)(n0 + strip + lrow) * 768 + gq * 8;
    const short* g1 = g0 + (size_t)16 * 768;

    f32x4 acc[2][2];
    #pragma unroll
    for (int i = 0; i < 2; ++i)
        #pragma unroll
        for (int j = 0; j < 2; ++j)
            acc[i][j] = (f32x4){0.f, 0.f, 0.f, 0.f};

    for (int k0 = 0; k0 < 768; k0 += 64) {
        __syncthreads();
        #pragma unroll
        for (int s = 0; s < 2; ++s) {
            short* l0 = (wave < 2) ? &Asl[s][strip * 32] : &Bsl[s][strip * 32];
            short* l1 = (wave < 2) ? &Asl[s][(strip + 16) * 32] : &Bsl[s][(strip + 16) * 32];
            GLOAD_LDS16(g0 + k0 + s * 32, l0);
            GLOAD_LDS16(g1 + k0 + s * 32, l1);
        }
        __syncthreads();
        #pragma unroll
        for (int s = 0; s < 2; ++s) {
            short8 afr[2], bfr[2];
            #pragma unroll
            for (int mt = 0; mt < 2; ++mt)
                afr[mt] = *(const short8*)&Asl[s][(wm * 32 + mt * 16 + rrow) * 32 + ((quad + srd) & 3) * 8];
            #pragma unroll
            for (int nt = 0; nt < 2; ++nt)
                bfr[nt] = *(const short8*)&Bsl[s][(wn * 32 + nt * 16 + rrow) * 32 + ((quad + srd) & 3) * 8];
            #pragma unroll
            for (int mt = 0; mt < 2; ++mt)
                #pragma unroll
                for (int nt = 0; nt < 2; ++nt)
                    acc[mt][nt] = __builtin_amdgcn_mfma_f32_16x16x32_bf16(
                        afr[mt], bfr[nt], acc[mt][nt], 0, 0, 0);
        }
    }

    #pragma unroll
    for (int mt = 0; mt < 2; ++mt) {
        #pragma unroll
        for (int nt = 0; nt < 2; ++nt) {
            int n = wn * 32 + nt * 16 + rrow;
            float bv = bq[n0 + n];
            #pragma unroll
            for (int i = 0; i < 4; ++i) {
                int m = m0 + wm * 32 + mt * 16 + quad * 4 + i;
                q[(size_t)m * 128 + n0 + n] = __float2bfloat16(acc[mt][nt][i] + bv);
            }
        }
    }
}

// ---------------------------------------------------------------------------
// Kernel 4: MFMA flash attention, one block per (b,h), 4 waves.
// ---------------------------------------------------------------------------
__global__ __launch_bounds__(256) void attn_mfma_kernel(
    const __hip_bfloat16* __restrict__ q, const __hip_bfloat16* __restrict__ kvf,
    const u64* __restrict__ maskbits, __hip_bfloat16* __restrict__ att)
{
    constexpr int RP = 208;
    constexpr int QS = 40;
    constexpr int VS = 232;
    __shared__ short Qs[RP * QS];
    __shared__ short Ks[RP * QS];
    __shared__ short Vt[16 * VS];
    __shared__ short Ps[4][16 * VS];
    __shared__ u64 smask[RP][4];

    int b = blockIdx.x >> 3, h = blockIdx.x & 7;
    int t = threadIdx.x;
    int wave = t >> 6, lane = t & 63;
    int rrow = lane & 15, quad = lane >> 4;

    const short8 z8 = {0, 0, 0, 0, 0, 0, 0, 0};
    for (int idx = t; idx < RP * 2; idx += 256) {
        int r = idx >> 1, g = idx & 1;
        short8 qa = z8, ka = z8;
        if (r < Rc) {
            qa = *(const short8*)((const short*)q + ((size_t)(b * Rc + r)) * 128 + h * 16 + g * 8);
            ka = *(const short8*)((const short*)kvf + ((size_t)(b * Nc + r)) * 256 + h * 16 + g * 8);
        }
        *(short8*)&Qs[r * QS + g * 8] = qa;
        *(short8*)&Ks[r * QS + g * 8] = ka;
        *(short8*)&Qs[r * QS + 16 + g * 8] = z8;
        *(short8*)&Ks[r * QS + 16 + g * 8] = z8;
    }
    if (t < Rc) {
        const short* vp = (const short*)kvf + ((size_t)(b * Nc + t)) * 256 + 128 + h * 16;
        short8 v0 = *(const short8*)vp;
        short8 v1 = *(const short8*)(vp + 8);
        #pragma unroll
        for (int d = 0; d < 8; ++d) Vt[d * VS + t] = v0[d];
        #pragma unroll
        for (int d = 0; d < 8; ++d) Vt[(d + 8) * VS + t] = v1[d];
    }
    for (int idx = t; idx < 16 * 32; idx += 256) {
        int d = idx >> 5, cN = 200 + (idx & 31);
        if (cN < VS) Vt[d * VS + cN] = 0;
    }
    for (int idx = lane; idx < 16 * 16; idx += 64) {
        int rr = idx >> 4, cc = 208 + (idx & 15);
        Ps[wave][rr * VS + cc] = 0;
    }
    for (int idx = t; idx < RP * 4; idx += 256) {
        int r = idx >> 2, w = idx & 3;
        smask[r][w] = (r < Rc) ? maskbits[((size_t)b * Rc + r) * 4 + w] : ~0ull;
    }
    __syncthreads();

    for (int rt = wave; rt < 13; rt += 4) {
        short8 qf = *(const short8*)&Qs[(rt * 16 + rrow) * QS + quad * 8];
        f32x4 sacc[13];
        #pragma unroll
        for (int nt = 0; nt < 13; ++nt) {
            short8 kf = *(const short8*)&Ks[(nt * 16 + rrow) * QS + quad * 8];
            sacc[nt] = __builtin_amdgcn_mfma_f32_16x16x32_bf16(
                qf, kf, (f32x4){0.f, 0.f, 0.f, 0.f}, 0, 0, 0);
        }
        float inv[4];
        #pragma unroll
        for (int i = 0; i < 4; ++i) {
            int r = rt * 16 + quad * 4 + i;
            u64 wv0 = smask[r][0], wv1 = smask[r][1], wv2 = smask[r][2], wv3 = smask[r][3];
            float mx = -INFINITY;
            #pragma unroll
            for (int nt = 0; nt < 13; ++nt) {
                u64 w = (nt < 4) ? wv0 : (nt < 8) ? wv1 : (nt < 12) ? wv2 : wv3;
                int sh = ((nt & 3) << 4) + rrow;
                float s = ((w >> sh) & 1ull) ? sacc[nt][i] : -INFINITY;
                sacc[nt][i] = s;
                mx = fmaxf(mx, s);
            }
            mx = fmaxf(mx, __shfl_xor(mx, 1));
            mx = fmaxf(mx, __shfl_xor(mx, 2));
            mx = fmaxf(mx, __shfl_xor(mx, 4));
            mx = fmaxf(mx, __shfl_xor(mx, 8));
            float l = 0.f;
            #pragma unroll
            for (int nt = 0; nt < 13; ++nt) {
                float p = __expf(sacc[nt][i] - mx);
                sacc[nt][i] = p;
                l += p;
            }
            l += __shfl_xor(l, 1);
            l += __shfl_xor(l, 2);
            l += __shfl_xor(l, 4);
            l += __shfl_xor(l, 8);
            inv[i] = (l > 0.f) ? 1.f / l : 0.f;
        }
        #pragma unroll
        for (int nt = 0; nt < 13; ++nt)
            #pragma unroll
            for (int i = 0; i < 4; ++i)
                *(__hip_bfloat16*)&Ps[wave][(quad * 4 + i) * VS + nt * 16 + rrow] =
                    __float2bfloat16(sacc[nt][i]);
        f32x4 oacc = (f32x4){0.f, 0.f, 0.f, 0.f};
        #pragma unroll
        for (int kt = 0; kt < 7; ++kt) {
            short8 pf = *(const short8*)&Ps[wave][rrow * VS + kt * 32 + quad * 8];
            short8 vf = *(const short8*)&Vt[rrow * VS + kt * 32 + quad * 8];
            oacc = __builtin_amdgcn_mfma_f32_16x16x32_bf16(pf, vf, oacc, 0, 0, 0);
        }
        #pragma unroll
        for (int i = 0; i < 4; ++i) {
            int r = rt * 16 + quad * 4 + i;
            if (r < Rc)
                att[((size_t)(b * Rc + r)) * 128 + h * 16 + rrow] =
                    __float2bfloat16(oacc[i] * inv[i]);
        }
    }
}

// ---------------------------------------------------------------------------
// Kernel 5: logits = 10*tanh((att @ em^T + be)/sqrt(128)) masked via maskbits
// ---------------------------------------------------------------------------
__global__ __launch_bounds__(256) void logits_mfma_kernel(
    const __hip_bfloat16* __restrict__ att, const __hip_bfloat16* __restrict__ em,
    const float* __restrict__ be, const u64* __restrict__ maskbits,
    float* __restrict__ out)
{
    __shared__ short Asl[128 * 32];
    __shared__ short Bsl[128 * 32];
    __shared__ u64 sm[128][4];
    __shared__ float sbe[128];
    int b = blockIdx.x;
    int m0 = blockIdx.y * 128;
    int n0 = blockIdx.z * 128;
    int tid = threadIdx.x;
    int wave = tid >> 6, lane = tid & 63;

    for (int idx = tid; idx < 512; idx += 256) {
        int r = idx >> 2, w = idx & 3;
        int gr = m0 + r;
        sm[r][w] = (gr < Rc) ? maskbits[((size_t)b * Rc + gr) * 4 + w] : 0ull;
    }
    if (tid < 128) {
        int gn = n0 + tid;
        sbe[tid] = (gn < Nc) ? be[(size_t)b * Nc + gn] : 0.f;
    }

    int lrow = lane >> 2;
    int cg   = lane & 3;
    int ss   = (lane >> 3) & 3;
    int gq   = (cg - ss) & 3;
    const short* Ab = (const short*)(att + (size_t)b * Rc * 128);
    const short* Bb = (const short*)(em + (size_t)b * Nc * 128);
    const short* gA0 = Ab + (size_t)(m0 + wave * 32 + lrow) * 128 + gq * 8;
    const short* gA1 = gA0 + (size_t)16 * 128;
    const short* gB0 = Bb + (size_t)(n0 + wave * 32 + lrow) * 128 + gq * 8;
    const short* gB1 = gB0 + (size_t)16 * 128;
    short* lA0 = &Asl[(wave * 32) * 32];
    short* lA1 = &Asl[(wave * 32 + 16) * 32];
    short* lB0 = &Bsl[(wave * 32) * 32];
    short* lB1 = &Bsl[(wave * 32 + 16) * 32];

    int wm = wave >> 1, wn = wave & 1;
    int rrow = lane & 15, quad = lane >> 4;
    int srd  = (rrow >> 1) & 3;

    f32x4 acc[4][4];
    #pragma unroll
    for (int i = 0; i < 4; ++i)
        #pragma unroll
        for (int j = 0; j < 4; ++j)
            acc[i][j] = (f32x4){0.f, 0.f, 0.f, 0.f};

    for (int k0 = 0; k0 < 128; k0 += 32) {
        __syncthreads();
        GLOAD_LDS16(gA0 + k0, lA0);
        GLOAD_LDS16(gA1 + k0, lA1);
        GLOAD_LDS16(gB0 + k0, lB0);
        GLOAD_LDS16(gB1 + k0, lB1);
        __syncthreads();
        short8 afr[4], bfr[4];
        #pragma unroll
        for (int mt = 0; mt < 4; ++mt) {
            int rowa = wm * 64 + mt * 16 + rrow;
            afr[mt] = *(const short8*)&Asl[rowa * 32 + ((quad + srd) & 3) * 8];
            int rowb = wn * 64 + mt * 16 + rrow;
            bfr[mt] = *(const short8*)&Bsl[rowb * 32 + ((quad + srd) & 3) * 8];
        }
        #pragma unroll
        for (int mt = 0; mt < 4; ++mt)
            #pragma unroll
            for (int nt = 0; nt < 4; ++nt)
                acc[mt][nt] = __builtin_amdgcn_mfma_f32_16x16x32_bf16(
                    afr[mt], bfr[nt], acc[mt][nt], 0, 0, 0);
    }

    const float scale = 0.08838834764831843f;
    #pragma unroll
    for (int mt = 0; mt < 4; ++mt) {
        #pragma unroll
        for (int nt = 0; nt < 4; ++nt) {
            int nl = wn * 64 + nt * 16 + rrow;
            int n = n0 + nl;
            #pragma unroll
            for (int i = 0; i < 4; ++i) {
                int r = m0 + wm * 64 + mt * 16 + quad * 4 + i;
                if (r < Rc && n < Nc) {
                    u64 w = sm[r - m0][n >> 6];
                    float sh = (acc[mt][nt][i] + sbe[nl]) * scale;
                    float lg = ((w >> (n & 63)) & 1ull)
                             ? 10.f * tanhf(sh) : -INFINITY;
                    out[((size_t)b * Rc + r) * Nc + n] = lg;
                }
            }
        }
    }
}

// ---------------------------------------------------------------------------
// Kernel 6: row softmax over N=200, in place.
// ---------------------------------------------------------------------------
__global__ __launch_bounds__(64) void softmax_kernel(float* __restrict__ out)
{
    int br = blockIdx.x;
    float* row = out + (size_t)br * Nc;
    int t = threadIdx.x;
    float v[4]; float m = -INFINITY;
    #pragma unroll
    for (int j = 0; j < 4; ++j) {
        int n = t + 64 * j;
        v[j] = (n < Nc) ? row[n] : -INFINITY;
        m = fmaxf(m, v[j]);
    }
    #pragma unroll
    for (int off = 32; off > 0; off >>= 1) m = fmaxf(m, __shfl_xor(m, off));
    float e[4]; float s = 0.f;
    #pragma unroll
    for (int j = 0; j < 4; ++j) {
        e[j] = (v[j] == -INFINITY) ? 0.f : expf(v[j] - m);
        s += e[j];
    }
    #pragma unroll
    for (int off = 32; off > 0; off >>= 1) s += __shfl_xor(s, off);
    float inv = 1.f / s;
    #pragma unroll
    for (int j = 0; j < 4; ++j) {
        int n = t + 64 * j;
        if (n < Nc) row[n] = e[j] * inv;
    }
}

// ---------------------------------------------------------------------------
extern "C" void kernel_launch(void* const* d_in, const int* in_sizes, int n_in,
                              void* d_out, int out_size, void* d_ws, size_t ws_size,
                              hipStream_t stream)
{
    const float* enc  = (const float*)d_in[0];
    const float* dist = (const float*)d_in[1];
    const float* mask = (const float*)d_in[2];
    const int*   cur  = (const int*)d_in[3];
    const float* Wq   = (const float*)d_in[4];
    const float* Wk   = (const float*)d_in[5];
    const float* Wv   = (const float*)d_in[6];
    const float* Wmhc = (const float*)d_in[7];
    const float* bmhc = (const float*)d_in[8];
    const float* W1   = (const float*)d_in[9];
    const float* b1   = (const float*)d_in[10];
    const float* W2   = (const float*)d_in[11];
    const float* b2   = (const float*)d_in[12];
    float* out = (float*)d_out;

    char* ws = (char*)d_ws;
    size_t off = 0;
    auto alloc = [&](size_t bytes) { char* p = ws + off; off += (bytes + 255) & ~(size_t)255; return p; };
    __hip_bfloat16* W1t  = (__hip_bfloat16*)alloc((size_t)640 * 1280 * 2);
    __hip_bfloat16* Wkvt = (__hip_bfloat16*)alloc((size_t)256 * 128 * 2);
    __hip_bfloat16* Wmb  = (__hip_bfloat16*)alloc((size_t)128 * 128 * 2);
    __hip_bfloat16* Wcat = (__hip_bfloat16*)alloc((size_t)128 * 768 * 2);
    float* bq = (float*)alloc((size_t)128 * 4);
    // encb: rows [0, Bc*Nc) = enc bf16; rows [Bc*Nc, Bc*Nc+BRc) = mean rows
    __hip_bfloat16* encb = (__hip_bfloat16*)alloc((size_t)(Bc * Nc + BRc + 64) * Dc * 2);
    unsigned* aoff = (unsigned*)alloc((size_t)BRc * 16 * 4);
    __hip_bfloat16* hq   = (__hip_bfloat16*)alloc((size_t)BRc * 768 * 2);
    __hip_bfloat16* q    = (__hip_bfloat16*)alloc((size_t)BRc * 128 * 2);
    __hip_bfloat16* kvf  = (__hip_bfloat16*)alloc((size_t)Bc * Nc * 256 * 2);
    __hip_bfloat16* att  = (__hip_bfloat16*)alloc((size_t)(BRc + 64) * 128 * 2);
    __hip_bfloat16* em   = (__hip_bfloat16*)alloc((size_t)(Bc * Nc + 64) * 128 * 2);
    float* be = (float*)alloc((size_t)Bc * Nc * 4);
    u64* maskbits = (u64*)alloc((size_t)BRc * 4 * 8);

    // 1) prep + kNN (independent roles, one launch, 2530 blocks)
    prep_knn_kernel<<<2530, 256, 0, stream>>>(
        W1, W2, Wq, Wmhc, Wk, Wv, b2, enc, dist, mask, cur,
        W1t, Wkvt, Wmb, Wcat, bq, encb, aoff, hq, maskbits);
    // 2) gemm1 + kvf + em + be (64x64 tiles, one launch, 1625 blocks)
    fused_gemms_kernel<<<1625, 256, 0, stream>>>(
        encb, aoff, W1t, b1, Wkvt, Wmb, bmhc, enc, hq, kvf, em, be);
    // 3) q = hq @ Wcat^T + bq  (64x64 tiles, 200 blocks)
    qgemm_kernel<<<dim3(2, BRc / 64), 256, 0, stream>>>(hq, Wcat, bq, q);
    // 4) MFMA flash attention
    attn_mfma_kernel<<<Bc * Hc, 256, 0, stream>>>(q, kvf, maskbits, att);
    // 5) logits = tanh((att@em^T + be)*scale) masked
    logits_mfma_kernel<<<dim3(Bc, 2, 2), 256, 0, stream>>>(att, em, be, maskbits, out);
    // 6) softmax
    softmax_kernel<<<BRc, 64, 0, stream>>>(out);
}

// Round 14
// 177.781 us; speedup vs baseline: 1.4060x; 1.0449x over previous
//
#include <hip/hip_runtime.h>
#include <hip/hip_bf16.h>
#include <math.h>

#define Bc 32
#define Rc 200
#define Nc 200
#define Dc 128
#define Hc 8
#define QKc 16
#define Kc 10
#define BRc (Bc*Rc)

typedef __attribute__((ext_vector_type(8))) short short8;
typedef __attribute__((ext_vector_type(4))) float f32x4;
typedef unsigned long long u64;

#define GLOAD_LDS16(g, l) __builtin_amdgcn_global_load_lds( \
    (const __attribute__((address_space(1))) void*)(g), \
    (__attribute__((address_space(3))) void*)(l), 16, 0, 0)

// ---------------------------------------------------------------------------
// 32x32 transpose+convert tile helper (block-uniform call sites only)
// ---------------------------------------------------------------------------
__device__ inline void transpose_tile(const float* __restrict__ src, int lds_,
                                      __hip_bfloat16* __restrict__ dst, int ldd,
                                      int k0, int n0, float scale)
{
    __shared__ float tile[32][33];
    int tx = threadIdx.x & 31, ty = threadIdx.x >> 5;  // 32 x 8
    #pragma unroll
    for (int i = ty; i < 32; i += 8)
        tile[i][tx] = src[(size_t)(k0 + i) * lds_ + n0 + tx];
    __syncthreads();
    #pragma unroll
    for (int i = ty; i < 32; i += 8)
        dst[(size_t)(n0 + i) * ldd + k0 + tx] = __float2bfloat16(tile[tx][i] * scale);
}

// ---------------------------------------------------------------------------
// Kernel 1: prep + kNN fused (independent roles, one launch).
//  [0,800)    W1 -> W1t   [800,816) Wk   [816,832) Wv   [832,848) Wmhc->Wmb
//  [848,864)  Wq top -> Wcat[:,0:128] (x0.25)
//  [864,904)  Wfused = W2 @ Wq_bot (fp32) -> Wcat[:,128:768] (x0.25)
//  [904,929)  enc -> encb bf16    [929] bq
//  [930,2530) kNN: wave-per-row, register-only butterfly top-10.
// ---------------------------------------------------------------------------
__global__ __launch_bounds__(256) void prep_knn_kernel(
    const float* __restrict__ W1, const float* __restrict__ W2,
    const float* __restrict__ Wq, const float* __restrict__ Wmhc,
    const float* __restrict__ Wk, const float* __restrict__ Wv,
    const float* __restrict__ b2, const float* __restrict__ enc,
    const float* __restrict__ dist, const float* __restrict__ mask,
    const int* __restrict__ cur,
    __hip_bfloat16* __restrict__ W1t, __hip_bfloat16* __restrict__ Wkvt,
    __hip_bfloat16* __restrict__ Wmb, __hip_bfloat16* __restrict__ Wcat,
    float* __restrict__ bq, __hip_bfloat16* __restrict__ encb,
    unsigned* __restrict__ aoff, __hip_bfloat16* __restrict__ hq,
    u64* __restrict__ maskbits)
{
    int bid = blockIdx.x;
    int t = threadIdx.x;
    if (bid < 800) {
        transpose_tile(W1, 640, W1t, 1280, (bid % 40) * 32, (bid / 40) * 32, 1.f);
    } else if (bid < 816) {
        int id = bid - 800;
        transpose_tile(Wk, 128, Wkvt, 128, (id & 3) * 32, (id >> 2) * 32, 1.f);
    } else if (bid < 832) {
        int id = bid - 816;
        transpose_tile(Wv, 128, Wkvt + 128 * 128, 128, (id & 3) * 32, (id >> 2) * 32, 1.f);
    } else if (bid < 848) {
        int e = (bid - 832) * 1024 + t * 4;
        #pragma unroll
        for (int j = 0; j < 4; ++j) Wmb[e + j] = __float2bfloat16(Wmhc[e + j]);
    } else if (bid < 864) {
        int id = bid - 848;
        transpose_tile(Wq, 128, Wcat, 768, (id & 3) * 32, (id >> 2) * 32, 0.25f);
    } else if (bid < 904) {
        int j0 = (bid - 864) * 16;
        int n = t & 127, half = t >> 7;
        #pragma unroll
        for (int jj = 0; jj < 8; ++jj) {
            int j = j0 + half * 8 + jj;
            float acc = 0.f;
            for (int k = 0; k < 128; ++k)
                acc = fmaf(W2[(size_t)j * 128 + k], Wq[(size_t)(128 + k) * 128 + n], acc);
            Wcat[(size_t)n * 768 + 128 + j] = __float2bfloat16(acc * 0.25f);
        }
    } else if (bid < 929) {
        size_t base = (size_t)(bid - 904) * 32768 + (size_t)t * 4;
        #pragma unroll 4
        for (int it = 0; it < 32; ++it) {
            size_t i = base + (size_t)it * 1024;
            float4 v = *(const float4*)(enc + i);
            encb[i + 0] = __float2bfloat16(v.x);
            encb[i + 1] = __float2bfloat16(v.y);
            encb[i + 2] = __float2bfloat16(v.z);
            encb[i + 3] = __float2bfloat16(v.w);
        }
    } else if (bid == 929) {
        if (t < 128) {
            float acc = 0.f;
            for (int k = 0; k < 128; ++k)
                acc = fmaf(b2[k], Wq[(size_t)(128 + k) * 128 + t], acc);
            bq[t] = acc * 0.25f;
        }
    } else {
        // kNN role: wave-per-row, register-only
        int lane = t & 63, w = t >> 6;
        int br = (bid - 930) * 4 + w;
        int b = br / Rc;
        int c = cur[br];
        const float* drow = dist + ((size_t)b * Nc + c) * Nc;
        const float* mrow = mask + (size_t)br * Nc;

        float v[4];
        #pragma unroll
        for (int j = 0; j < 4; ++j) {
            int n = lane + 64 * j;
            bool allowed = false;
            float val = INFINITY;
            if (n < Nc) {
                float mv = mrow[n];
                if (!isinf(mv)) { val = drow[n]; allowed = true; }
            }
            v[j] = val;
            u64 wb = __ballot(allowed);
            if (lane == 0) maskbits[(size_t)br * 4 + j] = wb;
        }
        int idxs[Kc];
        unsigned myrow = 0;
        #pragma unroll
        for (int k = 0; k < Kc; ++k) {
            float bv = v[0]; int bn = lane;
            #pragma unroll
            for (int j = 1; j < 4; ++j) {
                if (v[j] < bv) { bv = v[j]; bn = lane + 64 * j; }
            }
            #pragma unroll
            for (int off = 32; off > 0; off >>= 1) {
                float ov = __shfl_xor(bv, off);
                int   on = __shfl_xor(bn, off);
                if (ov < bv || (ov == bv && on < bn)) { bv = ov; bn = on; }
            }
            bool pad = isinf(bv);
            idxs[k] = pad ? Nc : bn;
            if (lane == k) myrow = pad ? (unsigned)(Bc * Nc + br) : (unsigned)(b * Nc + bn);
            int oj = bn >> 6, ol = bn & 63;
            if (!pad && lane == ol) v[oj] = INFINITY;
        }
        if (lane < Kc) aoff[(size_t)br * 16 + lane] = myrow << 7;

        const float* erow = enc + ((size_t)b * Nc + c) * Dc;
        __hip_bfloat16* hrow = hq + (size_t)br * 768;
        hrow[lane]      = __float2bfloat16(erow[lane]);
        hrow[lane + 64] = __float2bfloat16(erow[lane + 64]);

        if (idxs[Kc - 1] == Nc) {   // wave-uniform cold path: pads exist
            float cnt = 0.f;
            #pragma unroll
            for (int k = 0; k < Kc; ++k) cnt += (idxs[k] < Nc) ? 1.f : 0.f;
            float icnt = 1.f / fmaxf(cnt, 1e-9f);
            #pragma unroll
            for (int half = 0; half < 2; ++half) {
                int d = lane + 64 * half;
                float sum = 0.f;
                #pragma unroll
                for (int k = 0; k < Kc; ++k) {
                    if (idxs[k] < Nc)
                        sum += enc[((size_t)b * Nc + idxs[k]) * Dc + d];
                }
                encb[((size_t)(Bc * Nc) + br) * Dc + d] = __float2bfloat16(sum * icnt);
            }
        }
    }
}

// ---------------------------------------------------------------------------
// Kernel 2: mid-pipeline GEMMs, 64x64 tiles (waves 0-1 stage A, 2-3 stage B):
//  [0,1000)    gemm1: hq[:,128:768] = relu(gather(encb) @ W1t^T + b1), K=1280
//  [1000,1400) kvf = encb @ [Wk|Wv]^T  (K=128)
//  [1400,1600) em  = encb @ Wmb^T      (K=128)
//  [1600,1625) be[i] = bmhc . enc[i]
// ---------------------------------------------------------------------------
__global__ __launch_bounds__(256) void fused_gemms_kernel(
    const __hip_bfloat16* __restrict__ encb, const unsigned* __restrict__ aoff,
    const __hip_bfloat16* __restrict__ W1t, const float* __restrict__ b1,
    const __hip_bfloat16* __restrict__ Wkvt, const __hip_bfloat16* __restrict__ Wmb,
    const float* __restrict__ bmhc, const float* __restrict__ enc,
    __hip_bfloat16* __restrict__ hq, __hip_bfloat16* __restrict__ kvf,
    __hip_bfloat16* __restrict__ em, float* __restrict__ be)
{
    __shared__ short Asl[2][64 * 32];
    __shared__ short Bsl[2][64 * 32];
    int bid = blockIdx.x;
    int tid = threadIdx.x;
    int wave = tid >> 6, lane = tid & 63;
    int lrow = lane >> 2;
    int cg   = lane & 3;
    int ss   = (lane >> 3) & 3;
    int gq   = (cg - ss) & 3;
    int wm = wave >> 1, wn = wave & 1;
    int rrow = lane & 15, quad = lane >> 4;
    int srd  = (rrow >> 1) & 3;
    int strip = (wave & 1) * 32;   // staging strip for this wave's operand

    if (bid < 1000) {
        // ---- gemm1 (gather A, K=1280 fully unrolled), 64x64
        int m0 = (bid / 10) * 64, n0 = (bid % 10) * 64;
        unsigned o0[Kc], o1[Kc];
        if (wave < 2) {
            const unsigned* ap0 = aoff + (size_t)(m0 + strip + lrow) * 16;
            const unsigned* ap1 = ap0 + 16 * 16;
            #pragma unroll
            for (int j = 0; j < Kc; ++j) { o0[j] = ap0[j]; o1[j] = ap1[j]; }
        }
        const short* Eb = (const short*)encb;
        const short* gB0 = (const short*)W1t + (size_t)(n0 + strip + lrow) * 1280 + gq * 8;
        const short* gB1 = gB0 + (size_t)16 * 1280;

        f32x4 acc[2][2];
        #pragma unroll
        for (int i = 0; i < 2; ++i)
            #pragma unroll
            for (int j = 0; j < 2; ++j)
                acc[i][j] = (f32x4){0.f, 0.f, 0.f, 0.f};

        #pragma unroll
        for (int kt = 0; kt < 20; ++kt) {
            int k0 = kt * 64;
            int slot = kt >> 1;
            int dbase = (kt & 1) * 64 + gq * 8;
            __syncthreads();
            #pragma unroll
            for (int s = 0; s < 2; ++s) {
                if (wave < 2) {
                    GLOAD_LDS16(Eb + o0[slot] + dbase + s * 32, &Asl[s][strip * 32]);
                    GLOAD_LDS16(Eb + o1[slot] + dbase + s * 32, &Asl[s][(strip + 16) * 32]);
                } else {
                    GLOAD_LDS16(gB0 + k0 + s * 32, &Bsl[s][strip * 32]);
                    GLOAD_LDS16(gB1 + k0 + s * 32, &Bsl[s][(strip + 16) * 32]);
                }
            }
            __syncthreads();
            #pragma unroll
            for (int s = 0; s < 2; ++s) {
                short8 afr[2], bfr[2];
                #pragma unroll
                for (int mt = 0; mt < 2; ++mt)
                    afr[mt] = *(const short8*)&Asl[s][(wm * 32 + mt * 16 + rrow) * 32 + ((quad + srd) & 3) * 8];
                #pragma unroll
                for (int nt = 0; nt < 2; ++nt)
                    bfr[nt] = *(const short8*)&Bsl[s][(wn * 32 + nt * 16 + rrow) * 32 + ((quad + srd) & 3) * 8];
                #pragma unroll
                for (int mt = 0; mt < 2; ++mt)
                    #pragma unroll
                    for (int nt = 0; nt < 2; ++nt)
                        acc[mt][nt] = __builtin_amdgcn_mfma_f32_16x16x32_bf16(
                            afr[mt], bfr[nt], acc[mt][nt], 0, 0, 0);
            }
        }
        #pragma unroll
        for (int mt = 0; mt < 2; ++mt)
            #pragma unroll
            for (int nt = 0; nt < 2; ++nt) {
                int n = wn * 32 + nt * 16 + rrow;
                float bv = b1[n0 + n];
                #pragma unroll
                for (int i = 0; i < 4; ++i) {
                    int m = m0 + wm * 32 + mt * 16 + quad * 4 + i;
                    float vv = fmaxf(acc[mt][nt][i] + bv, 0.f);
                    hq[(size_t)m * 768 + 128 + n0 + n] = __float2bfloat16(vv);
                }
            }
    } else if (bid < 1600) {
        // ---- kvf or em (K=128, 2 barrier iters), 64x64
        const short* Bbase; __hip_bfloat16* Cout; int ldc, m0, n0;
        if (bid < 1400) {
            int id = bid - 1000;
            Bbase = (const short*)Wkvt; Cout = kvf; ldc = 256;
            m0 = (id >> 2) * 64; n0 = (id & 3) * 64;
        } else {
            int id = bid - 1400;
            Bbase = (const short*)Wmb; Cout = em; ldc = 128;
            m0 = (id >> 1) * 64; n0 = (id & 1) * 64;
        }
        const short* g0 = (wave < 2)
            ? (const short*)encb + (size_t)(m0 + strip + lrow) * 128 + gq * 8
            : Bbase + (size_t)(n0 + strip + lrow) * 128 + gq * 8;
        const short* g1 = g0 + (size_t)16 * 128;

        f32x4 acc[2][2];
        #pragma unroll
        for (int i = 0; i < 2; ++i)
            #pragma unroll
            for (int j = 0; j < 2; ++j)
                acc[i][j] = (f32x4){0.f, 0.f, 0.f, 0.f};

        #pragma unroll
        for (int kt = 0; kt < 2; ++kt) {
            int k0 = kt * 64;
            __syncthreads();
            #pragma unroll
            for (int s = 0; s < 2; ++s) {
                short* l0 = (wave < 2) ? &Asl[s][strip * 32] : &Bsl[s][strip * 32];
                short* l1 = (wave < 2) ? &Asl[s][(strip + 16) * 32] : &Bsl[s][(strip + 16) * 32];
                GLOAD_LDS16(g0 + k0 + s * 32, l0);
                GLOAD_LDS16(g1 + k0 + s * 32, l1);
            }
            __syncthreads();
            #pragma unroll
            for (int s = 0; s < 2; ++s) {
                short8 afr[2], bfr[2];
                #pragma unroll
                for (int mt = 0; mt < 2; ++mt)
                    afr[mt] = *(const short8*)&Asl[s][(wm * 32 + mt * 16 + rrow) * 32 + ((quad + srd) & 3) * 8];
                #pragma unroll
                for (int nt = 0; nt < 2; ++nt)
                    bfr[nt] = *(const short8*)&Bsl[s][(wn * 32 + nt * 16 + rrow) * 32 + ((quad + srd) & 3) * 8];
                #pragma unroll
                for (int mt = 0; mt < 2; ++mt)
                    #pragma unroll
                    for (int nt = 0; nt < 2; ++nt)
                        acc[mt][nt] = __builtin_amdgcn_mfma_f32_16x16x32_bf16(
                            afr[mt], bfr[nt], acc[mt][nt], 0, 0, 0);
            }
        }
        #pragma unroll
        for (int mt = 0; mt < 2; ++mt)
            #pragma unroll
            for (int nt = 0; nt < 2; ++nt) {
                int n = wn * 32 + nt * 16 + rrow;
                #pragma unroll
                for (int i = 0; i < 4; ++i) {
                    int m = m0 + wm * 32 + mt * 16 + quad * 4 + i;
                    Cout[(size_t)m * ldc + n0 + n] = __float2bfloat16(acc[mt][nt][i]);
                }
            }
    } else {
        // ---- be[i] = bmhc . enc[i,:]   (i < Bc*Nc = 6400; 25 blocks)
        int i = (bid - 1600) * 256 + tid;
        if (i < Bc * Nc) {
            const float* row = enc + (size_t)i * 128;
            float acc = 0.f;
            #pragma unroll
            for (int dq = 0; dq < 32; ++dq) {
                float4 e4 = *(const float4*)(row + dq * 4);
                acc = fmaf(bmhc[dq * 4 + 0], e4.x, acc);
                acc = fmaf(bmhc[dq * 4 + 1], e4.y, acc);
                acc = fmaf(bmhc[dq * 4 + 2], e4.z, acc);
                acc = fmaf(bmhc[dq * 4 + 3], e4.w, acc);
            }
            be[i] = acc;
        }
    }
}

// ---------------------------------------------------------------------------
// Kernel 3: q = hq @ Wcat^T + bq  (64x64 tiles, grid (2,100) = 200 blocks)
// ---------------------------------------------------------------------------
__global__ __launch_bounds__(256) void qgemm_kernel(
    const __hip_bfloat16* __restrict__ hq, const __hip_bfloat16* __restrict__ Wcat,
    const float* __restrict__ bq, __hip_bfloat16* __restrict__ q)
{
    __shared__ short Asl[2][64 * 32];
    __shared__ short Bsl[2][64 * 32];
    int tid = threadIdx.x;
    int wave = tid >> 6, lane = tid & 63;
    int m0 = blockIdx.y * 64, n0 = blockIdx.x * 64;
    int lrow = lane >> 2;
    int cg   = lane & 3;
    int ss   = (lane >> 3) & 3;
    int gq   = (cg - ss) & 3;
    int wm = wave >> 1, wn = wave & 1;
    int rrow = lane & 15, quad = lane >> 4;
    int srd  = (rrow >> 1) & 3;
    int strip = (wave & 1) * 32;

    const short* g0 = (wave < 2)
        ? (const short*)hq + (size_t)(m0 + strip + lrow) * 768 + gq * 8
        : (const short*)Wcat + (size_t)(n0 + strip + lrow) * 768 + gq * 8;
    const short* g1 = g0 + (size_t)16 * 768;

    f32x4 acc[2][2];
    #pragma unroll
    for (int i = 0; i < 2; ++i)
        #pragma unroll
        for (int j = 0; j < 2; ++j)
            acc[i][j] = (f32x4){0.f, 0.f, 0.f, 0.f};

    for (int k0 = 0; k0 < 768; k0 += 64) {
        __syncthreads();
        #pragma unroll
        for (int s = 0; s < 2; ++s) {
            short* l0 = (wave < 2) ? &Asl[s][strip * 32] : &Bsl[s][strip * 32];
            short* l1 = (wave < 2) ? &Asl[s][(strip + 16) * 32] : &Bsl[s][(strip + 16) * 32];
            GLOAD_LDS16(g0 + k0 + s * 32, l0);
            GLOAD_LDS16(g1 + k0 + s * 32, l1);
        }
        __syncthreads();
        #pragma unroll
        for (int s = 0; s < 2; ++s) {
            short8 afr[2], bfr[2];
            #pragma unroll
            for (int mt = 0; mt < 2; ++mt)
                afr[mt] = *(const short8*)&Asl[s][(wm * 32 + mt * 16 + rrow) * 32 + ((quad + srd) & 3) * 8];
            #pragma unroll
            for (int nt = 0; nt < 2; ++nt)
                bfr[nt] = *(const short8*)&Bsl[s][(wn * 32 + nt * 16 + rrow) * 32 + ((quad + srd) & 3) * 8];
            #pragma unroll
            for (int mt = 0; mt < 2; ++mt)
                #pragma unroll
                for (int nt = 0; nt < 2; ++nt)
                    acc[mt][nt] = __builtin_amdgcn_mfma_f32_16x16x32_bf16(
                        afr[mt], bfr[nt], acc[mt][nt], 0, 0, 0);
        }
    }

    #pragma unroll
    for (int mt = 0; mt < 2; ++mt) {
        #pragma unroll
        for (int nt = 0; nt < 2; ++nt) {
            int n = wn * 32 + nt * 16 + rrow;
            float bv = bq[n0 + n];
            #pragma unroll
            for (int i = 0; i < 4; ++i) {
                int m = m0 + wm * 32 + mt * 16 + quad * 4 + i;
                q[(size_t)m * 128 + n0 + n] = __float2bfloat16(acc[mt][nt][i] + bv);
            }
        }
    }
}

// ---------------------------------------------------------------------------
// Kernel 4: MFMA flash attention, one block per (b,h), 4 waves.
// ---------------------------------------------------------------------------
__global__ __launch_bounds__(256) void attn_mfma_kernel(
    const __hip_bfloat16* __restrict__ q, const __hip_bfloat16* __restrict__ kvf,
    const u64* __restrict__ maskbits, __hip_bfloat16* __restrict__ att)
{
    constexpr int RP = 208;
    constexpr int QS = 40;
    constexpr int VS = 232;
    __shared__ short Qs[RP * QS];
    __shared__ short Ks[RP * QS];
    __shared__ short Vt[16 * VS];
    __shared__ short Ps[4][16 * VS];
    __shared__ u64 smask[RP][4];

    int b = blockIdx.x >> 3, h = blockIdx.x & 7;
    int t = threadIdx.x;
    int wave = t >> 6, lane = t & 63;
    int rrow = lane & 15, quad = lane >> 4;

    const short8 z8 = {0, 0, 0, 0, 0, 0, 0, 0};
    for (int idx = t; idx < RP * 2; idx += 256) {
        int r = idx >> 1, g = idx & 1;
        short8 qa = z8, ka = z8;
        if (r < Rc) {
            qa = *(const short8*)((const short*)q + ((size_t)(b * Rc + r)) * 128 + h * 16 + g * 8);
            ka = *(const short8*)((const short*)kvf + ((size_t)(b * Nc + r)) * 256 + h * 16 + g * 8);
        }
        *(short8*)&Qs[r * QS + g * 8] = qa;
        *(short8*)&Ks[r * QS + g * 8] = ka;
        *(short8*)&Qs[r * QS + 16 + g * 8] = z8;
        *(short8*)&Ks[r * QS + 16 + g * 8] = z8;
    }
    if (t < Rc) {
        const short* vp = (const short*)kvf + ((size_t)(b * Nc + t)) * 256 + 128 + h * 16;
        short8 v0 = *(const short8*)vp;
        short8 v1 = *(const short8*)(vp + 8);
        #pragma unroll
        for (int d = 0; d < 8; ++d) Vt[d * VS + t] = v0[d];
        #pragma unroll
        for (int d = 0; d < 8; ++d) Vt[(d + 8) * VS + t] = v1[d];
    }
    for (int idx = t; idx < 16 * 32; idx += 256) {
        int d = idx >> 5, cN = 200 + (idx & 31);
        if (cN < VS) Vt[d * VS + cN] = 0;
    }
    for (int idx = lane; idx < 16 * 16; idx += 64) {
        int rr = idx >> 4, cc = 208 + (idx & 15);
        Ps[wave][rr * VS + cc] = 0;
    }
    for (int idx = t; idx < RP * 4; idx += 256) {
        int r = idx >> 2, w = idx & 3;
        smask[r][w] = (r < Rc) ? maskbits[((size_t)b * Rc + r) * 4 + w] : ~0ull;
    }
    __syncthreads();

    for (int rt = wave; rt < 13; rt += 4) {
        short8 qf = *(const short8*)&Qs[(rt * 16 + rrow) * QS + quad * 8];
        f32x4 sacc[13];
        #pragma unroll
        for (int nt = 0; nt < 13; ++nt) {
            short8 kf = *(const short8*)&Ks[(nt * 16 + rrow) * QS + quad * 8];
            sacc[nt] = __builtin_amdgcn_mfma_f32_16x16x32_bf16(
                qf, kf, (f32x4){0.f, 0.f, 0.f, 0.f}, 0, 0, 0);
        }
        float inv[4];
        #pragma unroll
        for (int i = 0; i < 4; ++i) {
            int r = rt * 16 + quad * 4 + i;
            u64 wv0 = smask[r][0], wv1 = smask[r][1], wv2 = smask[r][2], wv3 = smask[r][3];
            float mx = -INFINITY;
            #pragma unroll
            for (int nt = 0; nt < 13; ++nt) {
                u64 w = (nt < 4) ? wv0 : (nt < 8) ? wv1 : (nt < 12) ? wv2 : wv3;
                int sh = ((nt & 3) << 4) + rrow;
                float s = ((w >> sh) & 1ull) ? sacc[nt][i] : -INFINITY;
                sacc[nt][i] = s;
                mx = fmaxf(mx, s);
            }
            mx = fmaxf(mx, __shfl_xor(mx, 1));
            mx = fmaxf(mx, __shfl_xor(mx, 2));
            mx = fmaxf(mx, __shfl_xor(mx, 4));
            mx = fmaxf(mx, __shfl_xor(mx, 8));
            float l = 0.f;
            #pragma unroll
            for (int nt = 0; nt < 13; ++nt) {
                float p = __expf(sacc[nt][i] - mx);
                sacc[nt][i] = p;
                l += p;
            }
            l += __shfl_xor(l, 1);
            l += __shfl_xor(l, 2);
            l += __shfl_xor(l, 4);
            l += __shfl_xor(l, 8);
            inv[i] = (l > 0.f) ? 1.f / l : 0.f;
        }
        #pragma unroll
        for (int nt = 0; nt < 13; ++nt)
            #pragma unroll
            for (int i = 0; i < 4; ++i)
                *(__hip_bfloat16*)&Ps[wave][(quad * 4 + i) * VS + nt * 16 + rrow] =
                    __float2bfloat16(sacc[nt][i]);
        f32x4 oacc = (f32x4){0.f, 0.f, 0.f, 0.f};
        #pragma unroll
        for (int kt = 0; kt < 7; ++kt) {
            short8 pf = *(const short8*)&Ps[wave][rrow * VS + kt * 32 + quad * 8];
            short8 vf = *(const short8*)&Vt[rrow * VS + kt * 32 + quad * 8];
            oacc = __builtin_amdgcn_mfma_f32_16x16x32_bf16(pf, vf, oacc, 0, 0, 0);
        }
        #pragma unroll
        for (int i = 0; i < 4; ++i) {
            int r = rt * 16 + quad * 4 + i;
            if (r < Rc)
                att[((size_t)(b * Rc + r)) * 128 + h * 16 + rrow] =
                    __float2bfloat16(oacc[i] * inv[i]);
        }
    }
}

// ---------------------------------------------------------------------------
// Kernel 5: fused logits + softmax. Block = (b, 64-row tile), grid (32,4) =
// 128 blocks, 72 KB LDS -> 2 blocks/CU. Each wave owns one COMPLETE 16-row
// tile x all 13 n-tiles, so the row softmax is wave-local (16-lane shuffles).
// logits = 10*tanh((att @ em^T + be)/sqrt(128)), masked via maskbits, then
// row-softmaxed; writes final probabilities directly to d_out.
// ---------------------------------------------------------------------------
__global__ __launch_bounds__(256) void logits_softmax_kernel(
    const __hip_bfloat16* __restrict__ att, const __hip_bfloat16* __restrict__ em,
    const float* __restrict__ be, const u64* __restrict__ maskbits,
    float* __restrict__ out)
{
    __shared__ short Asl[4][64 * 32];    // 16 KB (A: att rows, 4 k-chunks)
    __shared__ short Bsl[4][208 * 32];   // 53 KB (B: em rows)
    __shared__ u64 sm[64][4];
    __shared__ float sbe[208];
    int b = blockIdx.x, m0 = blockIdx.y * 64;
    int t = threadIdx.x, wave = t >> 6, lane = t & 63;
    int lrow = lane >> 2, cg = lane & 3, ss = (lane >> 3) & 3, gq = (cg - ss) & 3;
    int rrow = lane & 15, quad = lane >> 4, srd = (rrow >> 1) & 3;

    const short* Aa = (const short*)att + ((size_t)b * Rc + m0) * 128;
    const short* Ben = (const short*)em + (size_t)b * Nc * 128;

    // stage A: each wave stages its own 16-row tile, 4 k-chunks
    #pragma unroll
    for (int kc = 0; kc < 4; ++kc)
        GLOAD_LDS16(Aa + (size_t)(wave * 16 + lrow) * 128 + kc * 32 + gq * 8,
                    &Asl[kc][(wave * 16) * 32]);
    // stage B: 13 row-tiles round-robin across waves
    for (int cch = wave; cch < 13; cch += 4)
        #pragma unroll
        for (int kc = 0; kc < 4; ++kc)
            GLOAD_LDS16(Ben + (size_t)(cch * 16 + lrow) * 128 + kc * 32 + gq * 8,
                        &Bsl[kc][(cch * 16) * 32]);
    {
        int r = t >> 2, w = t & 3;   // 256 threads = 64 rows x 4 words
        sm[r][w] = (m0 + r < Rc) ? maskbits[((size_t)b * Rc + m0 + r) * 4 + w] : 0ull;
    }
    if (t < 208) sbe[t] = (t < Nc) ? be[(size_t)b * Nc + t] : 0.f;
    __syncthreads();

    short8 afr[4];
    #pragma unroll
    for (int kc = 0; kc < 4; ++kc)
        afr[kc] = *(const short8*)&Asl[kc][(wave * 16 + rrow) * 32 + ((quad + srd) & 3) * 8];

    f32x4 acc[13];
    #pragma unroll
    for (int nt = 0; nt < 13; ++nt)
        acc[nt] = (f32x4){0.f, 0.f, 0.f, 0.f};
    #pragma unroll
    for (int nt = 0; nt < 13; ++nt)
        #pragma unroll
        for (int kc = 0; kc < 4; ++kc) {
            short8 bfr = *(const short8*)
                &Bsl[kc][(nt * 16 + rrow) * 32 + ((quad + srd) & 3) * 8];
            acc[nt] = __builtin_amdgcn_mfma_f32_16x16x32_bf16(afr[kc], bfr, acc[nt], 0, 0, 0);
        }

    const float scale = 0.08838834764831843f;  // 1/sqrt(128)
    #pragma unroll
    for (int i = 0; i < 4; ++i) {
        int rloc = wave * 16 + quad * 4 + i;
        int r = m0 + rloc;
        u64 w0 = sm[rloc][0], w1 = sm[rloc][1], w2 = sm[rloc][2], w3 = sm[rloc][3];
        float vals[13];
        float mx = -INFINITY;
        #pragma unroll
        for (int nt = 0; nt < 13; ++nt) {
            u64 w = (nt < 4) ? w0 : (nt < 8) ? w1 : (nt < 12) ? w2 : w3;
            int sh = ((nt & 3) << 4) + rrow;
            float lg = ((w >> sh) & 1ull)
                     ? 10.f * tanhf((acc[nt][i] + sbe[nt * 16 + rrow]) * scale)
                     : -INFINITY;
            vals[nt] = lg;
            mx = fmaxf(mx, lg);
        }
        mx = fmaxf(mx, __shfl_xor(mx, 1));
        mx = fmaxf(mx, __shfl_xor(mx, 2));
        mx = fmaxf(mx, __shfl_xor(mx, 4));
        mx = fmaxf(mx, __shfl_xor(mx, 8));
        float l = 0.f;
        #pragma unroll
        for (int nt = 0; nt < 13; ++nt) {
            float p = (vals[nt] == -INFINITY) ? 0.f : __expf(vals[nt] - mx);
            vals[nt] = p;
            l += p;
        }
        l += __shfl_xor(l, 1);
        l += __shfl_xor(l, 2);
        l += __shfl_xor(l, 4);
        l += __shfl_xor(l, 8);
        float inv = (l > 0.f) ? 1.f / l : 0.f;
        if (r < Rc) {
            #pragma unroll
            for (int nt = 0; nt < 13; ++nt) {
                int n = nt * 16 + rrow;
                if (n < Nc)
                    out[((size_t)b * Rc + r) * Nc + n] = vals[nt] * inv;
            }
        }
    }
}

// ---------------------------------------------------------------------------
extern "C" void kernel_launch(void* const* d_in, const int* in_sizes, int n_in,
                              void* d_out, int out_size, void* d_ws, size_t ws_size,
                              hipStream_t stream)
{
    const float* enc  = (const float*)d_in[0];
    const float* dist = (const float*)d_in[1];
    const float* mask = (const float*)d_in[2];
    const int*   cur  = (const int*)d_in[3];
    const float* Wq   = (const float*)d_in[4];
    const float* Wk   = (const float*)d_in[5];
    const float* Wv   = (const float*)d_in[6];
    const float* Wmhc = (const float*)d_in[7];
    const float* bmhc = (const float*)d_in[8];
    const float* W1   = (const float*)d_in[9];
    const float* b1   = (const float*)d_in[10];
    const float* W2   = (const float*)d_in[11];
    const float* b2   = (const float*)d_in[12];
    float* out = (float*)d_out;

    char* ws = (char*)d_ws;
    size_t off = 0;
    auto alloc = [&](size_t bytes) { char* p = ws + off; off += (bytes + 255) & ~(size_t)255; return p; };
    __hip_bfloat16* W1t  = (__hip_bfloat16*)alloc((size_t)640 * 1280 * 2);
    __hip_bfloat16* Wkvt = (__hip_bfloat16*)alloc((size_t)256 * 128 * 2);
    __hip_bfloat16* Wmb  = (__hip_bfloat16*)alloc((size_t)128 * 128 * 2);
    __hip_bfloat16* Wcat = (__hip_bfloat16*)alloc((size_t)128 * 768 * 2);
    float* bq = (float*)alloc((size_t)128 * 4);
    // encb: rows [0, Bc*Nc) = enc bf16; rows [Bc*Nc, Bc*Nc+BRc) = mean rows
    __hip_bfloat16* encb = (__hip_bfloat16*)alloc((size_t)(Bc * Nc + BRc + 64) * Dc * 2);
    unsigned* aoff = (unsigned*)alloc((size_t)BRc * 16 * 4);
    __hip_bfloat16* hq   = (__hip_bfloat16*)alloc((size_t)BRc * 768 * 2);
    __hip_bfloat16* q    = (__hip_bfloat16*)alloc((size_t)BRc * 128 * 2);
    __hip_bfloat16* kvf  = (__hip_bfloat16*)alloc((size_t)Bc * Nc * 256 * 2);
    __hip_bfloat16* att  = (__hip_bfloat16*)alloc((size_t)(BRc + 64) * 128 * 2);
    __hip_bfloat16* em   = (__hip_bfloat16*)alloc((size_t)(Bc * Nc + 64) * 128 * 2);
    float* be = (float*)alloc((size_t)Bc * Nc * 4);
    u64* maskbits = (u64*)alloc((size_t)BRc * 4 * 8);

    // 1) prep + kNN (independent roles, one launch, 2530 blocks)
    prep_knn_kernel<<<2530, 256, 0, stream>>>(
        W1, W2, Wq, Wmhc, Wk, Wv, b2, enc, dist, mask, cur,
        W1t, Wkvt, Wmb, Wcat, bq, encb, aoff, hq, maskbits);
    // 2) gemm1 + kvf + em + be (64x64 tiles, one launch, 1625 blocks)
    fused_gemms_kernel<<<1625, 256, 0, stream>>>(
        encb, aoff, W1t, b1, Wkvt, Wmb, bmhc, enc, hq, kvf, em, be);
    // 3) q = hq @ Wcat^T + bq  (64x64 tiles, 200 blocks)
    qgemm_kernel<<<dim3(2, BRc / 64), 256, 0, stream>>>(hq, Wcat, bq, q);
    // 4) MFMA flash attention
    attn_mfma_kernel<<<Bc * Hc, 256, 0, stream>>>(q, kvf, maskbits, att);
    // 5) fused logits + softmax -> final probabilities in d_out
    logits_softmax_kernel<<<dim3(Bc, 4), 256, 0, stream>>>(att, em, be, maskbits, out);
}

// Round 15
// 173.423 us; speedup vs baseline: 1.4414x; 1.0251x over previous
//
#include <hip/hip_runtime.h>
#include <hip/hip_bf16.h>
#include <math.h>

#define Bc 32
#define Rc 200
#define Nc 200
#define Dc 128
#define Hc 8
#define QKc 16
#define Kc 10
#define BRc (Bc*Rc)

typedef __attribute__((ext_vector_type(8))) short short8;
typedef __attribute__((ext_vector_type(4))) float f32x4;
typedef unsigned long long u64;

#define GLOAD_LDS16(g, l) __builtin_amdgcn_global_load_lds( \
    (const __attribute__((address_space(1))) void*)(g), \
    (__attribute__((address_space(3))) void*)(l), 16, 0, 0)

// ---------------------------------------------------------------------------
// 32x32 transpose+convert tile helper (block-uniform call sites only)
// ---------------------------------------------------------------------------
__device__ inline void transpose_tile(const float* __restrict__ src, int lds_,
                                      __hip_bfloat16* __restrict__ dst, int ldd,
                                      int k0, int n0, float scale)
{
    __shared__ float tile[32][33];
    int tx = threadIdx.x & 31, ty = threadIdx.x >> 5;  // 32 x 8
    #pragma unroll
    for (int i = ty; i < 32; i += 8)
        tile[i][tx] = src[(size_t)(k0 + i) * lds_ + n0 + tx];
    __syncthreads();
    #pragma unroll
    for (int i = ty; i < 32; i += 8)
        dst[(size_t)(n0 + i) * ldd + k0 + tx] = __float2bfloat16(tile[tx][i] * scale);
}

// ---------------------------------------------------------------------------
// Kernel 1: prep + kNN fused (independent roles, one launch).
//  [0,800)    W1 -> W1t   [800,816) Wk   [816,832) Wv   [832,848) Wmhc->Wmb
//  [848,864)  Wq top -> Wcat[:,0:128] (x0.25)
//  [864,904)  Wfused = W2 @ Wq_bot (fp32) -> Wcat[:,128:768] (x0.25)
//  [904,929)  enc -> encb bf16    [929] bq
//  [930,2530) kNN: wave-per-row, register-only butterfly top-10.
// ---------------------------------------------------------------------------
__global__ __launch_bounds__(256) void prep_knn_kernel(
    const float* __restrict__ W1, const float* __restrict__ W2,
    const float* __restrict__ Wq, const float* __restrict__ Wmhc,
    const float* __restrict__ Wk, const float* __restrict__ Wv,
    const float* __restrict__ b2, const float* __restrict__ enc,
    const float* __restrict__ dist, const float* __restrict__ mask,
    const int* __restrict__ cur,
    __hip_bfloat16* __restrict__ W1t, __hip_bfloat16* __restrict__ Wkvt,
    __hip_bfloat16* __restrict__ Wmb, __hip_bfloat16* __restrict__ Wcat,
    float* __restrict__ bq, __hip_bfloat16* __restrict__ encb,
    unsigned* __restrict__ aoff, __hip_bfloat16* __restrict__ hq,
    u64* __restrict__ maskbits)
{
    int bid = blockIdx.x;
    int t = threadIdx.x;
    if (bid < 800) {
        transpose_tile(W1, 640, W1t, 1280, (bid % 40) * 32, (bid / 40) * 32, 1.f);
    } else if (bid < 816) {
        int id = bid - 800;
        transpose_tile(Wk, 128, Wkvt, 128, (id & 3) * 32, (id >> 2) * 32, 1.f);
    } else if (bid < 832) {
        int id = bid - 816;
        transpose_tile(Wv, 128, Wkvt + 128 * 128, 128, (id & 3) * 32, (id >> 2) * 32, 1.f);
    } else if (bid < 848) {
        int e = (bid - 832) * 1024 + t * 4;
        #pragma unroll
        for (int j = 0; j < 4; ++j) Wmb[e + j] = __float2bfloat16(Wmhc[e + j]);
    } else if (bid < 864) {
        int id = bid - 848;
        transpose_tile(Wq, 128, Wcat, 768, (id & 3) * 32, (id >> 2) * 32, 0.25f);
    } else if (bid < 904) {
        int j0 = (bid - 864) * 16;
        int n = t & 127, half = t >> 7;
        #pragma unroll
        for (int jj = 0; jj < 8; ++jj) {
            int j = j0 + half * 8 + jj;
            float acc = 0.f;
            for (int k = 0; k < 128; ++k)
                acc = fmaf(W2[(size_t)j * 128 + k], Wq[(size_t)(128 + k) * 128 + n], acc);
            Wcat[(size_t)n * 768 + 128 + j] = __float2bfloat16(acc * 0.25f);
        }
    } else if (bid < 929) {
        size_t base = (size_t)(bid - 904) * 32768 + (size_t)t * 4;
        #pragma unroll 4
        for (int it = 0; it < 32; ++it) {
            size_t i = base + (size_t)it * 1024;
            float4 v = *(const float4*)(enc + i);
            encb[i + 0] = __float2bfloat16(v.x);
            encb[i + 1] = __float2bfloat16(v.y);
            encb[i + 2] = __float2bfloat16(v.z);
            encb[i + 3] = __float2bfloat16(v.w);
        }
    } else if (bid == 929) {
        if (t < 128) {
            float acc = 0.f;
            for (int k = 0; k < 128; ++k)
                acc = fmaf(b2[k], Wq[(size_t)(128 + k) * 128 + t], acc);
            bq[t] = acc * 0.25f;
        }
    } else {
        // kNN role: wave-per-row, register-only
        int lane = t & 63, w = t >> 6;
        int br = (bid - 930) * 4 + w;
        int b = br / Rc;
        int c = cur[br];
        const float* drow = dist + ((size_t)b * Nc + c) * Nc;
        const float* mrow = mask + (size_t)br * Nc;

        float v[4];
        #pragma unroll
        for (int j = 0; j < 4; ++j) {
            int n = lane + 64 * j;
            bool allowed = false;
            float val = INFINITY;
            if (n < Nc) {
                float mv = mrow[n];
                if (!isinf(mv)) { val = drow[n]; allowed = true; }
            }
            v[j] = val;
            u64 wb = __ballot(allowed);
            if (lane == 0) maskbits[(size_t)br * 4 + j] = wb;
        }
        int idxs[Kc];
        unsigned myrow = 0;
        #pragma unroll
        for (int k = 0; k < Kc; ++k) {
            float bv = v[0]; int bn = lane;
            #pragma unroll
            for (int j = 1; j < 4; ++j) {
                if (v[j] < bv) { bv = v[j]; bn = lane + 64 * j; }
            }
            #pragma unroll
            for (int off = 32; off > 0; off >>= 1) {
                float ov = __shfl_xor(bv, off);
                int   on = __shfl_xor(bn, off);
                if (ov < bv || (ov == bv && on < bn)) { bv = ov; bn = on; }
            }
            bool pad = isinf(bv);
            idxs[k] = pad ? Nc : bn;
            if (lane == k) myrow = pad ? (unsigned)(Bc * Nc + br) : (unsigned)(b * Nc + bn);
            int oj = bn >> 6, ol = bn & 63;
            if (!pad && lane == ol) v[oj] = INFINITY;
        }
        if (lane < Kc) aoff[(size_t)br * 16 + lane] = myrow << 7;

        const float* erow = enc + ((size_t)b * Nc + c) * Dc;
        __hip_bfloat16* hrow = hq + (size_t)br * 768;
        hrow[lane]      = __float2bfloat16(erow[lane]);
        hrow[lane + 64] = __float2bfloat16(erow[lane + 64]);

        if (idxs[Kc - 1] == Nc) {   // wave-uniform cold path: pads exist
            float cnt = 0.f;
            #pragma unroll
            for (int k = 0; k < Kc; ++k) cnt += (idxs[k] < Nc) ? 1.f : 0.f;
            float icnt = 1.f / fmaxf(cnt, 1e-9f);
            #pragma unroll
            for (int half = 0; half < 2; ++half) {
                int d = lane + 64 * half;
                float sum = 0.f;
                #pragma unroll
                for (int k = 0; k < Kc; ++k) {
                    if (idxs[k] < Nc)
                        sum += enc[((size_t)b * Nc + idxs[k]) * Dc + d];
                }
                encb[((size_t)(Bc * Nc) + br) * Dc + d] = __float2bfloat16(sum * icnt);
            }
        }
    }
}

// ---------------------------------------------------------------------------
// Kernel 2: mid-pipeline GEMMs, 64x64 tiles (waves 0-1 stage A, 2-3 stage B):
//  [0,1000)    gemm1: hq[:,128:768] = relu(gather(encb) @ W1t^T + b1), K=1280
//  [1000,1400) kvf = encb @ [Wk|Wv]^T  (K=128)
//  [1400,1600) em  = encb @ Wmb^T      (K=128)
//  [1600,1625) be[i] = bmhc . enc[i]
// ---------------------------------------------------------------------------
__global__ __launch_bounds__(256) void fused_gemms_kernel(
    const __hip_bfloat16* __restrict__ encb, const unsigned* __restrict__ aoff,
    const __hip_bfloat16* __restrict__ W1t, const float* __restrict__ b1,
    const __hip_bfloat16* __restrict__ Wkvt, const __hip_bfloat16* __restrict__ Wmb,
    const float* __restrict__ bmhc, const float* __restrict__ enc,
    __hip_bfloat16* __restrict__ hq, __hip_bfloat16* __restrict__ kvf,
    __hip_bfloat16* __restrict__ em, float* __restrict__ be)
{
    __shared__ short Asl[2][64 * 32];
    __shared__ short Bsl[2][64 * 32];
    int bid = blockIdx.x;
    int tid = threadIdx.x;
    int wave = tid >> 6, lane = tid & 63;
    int lrow = lane >> 2;
    int cg   = lane & 3;
    int ss   = (lane >> 3) & 3;
    int gq   = (cg - ss) & 3;
    int wm = wave >> 1, wn = wave & 1;
    int rrow = lane & 15, quad = lane >> 4;
    int srd  = (rrow >> 1) & 3;
    int strip = (wave & 1) * 32;   // staging strip for this wave's operand

    if (bid < 1000) {
        // ---- gemm1 (gather A, K=1280 fully unrolled), 64x64
        int m0 = (bid / 10) * 64, n0 = (bid % 10) * 64;
        unsigned o0[Kc], o1[Kc];
        if (wave < 2) {
            const unsigned* ap0 = aoff + (size_t)(m0 + strip + lrow) * 16;
            const unsigned* ap1 = ap0 + 16 * 16;
            #pragma unroll
            for (int j = 0; j < Kc; ++j) { o0[j] = ap0[j]; o1[j] = ap1[j]; }
        }
        const short* Eb = (const short*)encb;
        const short* gB0 = (const short*)W1t + (size_t)(n0 + strip + lrow) * 1280 + gq * 8;
        const short* gB1 = gB0 + (size_t)16 * 1280;

        f32x4 acc[2][2];
        #pragma unroll
        for (int i = 0; i < 2; ++i)
            #pragma unroll
            for (int j = 0; j < 2; ++j)
                acc[i][j] = (f32x4){0.f, 0.f, 0.f, 0.f};

        #pragma unroll
        for (int kt = 0; kt < 20; ++kt) {
            int k0 = kt * 64;
            int slot = kt >> 1;
            int dbase = (kt & 1) * 64 + gq * 8;
            __syncthreads();
            #pragma unroll
            for (int s = 0; s < 2; ++s) {
                if (wave < 2) {
                    GLOAD_LDS16(Eb + o0[slot] + dbase + s * 32, &Asl[s][strip * 32]);
                    GLOAD_LDS16(Eb + o1[slot] + dbase + s * 32, &Asl[s][(strip + 16) * 32]);
                } else {
                    GLOAD_LDS16(gB0 + k0 + s * 32, &Bsl[s][strip * 32]);
                    GLOAD_LDS16(gB1 + k0 + s * 32, &Bsl[s][(strip + 16) * 32]);
                }
            }
            __syncthreads();
            #pragma unroll
            for (int s = 0; s < 2; ++s) {
                short8 afr[2], bfr[2];
                #pragma unroll
                for (int mt = 0; mt < 2; ++mt)
                    afr[mt] = *(const short8*)&Asl[s][(wm * 32 + mt * 16 + rrow) * 32 + ((quad + srd) & 3) * 8];
                #pragma unroll
                for (int nt = 0; nt < 2; ++nt)
                    bfr[nt] = *(const short8*)&Bsl[s][(wn * 32 + nt * 16 + rrow) * 32 + ((quad + srd) & 3) * 8];
                #pragma unroll
                for (int mt = 0; mt < 2; ++mt)
                    #pragma unroll
                    for (int nt = 0; nt < 2; ++nt)
                        acc[mt][nt] = __builtin_amdgcn_mfma_f32_16x16x32_bf16(
                            afr[mt], bfr[nt], acc[mt][nt], 0, 0, 0);
            }
        }
        #pragma unroll
        for (int mt = 0; mt < 2; ++mt)
            #pragma unroll
            for (int nt = 0; nt < 2; ++nt) {
                int n = wn * 32 + nt * 16 + rrow;
                float bv = b1[n0 + n];
                #pragma unroll
                for (int i = 0; i < 4; ++i) {
                    int m = m0 + wm * 32 + mt * 16 + quad * 4 + i;
                    float vv = fmaxf(acc[mt][nt][i] + bv, 0.f);
                    hq[(size_t)m * 768 + 128 + n0 + n] = __float2bfloat16(vv);
                }
            }
    } else if (bid < 1600) {
        // ---- kvf or em (K=128, 2 barrier iters), 64x64
        const short* Bbase; __hip_bfloat16* Cout; int ldc, m0, n0;
        if (bid < 1400) {
            int id = bid - 1000;
            Bbase = (const short*)Wkvt; Cout = kvf; ldc = 256;
            m0 = (id >> 2) * 64; n0 = (id & 3) * 64;
        } else {
            int id = bid - 1400;
            Bbase = (const short*)Wmb; Cout = em; ldc = 128;
            m0 = (id >> 1) * 64; n0 = (id & 1) * 64;
        }
        const short* g0 = (wave < 2)
            ? (const short*)encb + (size_t)(m0 + strip + lrow) * 128 + gq * 8
            : Bbase + (size_t)(n0 + strip + lrow) * 128 + gq * 8;
        const short* g1 = g0 + (size_t)16 * 128;

        f32x4 acc[2][2];
        #pragma unroll
        for (int i = 0; i < 2; ++i)
            #pragma unroll
            for (int j = 0; j < 2; ++j)
                acc[i][j] = (f32x4){0.f, 0.f, 0.f, 0.f};

        #pragma unroll
        for (int kt = 0; kt < 2; ++kt) {
            int k0 = kt * 64;
            __syncthreads();
            #pragma unroll
            for (int s = 0; s < 2; ++s) {
                short* l0 = (wave < 2) ? &Asl[s][strip * 32] : &Bsl[s][strip * 32];
                short* l1 = (wave < 2) ? &Asl[s][(strip + 16) * 32] : &Bsl[s][(strip + 16) * 32];
                GLOAD_LDS16(g0 + k0 + s * 32, l0);
                GLOAD_LDS16(g1 + k0 + s * 32, l1);
            }
            __syncthreads();
            #pragma unroll
            for (int s = 0; s < 2; ++s) {
                short8 afr[2], bfr[2];
                #pragma unroll
                for (int mt = 0; mt < 2; ++mt)
                    afr[mt] = *(const short8*)&Asl[s][(wm * 32 + mt * 16 + rrow) * 32 + ((quad + srd) & 3) * 8];
                #pragma unroll
                for (int nt = 0; nt < 2; ++nt)
                    bfr[nt] = *(const short8*)&Bsl[s][(wn * 32 + nt * 16 + rrow) * 32 + ((quad + srd) & 3) * 8];
                #pragma unroll
                for (int mt = 0; mt < 2; ++mt)
                    #pragma unroll
                    for (int nt = 0; nt < 2; ++nt)
                        acc[mt][nt] = __builtin_amdgcn_mfma_f32_16x16x32_bf16(
                            afr[mt], bfr[nt], acc[mt][nt], 0, 0, 0);
            }
        }
        #pragma unroll
        for (int mt = 0; mt < 2; ++mt)
            #pragma unroll
            for (int nt = 0; nt < 2; ++nt) {
                int n = wn * 32 + nt * 16 + rrow;
                #pragma unroll
                for (int i = 0; i < 4; ++i) {
                    int m = m0 + wm * 32 + mt * 16 + quad * 4 + i;
                    Cout[(size_t)m * ldc + n0 + n] = __float2bfloat16(acc[mt][nt][i]);
                }
            }
    } else {
        // ---- be[i] = bmhc . enc[i,:]   (i < Bc*Nc = 6400; 25 blocks)
        int i = (bid - 1600) * 256 + tid;
        if (i < Bc * Nc) {
            const float* row = enc + (size_t)i * 128;
            float acc = 0.f;
            #pragma unroll
            for (int dq = 0; dq < 32; ++dq) {
                float4 e4 = *(const float4*)(row + dq * 4);
                acc = fmaf(bmhc[dq * 4 + 0], e4.x, acc);
                acc = fmaf(bmhc[dq * 4 + 1], e4.y, acc);
                acc = fmaf(bmhc[dq * 4 + 2], e4.z, acc);
                acc = fmaf(bmhc[dq * 4 + 3], e4.w, acc);
            }
            be[i] = acc;
        }
    }
}

// ---------------------------------------------------------------------------
// Kernel 3: q = hq @ Wcat^T + bq  (64x64 tiles, grid (2,100) = 200 blocks)
// ---------------------------------------------------------------------------
__global__ __launch_bounds__(256) void qgemm_kernel(
    const __hip_bfloat16* __restrict__ hq, const __hip_bfloat16* __restrict__ Wcat,
    const float* __restrict__ bq, __hip_bfloat16* __restrict__ q)
{
    __shared__ short Asl[2][64 * 32];
    __shared__ short Bsl[2][64 * 32];
    int tid = threadIdx.x;
    int wave = tid >> 6, lane = tid & 63;
    int m0 = blockIdx.y * 64, n0 = blockIdx.x * 64;
    int lrow = lane >> 2;
    int cg   = lane & 3;
    int ss   = (lane >> 3) & 3;
    int gq   = (cg - ss) & 3;
    int wm = wave >> 1, wn = wave & 1;
    int rrow = lane & 15, quad = lane >> 4;
    int srd  = (rrow >> 1) & 3;
    int strip = (wave & 1) * 32;

    const short* g0 = (wave < 2)
        ? (const short*)hq + (size_t)(m0 + strip + lrow) * 768 + gq * 8
        : (const short*)Wcat + (size_t)(n0 + strip + lrow) * 768 + gq * 8;
    const short* g1 = g0 + (size_t)16 * 768;

    f32x4 acc[2][2];
    #pragma unroll
    for (int i = 0; i < 2; ++i)
        #pragma unroll
        for (int j = 0; j < 2; ++j)
            acc[i][j] = (f32x4){0.f, 0.f, 0.f, 0.f};

    for (int k0 = 0; k0 < 768; k0 += 64) {
        __syncthreads();
        #pragma unroll
        for (int s = 0; s < 2; ++s) {
            short* l0 = (wave < 2) ? &Asl[s][strip * 32] : &Bsl[s][strip * 32];
            short* l1 = (wave < 2) ? &Asl[s][(strip + 16) * 32] : &Bsl[s][(strip + 16) * 32];
            GLOAD_LDS16(g0 + k0 + s * 32, l0);
            GLOAD_LDS16(g1 + k0 + s * 32, l1);
        }
        __syncthreads();
        #pragma unroll
        for (int s = 0; s < 2; ++s) {
            short8 afr[2], bfr[2];
            #pragma unroll
            for (int mt = 0; mt < 2; ++mt)
                afr[mt] = *(const short8*)&Asl[s][(wm * 32 + mt * 16 + rrow) * 32 + ((quad + srd) & 3) * 8];
            #pragma unroll
            for (int nt = 0; nt < 2; ++nt)
                bfr[nt] = *(const short8*)&Bsl[s][(wn * 32 + nt * 16 + rrow) * 32 + ((quad + srd) & 3) * 8];
            #pragma unroll
            for (int mt = 0; mt < 2; ++mt)
                #pragma unroll
                for (int nt = 0; nt < 2; ++nt)
                    acc[mt][nt] = __builtin_amdgcn_mfma_f32_16x16x32_bf16(
                        afr[mt], bfr[nt], acc[mt][nt], 0, 0, 0);
        }
    }

    #pragma unroll
    for (int mt = 0; mt < 2; ++mt) {
        #pragma unroll
        for (int nt = 0; nt < 2; ++nt) {
            int n = wn * 32 + nt * 16 + rrow;
            float bv = bq[n0 + n];
            #pragma unroll
            for (int i = 0; i < 4; ++i) {
                int m = m0 + wm * 32 + mt * 16 + quad * 4 + i;
                q[(size_t)m * 128 + n0 + n] = __float2bfloat16(acc[mt][nt][i] + bv);
            }
        }
    }
}

// ---------------------------------------------------------------------------
// Kernel 4: MFMA flash attention. Grid (Bc*Hc, 2): blockIdx.y selects the
// row-tile half (tiles 0-6 / 7-12) -> 512 blocks = 2 blocks/CU, 8 waves/CU.
// K/V/mask staging duplicated per half (L2-resident, negligible).
// ---------------------------------------------------------------------------
__global__ __launch_bounds__(256) void attn_mfma_kernel(
    const __hip_bfloat16* __restrict__ q, const __hip_bfloat16* __restrict__ kvf,
    const u64* __restrict__ maskbits, __hip_bfloat16* __restrict__ att)
{
    constexpr int RP = 208;
    constexpr int QS = 40;
    constexpr int VS = 232;
    __shared__ short Qs[RP * QS];
    __shared__ short Ks[RP * QS];
    __shared__ short Vt[16 * VS];
    __shared__ short Ps[4][16 * VS];
    __shared__ u64 smask[RP][4];

    int b = blockIdx.x >> 3, h = blockIdx.x & 7;
    int half = blockIdx.y;
    int t = threadIdx.x;
    int wave = t >> 6, lane = t & 63;
    int rrow = lane & 15, quad = lane >> 4;

    const short8 z8 = {0, 0, 0, 0, 0, 0, 0, 0};
    for (int idx = t; idx < RP * 2; idx += 256) {
        int r = idx >> 1, g = idx & 1;
        short8 qa = z8, ka = z8;
        if (r < Rc) {
            qa = *(const short8*)((const short*)q + ((size_t)(b * Rc + r)) * 128 + h * 16 + g * 8);
            ka = *(const short8*)((const short*)kvf + ((size_t)(b * Nc + r)) * 256 + h * 16 + g * 8);
        }
        *(short8*)&Qs[r * QS + g * 8] = qa;
        *(short8*)&Ks[r * QS + g * 8] = ka;
        *(short8*)&Qs[r * QS + 16 + g * 8] = z8;
        *(short8*)&Ks[r * QS + 16 + g * 8] = z8;
    }
    if (t < Rc) {
        const short* vp = (const short*)kvf + ((size_t)(b * Nc + t)) * 256 + 128 + h * 16;
        short8 v0 = *(const short8*)vp;
        short8 v1 = *(const short8*)(vp + 8);
        #pragma unroll
        for (int d = 0; d < 8; ++d) Vt[d * VS + t] = v0[d];
        #pragma unroll
        for (int d = 0; d < 8; ++d) Vt[(d + 8) * VS + t] = v1[d];
    }
    for (int idx = t; idx < 16 * 32; idx += 256) {
        int d = idx >> 5, cN = 200 + (idx & 31);
        if (cN < VS) Vt[d * VS + cN] = 0;
    }
    for (int idx = lane; idx < 16 * 16; idx += 64) {
        int rr = idx >> 4, cc = 208 + (idx & 15);
        Ps[wave][rr * VS + cc] = 0;
    }
    for (int idx = t; idx < RP * 4; idx += 256) {
        int r = idx >> 2, w = idx & 3;
        smask[r][w] = (r < Rc) ? maskbits[((size_t)b * Rc + r) * 4 + w] : ~0ull;
    }
    __syncthreads();

    int rt0 = half * 7, rt1 = half ? 13 : 7;
    for (int rt = rt0 + wave; rt < rt1; rt += 4) {
        short8 qf = *(const short8*)&Qs[(rt * 16 + rrow) * QS + quad * 8];
        f32x4 sacc[13];
        #pragma unroll
        for (int nt = 0; nt < 13; ++nt) {
            short8 kf = *(const short8*)&Ks[(nt * 16 + rrow) * QS + quad * 8];
            sacc[nt] = __builtin_amdgcn_mfma_f32_16x16x32_bf16(
                qf, kf, (f32x4){0.f, 0.f, 0.f, 0.f}, 0, 0, 0);
        }
        float inv[4];
        #pragma unroll
        for (int i = 0; i < 4; ++i) {
            int r = rt * 16 + quad * 4 + i;
            u64 wv0 = smask[r][0], wv1 = smask[r][1], wv2 = smask[r][2], wv3 = smask[r][3];
            float mx = -INFINITY;
            #pragma unroll
            for (int nt = 0; nt < 13; ++nt) {
                u64 w = (nt < 4) ? wv0 : (nt < 8) ? wv1 : (nt < 12) ? wv2 : wv3;
                int sh = ((nt & 3) << 4) + rrow;
                float s = ((w >> sh) & 1ull) ? sacc[nt][i] : -INFINITY;
                sacc[nt][i] = s;
                mx = fmaxf(mx, s);
            }
            mx = fmaxf(mx, __shfl_xor(mx, 1));
            mx = fmaxf(mx, __shfl_xor(mx, 2));
            mx = fmaxf(mx, __shfl_xor(mx, 4));
            mx = fmaxf(mx, __shfl_xor(mx, 8));
            float l = 0.f;
            #pragma unroll
            for (int nt = 0; nt < 13; ++nt) {
                float p = __expf(sacc[nt][i] - mx);
                sacc[nt][i] = p;
                l += p;
            }
            l += __shfl_xor(l, 1);
            l += __shfl_xor(l, 2);
            l += __shfl_xor(l, 4);
            l += __shfl_xor(l, 8);
            inv[i] = (l > 0.f) ? 1.f / l : 0.f;
        }
        #pragma unroll
        for (int nt = 0; nt < 13; ++nt)
            #pragma unroll
            for (int i = 0; i < 4; ++i)
                *(__hip_bfloat16*)&Ps[wave][(quad * 4 + i) * VS + nt * 16 + rrow] =
                    __float2bfloat16(sacc[nt][i]);
        f32x4 oacc = (f32x4){0.f, 0.f, 0.f, 0.f};
        #pragma unroll
        for (int kt = 0; kt < 7; ++kt) {
            short8 pf = *(const short8*)&Ps[wave][rrow * VS + kt * 32 + quad * 8];
            short8 vf = *(const short8*)&Vt[rrow * VS + kt * 32 + quad * 8];
            oacc = __builtin_amdgcn_mfma_f32_16x16x32_bf16(pf, vf, oacc, 0, 0, 0);
        }
        #pragma unroll
        for (int i = 0; i < 4; ++i) {
            int r = rt * 16 + quad * 4 + i;
            if (r < Rc)
                att[((size_t)(b * Rc + r)) * 128 + h * 16 + rrow] =
                    __float2bfloat16(oacc[i] * inv[i]);
        }
    }
}

// ---------------------------------------------------------------------------
// Kernel 5: fused logits + softmax. Block = (b, 64-row tile), grid (32,4) =
// 128 blocks, 72 KB LDS -> 2 blocks/CU. Each wave owns one COMPLETE 16-row
// tile x all 13 n-tiles, so the row softmax is wave-local (16-lane shuffles).
// ---------------------------------------------------------------------------
__global__ __launch_bounds__(256) void logits_softmax_kernel(
    const __hip_bfloat16* __restrict__ att, const __hip_bfloat16* __restrict__ em,
    const float* __restrict__ be, const u64* __restrict__ maskbits,
    float* __restrict__ out)
{
    __shared__ short Asl[4][64 * 32];    // 16 KB
    __shared__ short Bsl[4][208 * 32];   // 53 KB
    __shared__ u64 sm[64][4];
    __shared__ float sbe[208];
    int b = blockIdx.x, m0 = blockIdx.y * 64;
    int t = threadIdx.x, wave = t >> 6, lane = t & 63;
    int lrow = lane >> 2, cg = lane & 3, ss = (lane >> 3) & 3, gq = (cg - ss) & 3;
    int rrow = lane & 15, quad = lane >> 4, srd = (rrow >> 1) & 3;

    const short* Aa = (const short*)att + ((size_t)b * Rc + m0) * 128;
    const short* Ben = (const short*)em + (size_t)b * Nc * 128;

    #pragma unroll
    for (int kc = 0; kc < 4; ++kc)
        GLOAD_LDS16(Aa + (size_t)(wave * 16 + lrow) * 128 + kc * 32 + gq * 8,
                    &Asl[kc][(wave * 16) * 32]);
    for (int cch = wave; cch < 13; cch += 4)
        #pragma unroll
        for (int kc = 0; kc < 4; ++kc)
            GLOAD_LDS16(Ben + (size_t)(cch * 16 + lrow) * 128 + kc * 32 + gq * 8,
                        &Bsl[kc][(cch * 16) * 32]);
    {
        int r = t >> 2, w = t & 3;
        sm[r][w] = (m0 + r < Rc) ? maskbits[((size_t)b * Rc + m0 + r) * 4 + w] : 0ull;
    }
    if (t < 208) sbe[t] = (t < Nc) ? be[(size_t)b * Nc + t] : 0.f;
    __syncthreads();

    short8 afr[4];
    #pragma unroll
    for (int kc = 0; kc < 4; ++kc)
        afr[kc] = *(const short8*)&Asl[kc][(wave * 16 + rrow) * 32 + ((quad + srd) & 3) * 8];

    f32x4 acc[13];
    #pragma unroll
    for (int nt = 0; nt < 13; ++nt)
        acc[nt] = (f32x4){0.f, 0.f, 0.f, 0.f};
    #pragma unroll
    for (int nt = 0; nt < 13; ++nt)
        #pragma unroll
        for (int kc = 0; kc < 4; ++kc) {
            short8 bfr = *(const short8*)
                &Bsl[kc][(nt * 16 + rrow) * 32 + ((quad + srd) & 3) * 8];
            acc[nt] = __builtin_amdgcn_mfma_f32_16x16x32_bf16(afr[kc], bfr, acc[nt], 0, 0, 0);
        }

    const float scale = 0.08838834764831843f;  // 1/sqrt(128)
    #pragma unroll
    for (int i = 0; i < 4; ++i) {
        int rloc = wave * 16 + quad * 4 + i;
        int r = m0 + rloc;
        u64 w0 = sm[rloc][0], w1 = sm[rloc][1], w2 = sm[rloc][2], w3 = sm[rloc][3];
        float vals[13];
        float mx = -INFINITY;
        #pragma unroll
        for (int nt = 0; nt < 13; ++nt) {
            u64 w = (nt < 4) ? w0 : (nt < 8) ? w1 : (nt < 12) ? w2 : w3;
            int sh = ((nt & 3) << 4) + rrow;
            float lg = ((w >> sh) & 1ull)
                     ? 10.f * tanhf((acc[nt][i] + sbe[nt * 16 + rrow]) * scale)
                     : -INFINITY;
            vals[nt] = lg;
            mx = fmaxf(mx, lg);
        }
        mx = fmaxf(mx, __shfl_xor(mx, 1));
        mx = fmaxf(mx, __shfl_xor(mx, 2));
        mx = fmaxf(mx, __shfl_xor(mx, 4));
        mx = fmaxf(mx, __shfl_xor(mx, 8));
        float l = 0.f;
        #pragma unroll
        for (int nt = 0; nt < 13; ++nt) {
            float p = (vals[nt] == -INFINITY) ? 0.f : __expf(vals[nt] - mx);
            vals[nt] = p;
            l += p;
        }
        l += __shfl_xor(l, 1);
        l += __shfl_xor(l, 2);
        l += __shfl_xor(l, 4);
        l += __shfl_xor(l, 8);
        float inv = (l > 0.f) ? 1.f / l : 0.f;
        if (r < Rc) {
            #pragma unroll
            for (int nt = 0; nt < 13; ++nt) {
                int n = nt * 16 + rrow;
                if (n < Nc)
                    out[((size_t)b * Rc + r) * Nc + n] = vals[nt] * inv;
            }
        }
    }
}

// ---------------------------------------------------------------------------
extern "C" void kernel_launch(void* const* d_in, const int* in_sizes, int n_in,
                              void* d_out, int out_size, void* d_ws, size_t ws_size,
                              hipStream_t stream)
{
    const float* enc  = (const float*)d_in[0];
    const float* dist = (const float*)d_in[1];
    const float* mask = (const float*)d_in[2];
    const int*   cur  = (const int*)d_in[3];
    const float* Wq   = (const float*)d_in[4];
    const float* Wk   = (const float*)d_in[5];
    const float* Wv   = (const float*)d_in[6];
    const float* Wmhc = (const float*)d_in[7];
    const float* bmhc = (const float*)d_in[8];
    const float* W1   = (const float*)d_in[9];
    const float* b1   = (const float*)d_in[10];
    const float* W2   = (const float*)d_in[11];
    const float* b2   = (const float*)d_in[12];
    float* out = (float*)d_out;

    char* ws = (char*)d_ws;
    size_t off = 0;
    auto alloc = [&](size_t bytes) { char* p = ws + off; off += (bytes + 255) & ~(size_t)255; return p; };
    __hip_bfloat16* W1t  = (__hip_bfloat16*)alloc((size_t)640 * 1280 * 2);
    __hip_bfloat16* Wkvt = (__hip_bfloat16*)alloc((size_t)256 * 128 * 2);
    __hip_bfloat16* Wmb  = (__hip_bfloat16*)alloc((size_t)128 * 128 * 2);
    __hip_bfloat16* Wcat = (__hip_bfloat16*)alloc((size_t)128 * 768 * 2);
    float* bq = (float*)alloc((size_t)128 * 4);
    // encb: rows [0, Bc*Nc) = enc bf16; rows [Bc*Nc, Bc*Nc+BRc) = mean rows
    __hip_bfloat16* encb = (__hip_bfloat16*)alloc((size_t)(Bc * Nc + BRc + 64) * Dc * 2);
    unsigned* aoff = (unsigned*)alloc((size_t)BRc * 16 * 4);
    __hip_bfloat16* hq   = (__hip_bfloat16*)alloc((size_t)BRc * 768 * 2);
    __hip_bfloat16* q    = (__hip_bfloat16*)alloc((size_t)BRc * 128 * 2);
    __hip_bfloat16* kvf  = (__hip_bfloat16*)alloc((size_t)Bc * Nc * 256 * 2);
    __hip_bfloat16* att  = (__hip_bfloat16*)alloc((size_t)(BRc + 64) * 128 * 2);
    __hip_bfloat16* em   = (__hip_bfloat16*)alloc((size_t)(Bc * Nc + 64) * 128 * 2);
    float* be = (float*)alloc((size_t)Bc * Nc * 4);
    u64* maskbits = (u64*)alloc((size_t)BRc * 4 * 8);

    // 1) prep + kNN (independent roles, one launch, 2530 blocks)
    prep_knn_kernel<<<2530, 256, 0, stream>>>(
        W1, W2, Wq, Wmhc, Wk, Wv, b2, enc, dist, mask, cur,
        W1t, Wkvt, Wmb, Wcat, bq, encb, aoff, hq, maskbits);
    // 2) gemm1 + kvf + em + be (64x64 tiles, one launch, 1625 blocks)
    fused_gemms_kernel<<<1625, 256, 0, stream>>>(
        encb, aoff, W1t, b1, Wkvt, Wmb, bmhc, enc, hq, kvf, em, be);
    // 3) q = hq @ Wcat^T + bq  (64x64 tiles, 200 blocks)
    qgemm_kernel<<<dim3(2, BRc / 64), 256, 0, stream>>>(hq, Wcat, bq, q);
    // 4) MFMA flash attention (split row-tile halves: 512 blocks, 2/CU)
    attn_mfma_kernel<<<dim3(Bc * Hc, 2), 256, 0, stream>>>(q, kvf, maskbits, att);
    // 5) fused logits + softmax -> final probabilities in d_out
    logits_softmax_kernel<<<dim3(Bc, 4), 256, 0, stream>>>(att, em, be, maskbits, out);
}

// Round 16
// 171.559 us; speedup vs baseline: 1.4570x; 1.0109x over previous
//
#include <hip/hip_runtime.h>
#include <hip/hip_bf16.h>
#include <math.h>

#define Bc 32
#define Rc 200
#define Nc 200
#define Dc 128
#define Hc 8
#define QKc 16
#define Kc 10
#define BRc (Bc*Rc)

typedef __attribute__((ext_vector_type(8))) short short8;
typedef __attribute__((ext_vector_type(4))) float f32x4;
typedef unsigned long long u64;

#define GLOAD_LDS16(g, l) __builtin_amdgcn_global_load_lds( \
    (const __attribute__((address_space(1))) void*)(g), \
    (__attribute__((address_space(3))) void*)(l), 16, 0, 0)

// ---------------------------------------------------------------------------
// 32x32 transpose+convert tile helper (block-uniform call sites only)
// ---------------------------------------------------------------------------
__device__ inline void transpose_tile(const float* __restrict__ src, int lds_,
                                      __hip_bfloat16* __restrict__ dst, int ldd,
                                      int k0, int n0, float scale)
{
    __shared__ float tile[32][33];
    int tx = threadIdx.x & 31, ty = threadIdx.x >> 5;  // 32 x 8
    #pragma unroll
    for (int i = ty; i < 32; i += 8)
        tile[i][tx] = src[(size_t)(k0 + i) * lds_ + n0 + tx];
    __syncthreads();
    #pragma unroll
    for (int i = ty; i < 32; i += 8)
        dst[(size_t)(n0 + i) * ldd + k0 + tx] = __float2bfloat16(tile[tx][i] * scale);
}

// ---------------------------------------------------------------------------
// Kernel 1: prep + kNN fused (independent roles, one launch).
// ---------------------------------------------------------------------------
__global__ __launch_bounds__(256) void prep_knn_kernel(
    const float* __restrict__ W1, const float* __restrict__ W2,
    const float* __restrict__ Wq, const float* __restrict__ Wmhc,
    const float* __restrict__ Wk, const float* __restrict__ Wv,
    const float* __restrict__ b2, const float* __restrict__ enc,
    const float* __restrict__ dist, const float* __restrict__ mask,
    const int* __restrict__ cur,
    __hip_bfloat16* __restrict__ W1t, __hip_bfloat16* __restrict__ Wkvt,
    __hip_bfloat16* __restrict__ Wmb, __hip_bfloat16* __restrict__ Wcat,
    float* __restrict__ bq, __hip_bfloat16* __restrict__ encb,
    unsigned* __restrict__ aoff, __hip_bfloat16* __restrict__ hq,
    u64* __restrict__ maskbits)
{
    int bid = blockIdx.x;
    int t = threadIdx.x;
    if (bid < 800) {
        transpose_tile(W1, 640, W1t, 1280, (bid % 40) * 32, (bid / 40) * 32, 1.f);
    } else if (bid < 816) {
        int id = bid - 800;
        transpose_tile(Wk, 128, Wkvt, 128, (id & 3) * 32, (id >> 2) * 32, 1.f);
    } else if (bid < 832) {
        int id = bid - 816;
        transpose_tile(Wv, 128, Wkvt + 128 * 128, 128, (id & 3) * 32, (id >> 2) * 32, 1.f);
    } else if (bid < 848) {
        int e = (bid - 832) * 1024 + t * 4;
        #pragma unroll
        for (int j = 0; j < 4; ++j) Wmb[e + j] = __float2bfloat16(Wmhc[e + j]);
    } else if (bid < 864) {
        int id = bid - 848;
        transpose_tile(Wq, 128, Wcat, 768, (id & 3) * 32, (id >> 2) * 32, 0.25f);
    } else if (bid < 904) {
        int j0 = (bid - 864) * 16;
        int n = t & 127, half = t >> 7;
        #pragma unroll
        for (int jj = 0; jj < 8; ++jj) {
            int j = j0 + half * 8 + jj;
            float acc = 0.f;
            for (int k = 0; k < 128; ++k)
                acc = fmaf(W2[(size_t)j * 128 + k], Wq[(size_t)(128 + k) * 128 + n], acc);
            Wcat[(size_t)n * 768 + 128 + j] = __float2bfloat16(acc * 0.25f);
        }
    } else if (bid < 929) {
        size_t base = (size_t)(bid - 904) * 32768 + (size_t)t * 4;
        #pragma unroll 4
        for (int it = 0; it < 32; ++it) {
            size_t i = base + (size_t)it * 1024;
            float4 v = *(const float4*)(enc + i);
            encb[i + 0] = __float2bfloat16(v.x);
            encb[i + 1] = __float2bfloat16(v.y);
            encb[i + 2] = __float2bfloat16(v.z);
            encb[i + 3] = __float2bfloat16(v.w);
        }
    } else if (bid == 929) {
        if (t < 128) {
            float acc = 0.f;
            for (int k = 0; k < 128; ++k)
                acc = fmaf(b2[k], Wq[(size_t)(128 + k) * 128 + t], acc);
            bq[t] = acc * 0.25f;
        }
    } else {
        // kNN role: wave-per-row, register-only
        int lane = t & 63, w = t >> 6;
        int br = (bid - 930) * 4 + w;
        int b = br / Rc;
        int c = cur[br];
        const float* drow = dist + ((size_t)b * Nc + c) * Nc;
        const float* mrow = mask + (size_t)br * Nc;

        float v[4];
        #pragma unroll
        for (int j = 0; j < 4; ++j) {
            int n = lane + 64 * j;
            bool allowed = false;
            float val = INFINITY;
            if (n < Nc) {
                float mv = mrow[n];
                if (!isinf(mv)) { val = drow[n]; allowed = true; }
            }
            v[j] = val;
            u64 wb = __ballot(allowed);
            if (lane == 0) maskbits[(size_t)br * 4 + j] = wb;
        }
        int idxs[Kc];
        unsigned myrow = 0;
        #pragma unroll
        for (int k = 0; k < Kc; ++k) {
            float bv = v[0]; int bn = lane;
            #pragma unroll
            for (int j = 1; j < 4; ++j) {
                if (v[j] < bv) { bv = v[j]; bn = lane + 64 * j; }
            }
            #pragma unroll
            for (int off = 32; off > 0; off >>= 1) {
                float ov = __shfl_xor(bv, off);
                int   on = __shfl_xor(bn, off);
                if (ov < bv || (ov == bv && on < bn)) { bv = ov; bn = on; }
            }
            bool pad = isinf(bv);
            idxs[k] = pad ? Nc : bn;
            if (lane == k) myrow = pad ? (unsigned)(Bc * Nc + br) : (unsigned)(b * Nc + bn);
            int oj = bn >> 6, ol = bn & 63;
            if (!pad && lane == ol) v[oj] = INFINITY;
        }
        if (lane < Kc) aoff[(size_t)br * 16 + lane] = myrow << 7;

        const float* erow = enc + ((size_t)b * Nc + c) * Dc;
        __hip_bfloat16* hrow = hq + (size_t)br * 768;
        hrow[lane]      = __float2bfloat16(erow[lane]);
        hrow[lane + 64] = __float2bfloat16(erow[lane + 64]);

        if (idxs[Kc - 1] == Nc) {   // wave-uniform cold path: pads exist
            float cnt = 0.f;
            #pragma unroll
            for (int k = 0; k < Kc; ++k) cnt += (idxs[k] < Nc) ? 1.f : 0.f;
            float icnt = 1.f / fmaxf(cnt, 1e-9f);
            #pragma unroll
            for (int half = 0; half < 2; ++half) {
                int d = lane + 64 * half;
                float sum = 0.f;
                #pragma unroll
                for (int k = 0; k < Kc; ++k) {
                    if (idxs[k] < Nc)
                        sum += enc[((size_t)b * Nc + idxs[k]) * Dc + d];
                }
                encb[((size_t)(Bc * Nc) + br) * Dc + d] = __float2bfloat16(sum * icnt);
            }
        }
    }
}

// ---------------------------------------------------------------------------
// Kernel 2: mid-pipeline GEMMs, 64x64 tiles, BK=128 (halved barrier count;
// kvf/em stage their whole K=128 in one shot):
//  [0,1000)    gemm1: hq[:,128:768] = relu(gather(encb) @ W1t^T + b1), K=1280
//  [1000,1400) kvf = encb @ [Wk|Wv]^T  (K=128)
//  [1400,1600) em  = encb @ Wmb^T      (K=128)
//  [1600,1625) be[i] = bmhc . enc[i]
// ---------------------------------------------------------------------------
__global__ __launch_bounds__(256) void fused_gemms_kernel(
    const __hip_bfloat16* __restrict__ encb, const unsigned* __restrict__ aoff,
    const __hip_bfloat16* __restrict__ W1t, const float* __restrict__ b1,
    const __hip_bfloat16* __restrict__ Wkvt, const __hip_bfloat16* __restrict__ Wmb,
    const float* __restrict__ bmhc, const float* __restrict__ enc,
    __hip_bfloat16* __restrict__ hq, __hip_bfloat16* __restrict__ kvf,
    __hip_bfloat16* __restrict__ em, float* __restrict__ be)
{
    __shared__ short Asl[4][64 * 32];   // 16 KB
    __shared__ short Bsl[4][64 * 32];   // 16 KB
    int bid = blockIdx.x;
    int tid = threadIdx.x;
    int wave = tid >> 6, lane = tid & 63;
    int lrow = lane >> 2;
    int cg   = lane & 3;
    int ss   = (lane >> 3) & 3;
    int gq   = (cg - ss) & 3;
    int wm = wave >> 1, wn = wave & 1;
    int rrow = lane & 15, quad = lane >> 4;
    int srd  = (rrow >> 1) & 3;
    int strip = (wave & 1) * 32;   // staging strip for this wave's operand

    if (bid < 1000) {
        // ---- gemm1 (gather A, K=1280, 10 barrier iters of BK=128)
        int m0 = (bid / 10) * 64, n0 = (bid % 10) * 64;
        unsigned o0[Kc], o1[Kc];
        if (wave < 2) {
            const unsigned* ap0 = aoff + (size_t)(m0 + strip + lrow) * 16;
            const unsigned* ap1 = ap0 + 16 * 16;
            #pragma unroll
            for (int j = 0; j < Kc; ++j) { o0[j] = ap0[j]; o1[j] = ap1[j]; }
        }
        const short* Eb = (const short*)encb;
        const short* gB0 = (const short*)W1t + (size_t)(n0 + strip + lrow) * 1280 + gq * 8;
        const short* gB1 = gB0 + (size_t)16 * 1280;

        f32x4 acc[2][2];
        #pragma unroll
        for (int i = 0; i < 2; ++i)
            #pragma unroll
            for (int j = 0; j < 2; ++j)
                acc[i][j] = (f32x4){0.f, 0.f, 0.f, 0.f};

        #pragma unroll
        for (int kt = 0; kt < 10; ++kt) {
            __syncthreads();
            #pragma unroll
            for (int s = 0; s < 4; ++s) {
                if (wave < 2) {
                    GLOAD_LDS16(Eb + o0[kt] + s * 32 + gq * 8, &Asl[s][strip * 32]);
                    GLOAD_LDS16(Eb + o1[kt] + s * 32 + gq * 8, &Asl[s][(strip + 16) * 32]);
                } else {
                    GLOAD_LDS16(gB0 + kt * 128 + s * 32, &Bsl[s][strip * 32]);
                    GLOAD_LDS16(gB1 + kt * 128 + s * 32, &Bsl[s][(strip + 16) * 32]);
                }
            }
            __syncthreads();
            #pragma unroll
            for (int s = 0; s < 4; ++s) {
                short8 afr[2], bfr[2];
                #pragma unroll
                for (int mt = 0; mt < 2; ++mt)
                    afr[mt] = *(const short8*)&Asl[s][(wm * 32 + mt * 16 + rrow) * 32 + ((quad + srd) & 3) * 8];
                #pragma unroll
                for (int nt = 0; nt < 2; ++nt)
                    bfr[nt] = *(const short8*)&Bsl[s][(wn * 32 + nt * 16 + rrow) * 32 + ((quad + srd) & 3) * 8];
                #pragma unroll
                for (int mt = 0; mt < 2; ++mt)
                    #pragma unroll
                    for (int nt = 0; nt < 2; ++nt)
                        acc[mt][nt] = __builtin_amdgcn_mfma_f32_16x16x32_bf16(
                            afr[mt], bfr[nt], acc[mt][nt], 0, 0, 0);
            }
        }
        #pragma unroll
        for (int mt = 0; mt < 2; ++mt)
            #pragma unroll
            for (int nt = 0; nt < 2; ++nt) {
                int n = wn * 32 + nt * 16 + rrow;
                float bv = b1[n0 + n];
                #pragma unroll
                for (int i = 0; i < 4; ++i) {
                    int m = m0 + wm * 32 + mt * 16 + quad * 4 + i;
                    float vv = fmaxf(acc[mt][nt][i] + bv, 0.f);
                    hq[(size_t)m * 768 + 128 + n0 + n] = __float2bfloat16(vv);
                }
            }
    } else if (bid < 1600) {
        // ---- kvf or em (K=128, SINGLE barrier)
        const short* Bbase; __hip_bfloat16* Cout; int ldc, m0, n0;
        if (bid < 1400) {
            int id = bid - 1000;
            Bbase = (const short*)Wkvt; Cout = kvf; ldc = 256;
            m0 = (id >> 2) * 64; n0 = (id & 3) * 64;
        } else {
            int id = bid - 1400;
            Bbase = (const short*)Wmb; Cout = em; ldc = 128;
            m0 = (id >> 1) * 64; n0 = (id & 1) * 64;
        }
        const short* g0 = (wave < 2)
            ? (const short*)encb + (size_t)(m0 + strip + lrow) * 128 + gq * 8
            : Bbase + (size_t)(n0 + strip + lrow) * 128 + gq * 8;
        const short* g1 = g0 + (size_t)16 * 128;

        f32x4 acc[2][2];
        #pragma unroll
        for (int i = 0; i < 2; ++i)
            #pragma unroll
            for (int j = 0; j < 2; ++j)
                acc[i][j] = (f32x4){0.f, 0.f, 0.f, 0.f};

        #pragma unroll
        for (int s = 0; s < 4; ++s) {
            short* l0 = (wave < 2) ? &Asl[s][strip * 32] : &Bsl[s][strip * 32];
            short* l1 = (wave < 2) ? &Asl[s][(strip + 16) * 32] : &Bsl[s][(strip + 16) * 32];
            GLOAD_LDS16(g0 + s * 32, l0);
            GLOAD_LDS16(g1 + s * 32, l1);
        }
        __syncthreads();
        #pragma unroll
        for (int s = 0; s < 4; ++s) {
            short8 afr[2], bfr[2];
            #pragma unroll
            for (int mt = 0; mt < 2; ++mt)
                afr[mt] = *(const short8*)&Asl[s][(wm * 32 + mt * 16 + rrow) * 32 + ((quad + srd) & 3) * 8];
            #pragma unroll
            for (int nt = 0; nt < 2; ++nt)
                bfr[nt] = *(const short8*)&Bsl[s][(wn * 32 + nt * 16 + rrow) * 32 + ((quad + srd) & 3) * 8];
            #pragma unroll
            for (int mt = 0; mt < 2; ++mt)
                #pragma unroll
                for (int nt = 0; nt < 2; ++nt)
                    acc[mt][nt] = __builtin_amdgcn_mfma_f32_16x16x32_bf16(
                        afr[mt], bfr[nt], acc[mt][nt], 0, 0, 0);
        }
        #pragma unroll
        for (int mt = 0; mt < 2; ++mt)
            #pragma unroll
            for (int nt = 0; nt < 2; ++nt) {
                int n = wn * 32 + nt * 16 + rrow;
                #pragma unroll
                for (int i = 0; i < 4; ++i) {
                    int m = m0 + wm * 32 + mt * 16 + quad * 4 + i;
                    Cout[(size_t)m * ldc + n0 + n] = __float2bfloat16(acc[mt][nt][i]);
                }
            }
    } else {
        // ---- be[i] = bmhc . enc[i,:]   (i < Bc*Nc = 6400; 25 blocks)
        int i = (bid - 1600) * 256 + tid;
        if (i < Bc * Nc) {
            const float* row = enc + (size_t)i * 128;
            float acc = 0.f;
            #pragma unroll
            for (int dq = 0; dq < 32; ++dq) {
                float4 e4 = *(const float4*)(row + dq * 4);
                acc = fmaf(bmhc[dq * 4 + 0], e4.x, acc);
                acc = fmaf(bmhc[dq * 4 + 1], e4.y, acc);
                acc = fmaf(bmhc[dq * 4 + 2], e4.z, acc);
                acc = fmaf(bmhc[dq * 4 + 3], e4.w, acc);
            }
            be[i] = acc;
        }
    }
}

// ---------------------------------------------------------------------------
// Kernel 3: q = hq @ Wcat^T + bq  (64x64 tiles, BK=128 -> 6 barrier iters)
// ---------------------------------------------------------------------------
__global__ __launch_bounds__(256) void qgemm_kernel(
    const __hip_bfloat16* __restrict__ hq, const __hip_bfloat16* __restrict__ Wcat,
    const float* __restrict__ bq, __hip_bfloat16* __restrict__ q)
{
    __shared__ short Asl[4][64 * 32];
    __shared__ short Bsl[4][64 * 32];
    int tid = threadIdx.x;
    int wave = tid >> 6, lane = tid & 63;
    int m0 = blockIdx.y * 64, n0 = blockIdx.x * 64;
    int lrow = lane >> 2;
    int cg   = lane & 3;
    int ss   = (lane >> 3) & 3;
    int gq   = (cg - ss) & 3;
    int wm = wave >> 1, wn = wave & 1;
    int rrow = lane & 15, quad = lane >> 4;
    int srd  = (rrow >> 1) & 3;
    int strip = (wave & 1) * 32;

    const short* g0 = (wave < 2)
        ? (const short*)hq + (size_t)(m0 + strip + lrow) * 768 + gq * 8
        : (const short*)Wcat + (size_t)(n0 + strip + lrow) * 768 + gq * 8;
    const short* g1 = g0 + (size_t)16 * 768;

    f32x4 acc[2][2];
    #pragma unroll
    for (int i = 0; i < 2; ++i)
        #pragma unroll
        for (int j = 0; j < 2; ++j)
            acc[i][j] = (f32x4){0.f, 0.f, 0.f, 0.f};

    for (int k0 = 0; k0 < 768; k0 += 128) {
        __syncthreads();
        #pragma unroll
        for (int s = 0; s < 4; ++s) {
            short* l0 = (wave < 2) ? &Asl[s][strip * 32] : &Bsl[s][strip * 32];
            short* l1 = (wave < 2) ? &Asl[s][(strip + 16) * 32] : &Bsl[s][(strip + 16) * 32];
            GLOAD_LDS16(g0 + k0 + s * 32, l0);
            GLOAD_LDS16(g1 + k0 + s * 32, l1);
        }
        __syncthreads();
        #pragma unroll
        for (int s = 0; s < 4; ++s) {
            short8 afr[2], bfr[2];
            #pragma unroll
            for (int mt = 0; mt < 2; ++mt)
                afr[mt] = *(const short8*)&Asl[s][(wm * 32 + mt * 16 + rrow) * 32 + ((quad + srd) & 3) * 8];
            #pragma unroll
            for (int nt = 0; nt < 2; ++nt)
                bfr[nt] = *(const short8*)&Bsl[s][(wn * 32 + nt * 16 + rrow) * 32 + ((quad + srd) & 3) * 8];
            #pragma unroll
            for (int mt = 0; mt < 2; ++mt)
                #pragma unroll
                for (int nt = 0; nt < 2; ++nt)
                    acc[mt][nt] = __builtin_amdgcn_mfma_f32_16x16x32_bf16(
                        afr[mt], bfr[nt], acc[mt][nt], 0, 0, 0);
        }
    }

    #pragma unroll
    for (int mt = 0; mt < 2; ++mt) {
        #pragma unroll
        for (int nt = 0; nt < 2; ++nt) {
            int n = wn * 32 + nt * 16 + rrow;
            float bv = bq[n0 + n];
            #pragma unroll
            for (int i = 0; i < 4; ++i) {
                int m = m0 + wm * 32 + mt * 16 + quad * 4 + i;
                q[(size_t)m * 128 + n0 + n] = __float2bfloat16(acc[mt][nt][i] + bv);
            }
        }
    }
}

// ---------------------------------------------------------------------------
// Kernel 4: MFMA flash attention. Grid (Bc*Hc, 2): blockIdx.y selects the
// row-tile half (tiles 0-6 / 7-12) -> 512 blocks = 2 blocks/CU, 8 waves/CU.
// ---------------------------------------------------------------------------
__global__ __launch_bounds__(256) void attn_mfma_kernel(
    const __hip_bfloat16* __restrict__ q, const __hip_bfloat16* __restrict__ kvf,
    const u64* __restrict__ maskbits, __hip_bfloat16* __restrict__ att)
{
    constexpr int RP = 208;
    constexpr int QS = 40;
    constexpr int VS = 232;
    __shared__ short Qs[RP * QS];
    __shared__ short Ks[RP * QS];
    __shared__ short Vt[16 * VS];
    __shared__ short Ps[4][16 * VS];
    __shared__ u64 smask[RP][4];

    int b = blockIdx.x >> 3, h = blockIdx.x & 7;
    int half = blockIdx.y;
    int t = threadIdx.x;
    int wave = t >> 6, lane = t & 63;
    int rrow = lane & 15, quad = lane >> 4;

    const short8 z8 = {0, 0, 0, 0, 0, 0, 0, 0};
    for (int idx = t; idx < RP * 2; idx += 256) {
        int r = idx >> 1, g = idx & 1;
        short8 qa = z8, ka = z8;
        if (r < Rc) {
            qa = *(const short8*)((const short*)q + ((size_t)(b * Rc + r)) * 128 + h * 16 + g * 8);
            ka = *(const short8*)((const short*)kvf + ((size_t)(b * Nc + r)) * 256 + h * 16 + g * 8);
        }
        *(short8*)&Qs[r * QS + g * 8] = qa;
        *(short8*)&Ks[r * QS + g * 8] = ka;
        *(short8*)&Qs[r * QS + 16 + g * 8] = z8;
        *(short8*)&Ks[r * QS + 16 + g * 8] = z8;
    }
    if (t < Rc) {
        const short* vp = (const short*)kvf + ((size_t)(b * Nc + t)) * 256 + 128 + h * 16;
        short8 v0 = *(const short8*)vp;
        short8 v1 = *(const short8*)(vp + 8);
        #pragma unroll
        for (int d = 0; d < 8; ++d) Vt[d * VS + t] = v0[d];
        #pragma unroll
        for (int d = 0; d < 8; ++d) Vt[(d + 8) * VS + t] = v1[d];
    }
    for (int idx = t; idx < 16 * 32; idx += 256) {
        int d = idx >> 5, cN = 200 + (idx & 31);
        if (cN < VS) Vt[d * VS + cN] = 0;
    }
    for (int idx = lane; idx < 16 * 16; idx += 64) {
        int rr = idx >> 4, cc = 208 + (idx & 15);
        Ps[wave][rr * VS + cc] = 0;
    }
    for (int idx = t; idx < RP * 4; idx += 256) {
        int r = idx >> 2, w = idx & 3;
        smask[r][w] = (r < Rc) ? maskbits[((size_t)b * Rc + r) * 4 + w] : ~0ull;
    }
    __syncthreads();

    int rt0 = half * 7, rt1 = half ? 13 : 7;
    for (int rt = rt0 + wave; rt < rt1; rt += 4) {
        short8 qf = *(const short8*)&Qs[(rt * 16 + rrow) * QS + quad * 8];
        f32x4 sacc[13];
        #pragma unroll
        for (int nt = 0; nt < 13; ++nt) {
            short8 kf = *(const short8*)&Ks[(nt * 16 + rrow) * QS + quad * 8];
            sacc[nt] = __builtin_amdgcn_mfma_f32_16x16x32_bf16(
                qf, kf, (f32x4){0.f, 0.f, 0.f, 0.f}, 0, 0, 0);
        }
        float inv[4];
        #pragma unroll
        for (int i = 0; i < 4; ++i) {
            int r = rt * 16 + quad * 4 + i;
            u64 wv0 = smask[r][0], wv1 = smask[r][1], wv2 = smask[r][2], wv3 = smask[r][3];
            float mx = -INFINITY;
            #pragma unroll
            for (int nt = 0; nt < 13; ++nt) {
                u64 w = (nt < 4) ? wv0 : (nt < 8) ? wv1 : (nt < 12) ? wv2 : wv3;
                int sh = ((nt & 3) << 4) + rrow;
                float s = ((w >> sh) & 1ull) ? sacc[nt][i] : -INFINITY;
                sacc[nt][i] = s;
                mx = fmaxf(mx, s);
            }
            mx = fmaxf(mx, __shfl_xor(mx, 1));
            mx = fmaxf(mx, __shfl_xor(mx, 2));
            mx = fmaxf(mx, __shfl_xor(mx, 4));
            mx = fmaxf(mx, __shfl_xor(mx, 8));
            float l = 0.f;
            #pragma unroll
            for (int nt = 0; nt < 13; ++nt) {
                float p = __expf(sacc[nt][i] - mx);
                sacc[nt][i] = p;
                l += p;
            }
            l += __shfl_xor(l, 1);
            l += __shfl_xor(l, 2);
            l += __shfl_xor(l, 4);
            l += __shfl_xor(l, 8);
            inv[i] = (l > 0.f) ? 1.f / l : 0.f;
        }
        #pragma unroll
        for (int nt = 0; nt < 13; ++nt)
            #pragma unroll
            for (int i = 0; i < 4; ++i)
                *(__hip_bfloat16*)&Ps[wave][(quad * 4 + i) * VS + nt * 16 + rrow] =
                    __float2bfloat16(sacc[nt][i]);
        f32x4 oacc = (f32x4){0.f, 0.f, 0.f, 0.f};
        #pragma unroll
        for (int kt = 0; kt < 7; ++kt) {
            short8 pf = *(const short8*)&Ps[wave][rrow * VS + kt * 32 + quad * 8];
            short8 vf = *(const short8*)&Vt[rrow * VS + kt * 32 + quad * 8];
            oacc = __builtin_amdgcn_mfma_f32_16x16x32_bf16(pf, vf, oacc, 0, 0, 0);
        }
        #pragma unroll
        for (int i = 0; i < 4; ++i) {
            int r = rt * 16 + quad * 4 + i;
            if (r < Rc)
                att[((size_t)(b * Rc + r)) * 128 + h * 16 + rrow] =
                    __float2bfloat16(oacc[i] * inv[i]);
        }
    }
}

// ---------------------------------------------------------------------------
// Kernel 5: fused logits + softmax. 32-row blocks x 128 threads (2 waves),
// grid (32,7) = 224 blocks -> spread across all CUs. Each wave owns one
// complete 16-row tile x all 13 n-tiles; row softmax wave-local.
// ---------------------------------------------------------------------------
__global__ __launch_bounds__(128) void logits_softmax_kernel(
    const __hip_bfloat16* __restrict__ att, const __hip_bfloat16* __restrict__ em,
    const float* __restrict__ be, const u64* __restrict__ maskbits,
    float* __restrict__ out)
{
    __shared__ short Asl[4][32 * 32];    // 8 KB
    __shared__ short Bsl[4][208 * 32];   // 53 KB
    __shared__ u64 sm[32][4];
    __shared__ float sbe[208];
    int b = blockIdx.x, m0 = blockIdx.y * 32;
    int t = threadIdx.x, wave = t >> 6, lane = t & 63;
    int lrow = lane >> 2, cg = lane & 3, ss = (lane >> 3) & 3, gq = (cg - ss) & 3;
    int rrow = lane & 15, quad = lane >> 4, srd = (rrow >> 1) & 3;

    const short* Aa = (const short*)att + ((size_t)b * Rc + m0) * 128;
    const short* Ben = (const short*)em + (size_t)b * Nc * 128;

    #pragma unroll
    for (int kc = 0; kc < 4; ++kc)
        GLOAD_LDS16(Aa + (size_t)(wave * 16 + lrow) * 128 + kc * 32 + gq * 8,
                    &Asl[kc][(wave * 16) * 32]);
    for (int cch = wave; cch < 13; cch += 2)
        #pragma unroll
        for (int kc = 0; kc < 4; ++kc)
            GLOAD_LDS16(Ben + (size_t)(cch * 16 + lrow) * 128 + kc * 32 + gq * 8,
                        &Bsl[kc][(cch * 16) * 32]);
    {
        int r = t >> 2, w = t & 3;   // 128 threads = 32 rows x 4 words
        sm[r][w] = (m0 + r < Rc) ? maskbits[((size_t)b * Rc + m0 + r) * 4 + w] : 0ull;
    }
    for (int i = t; i < 208; i += 128) sbe[i] = (i < Nc) ? be[(size_t)b * Nc + i] : 0.f;
    __syncthreads();

    short8 afr[4];
    #pragma unroll
    for (int kc = 0; kc < 4; ++kc)
        afr[kc] = *(const short8*)&Asl[kc][(wave * 16 + rrow) * 32 + ((quad + srd) & 3) * 8];

    f32x4 acc[13];
    #pragma unroll
    for (int nt = 0; nt < 13; ++nt)
        acc[nt] = (f32x4){0.f, 0.f, 0.f, 0.f};
    #pragma unroll
    for (int nt = 0; nt < 13; ++nt)
        #pragma unroll
        for (int kc = 0; kc < 4; ++kc) {
            short8 bfr = *(const short8*)
                &Bsl[kc][(nt * 16 + rrow) * 32 + ((quad + srd) & 3) * 8];
            acc[nt] = __builtin_amdgcn_mfma_f32_16x16x32_bf16(afr[kc], bfr, acc[nt], 0, 0, 0);
        }

    const float scale = 0.08838834764831843f;  // 1/sqrt(128)
    #pragma unroll
    for (int i = 0; i < 4; ++i) {
        int rloc = wave * 16 + quad * 4 + i;
        int r = m0 + rloc;
        u64 w0 = sm[rloc][0], w1 = sm[rloc][1], w2 = sm[rloc][2], w3 = sm[rloc][3];
        float vals[13];
        float mx = -INFINITY;
        #pragma unroll
        for (int nt = 0; nt < 13; ++nt) {
            u64 w = (nt < 4) ? w0 : (nt < 8) ? w1 : (nt < 12) ? w2 : w3;
            int sh = ((nt & 3) << 4) + rrow;
            float lg = ((w >> sh) & 1ull)
                     ? 10.f * tanhf((acc[nt][i] + sbe[nt * 16 + rrow]) * scale)
                     : -INFINITY;
            vals[nt] = lg;
            mx = fmaxf(mx, lg);
        }
        mx = fmaxf(mx, __shfl_xor(mx, 1));
        mx = fmaxf(mx, __shfl_xor(mx, 2));
        mx = fmaxf(mx, __shfl_xor(mx, 4));
        mx = fmaxf(mx, __shfl_xor(mx, 8));
        float l = 0.f;
        #pragma unroll
        for (int nt = 0; nt < 13; ++nt) {
            float p = (vals[nt] == -INFINITY) ? 0.f : __expf(vals[nt] - mx);
            vals[nt] = p;
            l += p;
        }
        l += __shfl_xor(l, 1);
        l += __shfl_xor(l, 2);
        l += __shfl_xor(l, 4);
        l += __shfl_xor(l, 8);
        float inv = (l > 0.f) ? 1.f / l : 0.f;
        if (r < Rc) {
            #pragma unroll
            for (int nt = 0; nt < 13; ++nt) {
                int n = nt * 16 + rrow;
                if (n < Nc)
                    out[((size_t)b * Rc + r) * Nc + n] = vals[nt] * inv;
            }
        }
    }
}

// ---------------------------------------------------------------------------
extern "C" void kernel_launch(void* const* d_in, const int* in_sizes, int n_in,
                              void* d_out, int out_size, void* d_ws, size_t ws_size,
                              hipStream_t stream)
{
    const float* enc  = (const float*)d_in[0];
    const float* dist = (const float*)d_in[1];
    const float* mask = (const float*)d_in[2];
    const int*   cur  = (const int*)d_in[3];
    const float* Wq   = (const float*)d_in[4];
    const float* Wk   = (const float*)d_in[5];
    const float* Wv   = (const float*)d_in[6];
    const float* Wmhc = (const float*)d_in[7];
    const float* bmhc = (const float*)d_in[8];
    const float* W1   = (const float*)d_in[9];
    const float* b1   = (const float*)d_in[10];
    const float* W2   = (const float*)d_in[11];
    const float* b2   = (const float*)d_in[12];
    float* out = (float*)d_out;

    char* ws = (char*)d_ws;
    size_t off = 0;
    auto alloc = [&](size_t bytes) { char* p = ws + off; off += (bytes + 255) & ~(size_t)255; return p; };
    __hip_bfloat16* W1t  = (__hip_bfloat16*)alloc((size_t)640 * 1280 * 2);
    __hip_bfloat16* Wkvt = (__hip_bfloat16*)alloc((size_t)256 * 128 * 2);
    __hip_bfloat16* Wmb  = (__hip_bfloat16*)alloc((size_t)128 * 128 * 2);
    __hip_bfloat16* Wcat = (__hip_bfloat16*)alloc((size_t)128 * 768 * 2);
    float* bq = (float*)alloc((size_t)128 * 4);
    // encb: rows [0, Bc*Nc) = enc bf16; rows [Bc*Nc, Bc*Nc+BRc) = mean rows
    __hip_bfloat16* encb = (__hip_bfloat16*)alloc((size_t)(Bc * Nc + BRc + 64) * Dc * 2);
    unsigned* aoff = (unsigned*)alloc((size_t)BRc * 16 * 4);
    __hip_bfloat16* hq   = (__hip_bfloat16*)alloc((size_t)BRc * 768 * 2);
    __hip_bfloat16* q    = (__hip_bfloat16*)alloc((size_t)BRc * 128 * 2);
    __hip_bfloat16* kvf  = (__hip_bfloat16*)alloc((size_t)Bc * Nc * 256 * 2);
    __hip_bfloat16* att  = (__hip_bfloat16*)alloc((size_t)(BRc + 64) * 128 * 2);
    __hip_bfloat16* em   = (__hip_bfloat16*)alloc((size_t)(Bc * Nc + 64) * 128 * 2);
    float* be = (float*)alloc((size_t)Bc * Nc * 4);
    u64* maskbits = (u64*)alloc((size_t)BRc * 4 * 8);

    // 1) prep + kNN (independent roles, one launch, 2530 blocks)
    prep_knn_kernel<<<2530, 256, 0, stream>>>(
        W1, W2, Wq, Wmhc, Wk, Wv, b2, enc, dist, mask, cur,
        W1t, Wkvt, Wmb, Wcat, bq, encb, aoff, hq, maskbits);
    // 2) gemm1 + kvf + em + be (BK=128, one launch, 1625 blocks)
    fused_gemms_kernel<<<1625, 256, 0, stream>>>(
        encb, aoff, W1t, b1, Wkvt, Wmb, bmhc, enc, hq, kvf, em, be);
    // 3) q = hq @ Wcat^T + bq  (BK=128, 200 blocks)
    qgemm_kernel<<<dim3(2, BRc / 64), 256, 0, stream>>>(hq, Wcat, bq, q);
    // 4) MFMA flash attention (split row-tile halves: 512 blocks)
    attn_mfma_kernel<<<dim3(Bc * Hc, 2), 256, 0, stream>>>(q, kvf, maskbits, att);
    // 5) fused logits + softmax (32-row blocks, grid (32,7) = 224 blocks)
    logits_softmax_kernel<<<dim3(Bc, 7), 128, 0, stream>>>(att, em, be, maskbits, out);
}